// Round 1
// baseline (860.880 us; speedup 1.0000x reference)
//
#include <hip/hip_runtime.h>
#include <cmath>

#define DEVI __device__ __forceinline__

DEVI float sigm(float x){ return 1.f/(1.f+expf(-x)); }

// ---------------- small utility kernels ----------------

__global__ void k_zero(float* __restrict__ p, int n){
  int i = blockIdx.x*256 + threadIdx.x;
  if (i < n) p[i] = 0.f;
}

// column mean of memory (2048 x 128) -> cm[128]
__global__ __launch_bounds__(1024) void k_colmean(const float* __restrict__ mem, float* __restrict__ cm){
  __shared__ float s[8][128];
  int d = threadIdx.x & 127, g = threadIdx.x >> 7;
  float a = 0.f;
  for (int n = g; n < 2048; n += 8) a += mem[(size_t)n*128 + d];
  s[g][d] = a;
  __syncthreads();
  if (g == 0){
    float t = 0.f;
    #pragma unroll
    for (int i = 0; i < 8; i++) t += s[i][d];
    cm[d] = t * (1.f/2048.f);
  }
}

// inverse L2 norm of each 128-wide row (wave per row)
__global__ __launch_bounds__(256) void k_rownorm128(const float* __restrict__ A, float* __restrict__ invn, int rows){
  int w = (blockIdx.x*blockDim.x + threadIdx.x) >> 6;
  int lane = threadIdx.x & 63;
  if (w >= rows) return;
  const float* a = A + (size_t)w*128;
  float x0 = a[lane], x1 = a[lane+64];
  float s = x0*x0 + x1*x1;
  #pragma unroll
  for (int o = 32; o > 0; o >>= 1) s += __shfl_down(s, o);
  if (lane == 0) invn[w] = 1.f / fmaxf(sqrtf(s), 1e-12f);
}

// cin[b,k] = k<1024 ? x[b,k] : cm[(k-1024)%128]
__global__ void k_cin(const float* __restrict__ x, const float* __restrict__ cm, float* __restrict__ cin){
  int idx = blockIdx.x*256 + threadIdx.x;     // 256*1536
  int b = idx / 1536, k = idx - b*1536;
  cin[idx] = (k < 1024) ? x[b*1024 + k] : cm[(k-1024) & 127];
}

// ---------------- generic NT GEMM: C[M,N] = A[M,K] @ B[N,K]^T (epilogue opts) ----------------
// K must be a multiple of 16. 64x64 tile, 256 threads, 4x4 microtile.
__global__ __launch_bounds__(256) void gemm_nt(
    const float* __restrict__ A, const float* __restrict__ Bm, float* __restrict__ C,
    int M, int N, int K,
    const float* __restrict__ bias1, const float* __restrict__ bias2,
    const float* __restrict__ rowscale, const float* __restrict__ colscale)
{
  __shared__ float As[16][68];
  __shared__ float Bs[16][68];
  const int m0 = blockIdx.y*64, n0 = blockIdx.x*64;
  const int tid = threadIdx.x;
  const int tx = tid & 15, ty = tid >> 4;
  const int r = tid >> 2, kq = (tid & 3) << 2;
  float acc[4][4] = {};
  for (int k0 = 0; k0 < K; k0 += 16){
    float4 va = make_float4(0,0,0,0), vb = make_float4(0,0,0,0);
    int gm = m0 + r, gn = n0 + r, gk = k0 + kq;
    if (gm < M) va = *(const float4*)(A  + (size_t)gm*K + gk);
    if (gn < N) vb = *(const float4*)(Bm + (size_t)gn*K + gk);
    As[kq+0][r]=va.x; As[kq+1][r]=va.y; As[kq+2][r]=va.z; As[kq+3][r]=va.w;
    Bs[kq+0][r]=vb.x; Bs[kq+1][r]=vb.y; Bs[kq+2][r]=vb.z; Bs[kq+3][r]=vb.w;
    __syncthreads();
    #pragma unroll
    for (int k = 0; k < 16; k++){
      float a[4], b[4];
      #pragma unroll
      for (int i = 0; i < 4; i++) a[i] = As[k][ty*4+i];
      #pragma unroll
      for (int j = 0; j < 4; j++) b[j] = Bs[k][tx*4+j];
      #pragma unroll
      for (int i = 0; i < 4; i++)
        #pragma unroll
        for (int j = 0; j < 4; j++) acc[i][j] = fmaf(a[i], b[j], acc[i][j]);
    }
    __syncthreads();
  }
  #pragma unroll
  for (int i = 0; i < 4; i++){
    int m = m0 + ty*4 + i;
    if (m >= M) continue;
    float rs = rowscale ? rowscale[m] : 1.f;
    #pragma unroll
    for (int j = 0; j < 4; j++){
      int n = n0 + tx*4 + j;
      if (n >= N) continue;
      float v = acc[i][j] * rs;
      if (colscale) v *= colscale[n];
      if (bias1)    v += bias1[n];
      if (bias2)    v += bias2[n];
      C[(size_t)m*N + n] = v;
    }
  }
}

// LSTM gate activation: h from g (B x 4096), torch gate order i,f,g,o; c0=h0=0
__global__ void k_lstm(const float* __restrict__ g, float* __restrict__ h){
  int idx = blockIdx.x*256 + threadIdx.x;    // 256*1024
  int b = idx >> 10, j = idx & 1023;
  const float* gr = g + (size_t)b*4096;
  float c = sigm(gr[j]) * tanhf(gr[2048 + j]);
  h[idx] = sigm(gr[3072 + j]) * tanhf(c);
}

// block reduce over 128 threads (2 waves), result broadcast to all threads
DEVI float blockReduce128(float v, float* lds2){
  #pragma unroll
  for (int o = 32; o > 0; o >>= 1) v += __shfl_xor(v, o);
  int w = threadIdx.x >> 6;
  __syncthreads();
  if ((threadIdx.x & 63) == 0) lds2[w] = v;
  __syncthreads();
  return lds2[0] + lds2[1];
}

// parse interface vector itf (B x 787) into all components
__global__ __launch_bounds__(128) void k_parse(const float* __restrict__ itf,
    float* __restrict__ wv, float* __restrict__ ev, float* __restrict__ av,
    float* __restrict__ wg_, float* __restrict__ ag_, float* __restrict__ invwv,
    float* __restrict__ rm0, float* __restrict__ rm1, float* __restrict__ rm2,
    float* __restrict__ rks)
{
  __shared__ float red[2];
  int b = blockIdx.x, t = threadIdx.x;
  const float* it = itf + (size_t)b*787;
  float wg = sigm(it[256]);
  float ag = sigm(it[257]);
  if (t == 0){ wg_[b] = wg; ag_[b] = ag; }
  float w = it[t];                       // write value
  wv[b*128 + t] = w;
  av[b*128 + t] = w * wg;
  ev[b*128 + t] = sigm(it[128 + t]) * wg;
  float ss = blockReduce128(w*w, red);
  if (t == 0) invwv[b] = 1.f / fmaxf(sqrtf(ss), 1e-12f);
  if (t < 4){
    int rr = t;
    float m0v = it[259 + rr*3 + 0], m1v = it[259 + rr*3 + 1], m2v = it[259 + rr*3 + 2];
    float mx = fmaxf(m0v, fmaxf(m1v, m2v));
    float e0 = expf(m0v - mx), e1 = expf(m1v - mx), e2 = expf(m2v - mx);
    float inv = 1.f / (e0 + e1 + e2);
    rm0[b*4 + rr] = e0*inv; rm1[b*4 + rr] = e1*inv; rm2[b*4 + rr] = e2*inv;
  }
  #pragma unroll
  for (int rr = 0; rr < 4; rr++){
    float kv = it[275 + rr*128 + t];
    float ks = blockReduce128(kv*kv, red);
    float sx = it[271 + rr];
    float str = fmaxf(sx, 0.f) + log1pf(expf(-fabsf(sx)));  // softplus
    float invk = 1.f / fmaxf(sqrtf(ks), 1e-12f);
    rks[((size_t)b*4 + rr)*128 + t] = kv * invk * str;      // normalized key * strength
  }
}

// allocation weighting, sort-free: alloc[n] = u[n] * prod_{m stably-before n}(1-u[m])
__global__ __launch_bounds__(256) void k_alloc(const float* __restrict__ usage, float* __restrict__ out){
  __shared__ float u[2048];
  int t = threadIdx.x;
  for (int i = t; i < 2048; i += 256) u[i] = usage[i];
  __syncthreads();
  int n = blockIdx.x*256 + t;
  float un = u[n];
  float prod = 1.f;
  for (int m = 0; m < 2048; m++){
    float um = u[m];
    bool before = (um < un) || (um == un && m < n);
    prod *= before ? (1.f - um) : 1.f;
  }
  out[n] = un * prod;
}

// in-place row softmax, rows of length 2048, one block (256 thr) per row
__global__ __launch_bounds__(256) void k_softmax2048(float* __restrict__ P){
  __shared__ float red[4];
  float* p = P + (size_t)blockIdx.x*2048;
  int t = threadIdx.x;
  float r[8];
  float mx = -3.4e38f;
  #pragma unroll
  for (int i = 0; i < 8; i++){ r[i] = p[t + i*256]; mx = fmaxf(mx, r[i]); }
  #pragma unroll
  for (int o = 32; o > 0; o >>= 1) mx = fmaxf(mx, __shfl_xor(mx, o));
  if ((t & 63) == 0) red[t >> 6] = mx;
  __syncthreads();
  mx = fmaxf(fmaxf(red[0], red[1]), fmaxf(red[2], red[3]));
  float s = 0.f;
  #pragma unroll
  for (int i = 0; i < 8; i++){ r[i] = expf(r[i] - mx); s += r[i]; }
  #pragma unroll
  for (int o = 32; o > 0; o >>= 1) s += __shfl_xor(s, o);
  __syncthreads();
  if ((t & 63) == 0) red[t >> 6] = s;
  __syncthreads();
  s = red[0] + red[1] + red[2] + red[3];
  float inv = 1.f / s;
  #pragma unroll
  for (int i = 0; i < 8; i++) p[t + i*256] = r[i]*inv;
}

// ww[b,n] = wg[b] * (0.5*cw[b,n] + 0.5*alloc[n]*ag[b])   (in place over cw)
__global__ void k_writew(float* __restrict__ cw, const float* __restrict__ alloc,
                         const float* __restrict__ wg, const float* __restrict__ ag){
  int idx = blockIdx.x*256 + threadIdx.x;  // 256*2048
  int b = idx >> 11, n = idx & 2047;
  cw[idx] = wg[b] * (0.5f*cw[idx] + 0.5f*alloc[n]*ag[b]);
}

// generic row sums (wave per row)
__global__ void k_rowsum(const float* __restrict__ A, float* __restrict__ out, int rows, int cols){
  int w = (blockIdx.x*blockDim.x + threadIdx.x) >> 6;
  int lane = threadIdx.x & 63;
  if (w >= rows) return;
  const float* a = A + (size_t)w*cols;
  float s = 0.f;
  for (int c = lane; c < cols; c += 64) s += a[c];
  #pragma unroll
  for (int o = 32; o > 0; o >>= 1) s += __shfl_down(s, o);
  if (lane == 0) out[w] = s;
}

// column sums of a (2048 x 2048) matrix via partial + atomicAdd (out must be zeroed)
__global__ void k_colsum2048(const float* __restrict__ A, float* __restrict__ out){
  int c = blockIdx.x*256 + threadIdx.x;
  int r0 = blockIdx.y*128;
  float s = 0.f;
  for (int rr = 0; rr < 128; rr++) s += A[(size_t)(r0+rr)*2048 + c];
  atomicAdd(&out[c], s);
}

// bw[m] = (0.9*colsum_link[m] + 0.1*lusum[m]) / N ; fw with rowsum_link. lu symmetric.
__global__ void k_bwfw(const float* __restrict__ ww, const float* __restrict__ tb,
                       const float* __restrict__ rowsum, const float* __restrict__ colsum,
                       float* __restrict__ bw, float* __restrict__ fw){
  int m = blockIdx.x*256 + threadIdx.x;   // 8 blocks
  float q = 0.f, dd = 0.f;
  for (int b = 0; b < 256; b++){
    float w = ww[(size_t)b*2048 + m];
    q  = fmaf(tb[b], w, q);
    dd = fmaf(w, w, dd);
  }
  float lus = (q - dd) * (1.f/256.f);     // colsum(lu)[m] - lu[m,m]
  bw[m] = (0.9f*colsum[m] + 0.1f*lus) * (1.f/2048.f);
  fw[m] = (0.9f*rowsum[m] + 0.1f*lus) * (1.f/2048.f);
}

// mem_new = memory*(1 - ww^T@ev/B) + ww^T@av/B   (TN gemm, M=2048 n, N=128 d, K=256 b)
__global__ __launch_bounds__(256) void k_memupdate(const float* __restrict__ ww,
    const float* __restrict__ ev, const float* __restrict__ av,
    const float* __restrict__ mem, float* __restrict__ memn)
{
  __shared__ float Ws[16][68], Es[16][68], Vs[16][68];
  int m0 = blockIdx.y*64, n0 = blockIdx.x*64;
  int tid = threadIdx.x, tx = tid & 15, ty = tid >> 4;
  int kk = tid >> 4, col = (tid & 15) << 2;
  float ae[4][4] = {}, aa[4][4] = {};
  for (int k0 = 0; k0 < 256; k0 += 16){
    float4 vw  = *(const float4*)(ww + (size_t)(k0+kk)*2048 + m0 + col);
    float4 vev = *(const float4*)(ev + (size_t)(k0+kk)*128  + n0 + col);
    float4 vav = *(const float4*)(av + (size_t)(k0+kk)*128  + n0 + col);
    Ws[kk][col]=vw.x;  Ws[kk][col+1]=vw.y;  Ws[kk][col+2]=vw.z;  Ws[kk][col+3]=vw.w;
    Es[kk][col]=vev.x; Es[kk][col+1]=vev.y; Es[kk][col+2]=vev.z; Es[kk][col+3]=vev.w;
    Vs[kk][col]=vav.x; Vs[kk][col+1]=vav.y; Vs[kk][col+2]=vav.z; Vs[kk][col+3]=vav.w;
    __syncthreads();
    #pragma unroll
    for (int k = 0; k < 16; k++){
      float a[4], e[4], v[4];
      #pragma unroll
      for (int i = 0; i < 4; i++) a[i] = Ws[k][ty*4+i];
      #pragma unroll
      for (int j = 0; j < 4; j++){ e[j] = Es[k][tx*4+j]; v[j] = Vs[k][tx*4+j]; }
      #pragma unroll
      for (int i = 0; i < 4; i++)
        #pragma unroll
        for (int j = 0; j < 4; j++){
          ae[i][j] = fmaf(a[i], e[j], ae[i][j]);
          aa[i][j] = fmaf(a[i], v[j], aa[i][j]);
        }
    }
    __syncthreads();
  }
  #pragma unroll
  for (int i = 0; i < 4; i++){
    int n = m0 + ty*4 + i;
    #pragma unroll
    for (int j = 0; j < 4; j++){
      int d = n0 + tx*4 + j;
      float em = ae[i][j] * (1.f/256.f);
      float am = aa[i][j] * (1.f/256.f);
      memn[(size_t)n*128 + d] = mem[(size_t)n*128 + d] * (1.f - em) + am;
    }
  }
}

// bwm[d] = sum_n bw[n]*mem_new[n,d]; fwm likewise  (single block)
__global__ __launch_bounds__(1024) void k_bwmfwm(const float* __restrict__ memn,
    const float* __restrict__ bw, const float* __restrict__ fw,
    float* __restrict__ bwm, float* __restrict__ fwm)
{
  __shared__ float sb[8][128], sf[8][128];
  int d = threadIdx.x & 127, g = threadIdx.x >> 7;
  float ab = 0.f, af = 0.f;
  for (int n = g; n < 2048; n += 8){
    float m = memn[(size_t)n*128 + d];
    ab = fmaf(bw[n], m, ab);
    af = fmaf(fw[n], m, af);
  }
  sb[g][d] = ab; sf[g][d] = af;
  __syncthreads();
  if (g == 0){
    float s1 = 0.f, s2 = 0.f;
    #pragma unroll
    for (int i = 0; i < 8; i++){ s1 += sb[i][d]; s2 += sf[i][d]; }
    bwm[d] = s1; fwm[d] = s2;
  }
}

// read_out[row,d] = rm0[row]*(P[row,:]@mem_new)[d] + rm1[row]*bwm[d] + rm2[row]*fwm[d]
__global__ __launch_bounds__(128) void k_readout(const float* __restrict__ P,
    const float* __restrict__ memn, const float* __restrict__ rm0, const float* __restrict__ rm1,
    const float* __restrict__ rm2, const float* __restrict__ bwm, const float* __restrict__ fwm,
    float* __restrict__ ro)
{
  __shared__ float Ps[4][128];
  int r0 = blockIdx.x*4, d = threadIdx.x;
  float acc[4] = {0.f, 0.f, 0.f, 0.f};
  for (int nc = 0; nc < 2048; nc += 128){
    #pragma unroll
    for (int rr = 0; rr < 4; rr++) Ps[rr][d] = P[(size_t)(r0+rr)*2048 + nc + d];
    __syncthreads();
    #pragma unroll 8
    for (int n = 0; n < 128; n++){
      float m = memn[(size_t)(nc+n)*128 + d];
      #pragma unroll
      for (int rr = 0; rr < 4; rr++) acc[rr] = fmaf(Ps[rr][n], m, acc[rr]);
    }
    __syncthreads();
  }
  #pragma unroll
  for (int rr = 0; rr < 4; rr++){
    int row = r0 + rr;
    ro[(size_t)row*128 + d] = rm0[row]*acc[rr] + rm1[row]*bwm[d] + rm2[row]*fwm[d];
  }
}

// hro = concat(h, read_out) per batch row
__global__ void k_hro(const float* __restrict__ h, const float* __restrict__ ro, float* __restrict__ hro){
  int idx = blockIdx.x*256 + threadIdx.x;   // 256*1536
  int b = idx / 1536, k = idx - b*1536;
  hro[idx] = (k < 1024) ? h[b*1024 + k] : ro[b*512 + k - 1024];
}

// ---------------- launcher ----------------

extern "C" void kernel_launch(void* const* d_in, const int* in_sizes, int n_in,
                              void* d_out, int out_size, void* d_ws, size_t ws_size,
                              hipStream_t stream)
{
  const float* x     = (const float*)d_in[0];
  const float* mem   = (const float*)d_in[1];
  const float* usage = (const float*)d_in[2];
  const float* link  = (const float*)d_in[3];
  const float* W_ih  = (const float*)d_in[4];
  // d_in[5] = W_hh: unused (h0 = 0)
  const float* b_ih  = (const float*)d_in[6];
  const float* b_hh  = (const float*)d_in[7];
  const float* W_if  = (const float*)d_in[8];
  const float* b_if  = (const float*)d_in[9];
  const float* W_out = (const float*)d_in[10];
  const float* b_out = (const float*)d_in[11];
  float* out = (float*)d_out;
  float* ws  = (float*)d_ws;

  float* cm     = ws + 0;         // 128
  float* rn_mem = ws + 128;       // 2048
  float* rn_new = ws + 2176;      // 2048
  float* rsl    = ws + 4224;      // 2048 rowsum(link)
  float* csl    = ws + 6272;      // 2048 colsum(link)
  float* tb     = ws + 8320;      // 256
  float* bw     = ws + 8576;      // 2048
  float* fw     = ws + 10624;     // 2048
  float* bwm    = ws + 12672;     // 128
  float* fwm    = ws + 12800;     // 128
  float* wg     = ws + 12928;     // 256
  float* ag     = ws + 13184;     // 256
  float* invwv  = ws + 13440;     // 256
  float* rm0    = ws + 13696;     // 1024
  float* rm1    = ws + 14720;     // 1024
  float* rm2    = ws + 15744;     // 1024
  float* alloc  = ws + 16768;     // 2048
  float* wv     = ws + 18816;     // 32768  (B x 128)
  float* ev     = ws + 51584;     // 32768
  float* av     = ws + 84352;     // 32768
  float* rks    = ws + 117120;    // 131072 (B*R x 128)
  float* cin    = ws + 248192;    // 393216 (B x 1536)
  float* g      = ws + 641408;    // 1048576 (B x 4096)
  float* h      = ws + 1689984;   // 262144 (B x 1024)
  float* itf    = ws + 1952128;   // 201472 (B x 787)
  float* ww     = ws + 2153856;   // 524288 (B x 2048): cw logits -> cw -> write_w
  float* memn   = ws + 2678144;   // 262144 (2048 x 128)
  float* sim    = ws + 2940288;   // 2097152 (B*R x 2048): logits -> softmax P
  float* ro     = ws + 5037440;   // 131072 (B x R*D)
  float* hro    = ws + 5168512;   // 393216 (B x 1536)
  // total = 5,561,728 floats = 22.2 MB

  // stage 1: controller input
  k_colmean   <<<1, 1024, 0, stream>>>(mem, cm);
  k_rownorm128<<<512, 256, 0, stream>>>(mem, rn_mem, 2048);
  k_cin       <<<1536, 256, 0, stream>>>(x, cm, cin);

  // stage 2: LSTM controller
  gemm_nt<<<dim3(64,4), 256, 0, stream>>>(cin, W_ih, g, 256, 4096, 1536, b_ih, b_hh, nullptr, nullptr);
  k_lstm <<<1024, 256, 0, stream>>>(g, h);

  // stage 3: interface
  gemm_nt<<<dim3(13,4), 256, 0, stream>>>(h, W_if, itf, 256, 787, 1024, b_if, nullptr, nullptr, nullptr);
  k_parse<<<256, 128, 0, stream>>>(itf, wv, ev, av, wg, ag, invwv, rm0, rm1, rm2, rks);

  // stage 4: write weighting
  k_alloc<<<8, 256, 0, stream>>>(usage, alloc);
  gemm_nt<<<dim3(32,4), 256, 0, stream>>>(wv, mem, ww, 256, 2048, 128, nullptr, nullptr, invwv, rn_mem);
  k_softmax2048<<<256, 256, 0, stream>>>(ww);
  k_writew<<<2048, 256, 0, stream>>>(ww, alloc, wg, ag);

  // stage 5: link-derived read vectors (link_new never materialized)
  k_rowsum<<<512, 256, 0, stream>>>(link, rsl, 2048, 2048);
  k_zero  <<<8, 256, 0, stream>>>(csl, 2048);
  k_colsum2048<<<dim3(8,16), 256, 0, stream>>>(link, csl);
  k_rowsum<<<64, 256, 0, stream>>>(ww, tb, 256, 2048);
  k_bwfw  <<<8, 256, 0, stream>>>(ww, tb, rsl, csl, bw, fw);

  // stage 6: memory update
  k_memupdate <<<dim3(2,32), 256, 0, stream>>>(ww, ev, av, mem, memn);
  k_rownorm128<<<512, 256, 0, stream>>>(memn, rn_new, 2048);
  k_bwmfwm    <<<1, 1024, 0, stream>>>(memn, bw, fw, bwm, fwm);

  // stage 7: read addressing + read output
  gemm_nt<<<dim3(32,16), 256, 0, stream>>>(rks, memn, sim, 1024, 2048, 128, nullptr, nullptr, nullptr, rn_new);
  k_softmax2048<<<1024, 256, 0, stream>>>(sim);
  k_readout<<<256, 128, 0, stream>>>(sim, memn, rm0, rm1, rm2, bwm, fwm, ro);

  // stage 8: output projection
  k_hro  <<<1536, 256, 0, stream>>>(h, ro, hro);
  gemm_nt<<<dim3(16,4), 256, 0, stream>>>(hro, W_out, out, 256, 1024, 1536, b_out, nullptr, nullptr, nullptr);

  (void)in_sizes; (void)n_in; (void)out_size; (void)ws_size;
}

// Round 2
// 732.830 us; speedup vs baseline: 1.1747x; 1.1747x over previous
//
#include <hip/hip_runtime.h>
#include <cmath>

#define DEVI __device__ __forceinline__

DEVI float sigm(float x){ return 1.f/(1.f+expf(-x)); }

// ---------------- small utility kernels ----------------

__global__ void k_zero(float* __restrict__ p, int n){
  int i = blockIdx.x*256 + threadIdx.x;
  if (i < n) p[i] = 0.f;
}

// column mean of memory (2048 x 128) -> cm[128]
__global__ __launch_bounds__(1024) void k_colmean(const float* __restrict__ mem, float* __restrict__ cm){
  __shared__ float s[8][128];
  int d = threadIdx.x & 127, g = threadIdx.x >> 7;
  float a = 0.f;
  for (int n = g; n < 2048; n += 8) a += mem[(size_t)n*128 + d];
  s[g][d] = a;
  __syncthreads();
  if (g == 0){
    float t = 0.f;
    #pragma unroll
    for (int i = 0; i < 8; i++) t += s[i][d];
    cm[d] = t * (1.f/2048.f);
  }
}

// inverse L2 norm of each 128-wide row (wave per row)
__global__ __launch_bounds__(256) void k_rownorm128(const float* __restrict__ A, float* __restrict__ invn, int rows){
  int w = (blockIdx.x*blockDim.x + threadIdx.x) >> 6;
  int lane = threadIdx.x & 63;
  if (w >= rows) return;
  const float* a = A + (size_t)w*128;
  float x0 = a[lane], x1 = a[lane+64];
  float s = x0*x0 + x1*x1;
  #pragma unroll
  for (int o = 32; o > 0; o >>= 1) s += __shfl_down(s, o);
  if (lane == 0) invn[w] = 1.f / fmaxf(sqrtf(s), 1e-12f);
}

// cin[b,k] = k<1024 ? x[b,k] : cm[(k-1024)%128]
__global__ void k_cin(const float* __restrict__ x, const float* __restrict__ cm, float* __restrict__ cin){
  int idx = blockIdx.x*256 + threadIdx.x;     // 256*1536
  int b = idx / 1536, k = idx - b*1536;
  cin[idx] = (k < 1024) ? x[b*1024 + k] : cm[(k-1024) & 127];
}

// ---------------- generic NT GEMM: C[M,N] = A[M,K] @ B[N,K]^T (epilogue opts) ----------------
// K must be a multiple of 16. 64x64 tile, 256 threads, 4x4 microtile.
__global__ __launch_bounds__(256) void gemm_nt(
    const float* __restrict__ A, const float* __restrict__ Bm, float* __restrict__ C,
    int M, int N, int K,
    const float* __restrict__ bias1, const float* __restrict__ bias2,
    const float* __restrict__ rowscale, const float* __restrict__ colscale)
{
  __shared__ float As[16][68];
  __shared__ float Bs[16][68];
  const int m0 = blockIdx.y*64, n0 = blockIdx.x*64;
  const int tid = threadIdx.x;
  const int tx = tid & 15, ty = tid >> 4;
  const int r = tid >> 2, kq = (tid & 3) << 2;
  float acc[4][4] = {};
  for (int k0 = 0; k0 < K; k0 += 16){
    float4 va = make_float4(0,0,0,0), vb = make_float4(0,0,0,0);
    int gm = m0 + r, gn = n0 + r, gk = k0 + kq;
    if (gm < M) va = *(const float4*)(A  + (size_t)gm*K + gk);
    if (gn < N) vb = *(const float4*)(Bm + (size_t)gn*K + gk);
    As[kq+0][r]=va.x; As[kq+1][r]=va.y; As[kq+2][r]=va.z; As[kq+3][r]=va.w;
    Bs[kq+0][r]=vb.x; Bs[kq+1][r]=vb.y; Bs[kq+2][r]=vb.z; Bs[kq+3][r]=vb.w;
    __syncthreads();
    #pragma unroll
    for (int k = 0; k < 16; k++){
      float a[4], b[4];
      #pragma unroll
      for (int i = 0; i < 4; i++) a[i] = As[k][ty*4+i];
      #pragma unroll
      for (int j = 0; j < 4; j++) b[j] = Bs[k][tx*4+j];
      #pragma unroll
      for (int i = 0; i < 4; i++)
        #pragma unroll
        for (int j = 0; j < 4; j++) acc[i][j] = fmaf(a[i], b[j], acc[i][j]);
    }
    __syncthreads();
  }
  #pragma unroll
  for (int i = 0; i < 4; i++){
    int m = m0 + ty*4 + i;
    if (m >= M) continue;
    float rs = rowscale ? rowscale[m] : 1.f;
    #pragma unroll
    for (int j = 0; j < 4; j++){
      int n = n0 + tx*4 + j;
      if (n >= N) continue;
      float v = acc[i][j] * rs;
      if (colscale) v *= colscale[n];
      if (bias1)    v += bias1[n];
      if (bias2)    v += bias2[n];
      C[(size_t)m*N + n] = v;
    }
  }
}

// LSTM gate activation: h from g (B x 4096), torch gate order i,f,g,o; c0=h0=0
__global__ void k_lstm(const float* __restrict__ g, float* __restrict__ h){
  int idx = blockIdx.x*256 + threadIdx.x;    // 256*1024
  int b = idx >> 10, j = idx & 1023;
  const float* gr = g + (size_t)b*4096;
  float c = sigm(gr[j]) * tanhf(gr[2048 + j]);
  h[idx] = sigm(gr[3072 + j]) * tanhf(c);
}

// block reduce over 128 threads (2 waves), result broadcast to all threads
DEVI float blockReduce128(float v, float* lds2){
  #pragma unroll
  for (int o = 32; o > 0; o >>= 1) v += __shfl_xor(v, o);
  int w = threadIdx.x >> 6;
  __syncthreads();
  if ((threadIdx.x & 63) == 0) lds2[w] = v;
  __syncthreads();
  return lds2[0] + lds2[1];
}

// parse interface vector itf (B x 787) into all components
__global__ __launch_bounds__(128) void k_parse(const float* __restrict__ itf,
    float* __restrict__ wv, float* __restrict__ ev, float* __restrict__ av,
    float* __restrict__ wg_, float* __restrict__ ag_, float* __restrict__ invwv,
    float* __restrict__ rm0, float* __restrict__ rm1, float* __restrict__ rm2,
    float* __restrict__ rks)
{
  __shared__ float red[2];
  int b = blockIdx.x, t = threadIdx.x;
  const float* it = itf + (size_t)b*787;
  float wg = sigm(it[256]);
  float ag = sigm(it[257]);
  if (t == 0){ wg_[b] = wg; ag_[b] = ag; }
  float w = it[t];                       // write value
  wv[b*128 + t] = w;
  av[b*128 + t] = w * wg;
  ev[b*128 + t] = sigm(it[128 + t]) * wg;
  float ss = blockReduce128(w*w, red);
  if (t == 0) invwv[b] = 1.f / fmaxf(sqrtf(ss), 1e-12f);
  if (t < 4){
    int rr = t;
    float m0v = it[259 + rr*3 + 0], m1v = it[259 + rr*3 + 1], m2v = it[259 + rr*3 + 2];
    float mx = fmaxf(m0v, fmaxf(m1v, m2v));
    float e0 = expf(m0v - mx), e1 = expf(m1v - mx), e2 = expf(m2v - mx);
    float inv = 1.f / (e0 + e1 + e2);
    rm0[b*4 + rr] = e0*inv; rm1[b*4 + rr] = e1*inv; rm2[b*4 + rr] = e2*inv;
  }
  #pragma unroll
  for (int rr = 0; rr < 4; rr++){
    float kv = it[275 + rr*128 + t];
    float ks = blockReduce128(kv*kv, red);
    float sx = it[271 + rr];
    float str = fmaxf(sx, 0.f) + log1pf(expf(-fabsf(sx)));  // softplus
    float invk = 1.f / fmaxf(sqrtf(ks), 1e-12f);
    rks[((size_t)b*4 + rr)*128 + t] = kv * invk * str;      // normalized key * strength
  }
}

// allocation weighting, sort-free: alloc[n] = u[n] * prod_{m stably-before n}(1-u[m])
// one block per n; 256 threads do a strided partial product + multiply-reduce.
__global__ __launch_bounds__(256) void k_alloc(const float* __restrict__ usage, float* __restrict__ out){
  __shared__ float red[4];
  int n = blockIdx.x, t = threadIdx.x;
  float un = usage[n];
  float prod = 1.f;
  #pragma unroll
  for (int i = 0; i < 8; i++){
    int m = t + i*256;
    float um = usage[m];
    bool before = (um < un) || (um == un && m < n);
    prod *= before ? (1.f - um) : 1.f;
  }
  #pragma unroll
  for (int o = 32; o > 0; o >>= 1) prod *= __shfl_xor(prod, o);
  if ((t & 63) == 0) red[t >> 6] = prod;
  __syncthreads();
  if (t == 0) out[n] = un * (red[0]*red[1]) * (red[2]*red[3]);
}

// in-place row softmax, rows of length 2048, one block (256 thr) per row
__global__ __launch_bounds__(256) void k_softmax2048(float* __restrict__ P){
  __shared__ float red[4];
  float* p = P + (size_t)blockIdx.x*2048;
  int t = threadIdx.x;
  float r[8];
  float mx = -3.4e38f;
  #pragma unroll
  for (int i = 0; i < 8; i++){ r[i] = p[t + i*256]; mx = fmaxf(mx, r[i]); }
  #pragma unroll
  for (int o = 32; o > 0; o >>= 1) mx = fmaxf(mx, __shfl_xor(mx, o));
  if ((t & 63) == 0) red[t >> 6] = mx;
  __syncthreads();
  mx = fmaxf(fmaxf(red[0], red[1]), fmaxf(red[2], red[3]));
  float s = 0.f;
  #pragma unroll
  for (int i = 0; i < 8; i++){ r[i] = expf(r[i] - mx); s += r[i]; }
  #pragma unroll
  for (int o = 32; o > 0; o >>= 1) s += __shfl_xor(s, o);
  __syncthreads();
  if ((t & 63) == 0) red[t >> 6] = s;
  __syncthreads();
  s = red[0] + red[1] + red[2] + red[3];
  float inv = 1.f / s;
  #pragma unroll
  for (int i = 0; i < 8; i++) p[t + i*256] = r[i]*inv;
}

// ww[b,n] = wg[b] * (0.5*cw[b,n] + 0.5*alloc[n]*ag[b])   (in place over cw)
__global__ void k_writew(float* __restrict__ cw, const float* __restrict__ alloc,
                         const float* __restrict__ wg, const float* __restrict__ ag){
  int idx = blockIdx.x*256 + threadIdx.x;  // 256*2048
  int b = idx >> 11, n = idx & 2047;
  cw[idx] = wg[b] * (0.5f*cw[idx] + 0.5f*alloc[n]*ag[b]);
}

// generic row sums (wave per row)
__global__ void k_rowsum(const float* __restrict__ A, float* __restrict__ out, int rows, int cols){
  int w = (blockIdx.x*blockDim.x + threadIdx.x) >> 6;
  int lane = threadIdx.x & 63;
  if (w >= rows) return;
  const float* a = A + (size_t)w*cols;
  float s = 0.f;
  for (int c = lane; c < cols; c += 64) s += a[c];
  #pragma unroll
  for (int o = 32; o > 0; o >>= 1) s += __shfl_down(s, o);
  if (lane == 0) out[w] = s;
}

// column sums of a (2048 x 2048) matrix via partial + atomicAdd (out must be zeroed)
__global__ void k_colsum2048(const float* __restrict__ A, float* __restrict__ out){
  int c = blockIdx.x*256 + threadIdx.x;
  int r0 = blockIdx.y*128;
  float s = 0.f;
  for (int rr = 0; rr < 128; rr++) s += A[(size_t)(r0+rr)*2048 + c];
  atomicAdd(&out[c], s);
}

// bw[m] = (0.9*colsum_link[m] + 0.1*lusum[m]) / N ; fw with rowsum_link. lu symmetric.
// 1024 threads: 4-way batch split (z) + LDS reduce, 256 m-columns per block.
__global__ __launch_bounds__(1024) void k_bwfw(const float* __restrict__ ww, const float* __restrict__ tb,
                       const float* __restrict__ rowsum, const float* __restrict__ colsum,
                       float* __restrict__ bw, float* __restrict__ fw){
  __shared__ float sq[4][256], sd[4][256];
  int t = threadIdx.x & 255, z = threadIdx.x >> 8;
  int m = blockIdx.x*256 + t;   // 8 blocks
  float q = 0.f, dd = 0.f;
  for (int b = z*64; b < z*64 + 64; b++){
    float w = ww[(size_t)b*2048 + m];
    q  = fmaf(tb[b], w, q);
    dd = fmaf(w, w, dd);
  }
  sq[z][t] = q; sd[z][t] = dd;
  __syncthreads();
  if (z == 0){
    q  = sq[0][t] + sq[1][t] + sq[2][t] + sq[3][t];
    dd = sd[0][t] + sd[1][t] + sd[2][t] + sd[3][t];
    float lus = (q - dd) * (1.f/256.f);     // colsum(lu)[m] - lu[m,m]
    bw[m] = (0.9f*colsum[m] + 0.1f*lus) * (1.f/2048.f);
    fw[m] = (0.9f*rowsum[m] + 0.1f*lus) * (1.f/2048.f);
  }
}

// mem_new = memory*(1 - ww^T@ev/B) + ww^T@av/B   (TN gemm, M=2048 n, N=128 d, K=256 b)
__global__ __launch_bounds__(256) void k_memupdate(const float* __restrict__ ww,
    const float* __restrict__ ev, const float* __restrict__ av,
    const float* __restrict__ mem, float* __restrict__ memn)
{
  __shared__ float Ws[16][68], Es[16][68], Vs[16][68];
  int m0 = blockIdx.y*64, n0 = blockIdx.x*64;
  int tid = threadIdx.x, tx = tid & 15, ty = tid >> 4;
  int kk = tid >> 4, col = (tid & 15) << 2;
  float ae[4][4] = {}, aa[4][4] = {};
  for (int k0 = 0; k0 < 256; k0 += 16){
    float4 vw  = *(const float4*)(ww + (size_t)(k0+kk)*2048 + m0 + col);
    float4 vev = *(const float4*)(ev + (size_t)(k0+kk)*128  + n0 + col);
    float4 vav = *(const float4*)(av + (size_t)(k0+kk)*128  + n0 + col);
    Ws[kk][col]=vw.x;  Ws[kk][col+1]=vw.y;  Ws[kk][col+2]=vw.z;  Ws[kk][col+3]=vw.w;
    Es[kk][col]=vev.x; Es[kk][col+1]=vev.y; Es[kk][col+2]=vev.z; Es[kk][col+3]=vev.w;
    Vs[kk][col]=vav.x; Vs[kk][col+1]=vav.y; Vs[kk][col+2]=vav.z; Vs[kk][col+3]=vav.w;
    __syncthreads();
    #pragma unroll
    for (int k = 0; k < 16; k++){
      float a[4], e[4], v[4];
      #pragma unroll
      for (int i = 0; i < 4; i++) a[i] = Ws[k][ty*4+i];
      #pragma unroll
      for (int j = 0; j < 4; j++){ e[j] = Es[k][tx*4+j]; v[j] = Vs[k][tx*4+j]; }
      #pragma unroll
      for (int i = 0; i < 4; i++)
        #pragma unroll
        for (int j = 0; j < 4; j++){
          ae[i][j] = fmaf(a[i], e[j], ae[i][j]);
          aa[i][j] = fmaf(a[i], v[j], aa[i][j]);
        }
    }
    __syncthreads();
  }
  #pragma unroll
  for (int i = 0; i < 4; i++){
    int n = m0 + ty*4 + i;
    #pragma unroll
    for (int j = 0; j < 4; j++){
      int d = n0 + tx*4 + j;
      float em = ae[i][j] * (1.f/256.f);
      float am = aa[i][j] * (1.f/256.f);
      memn[(size_t)n*128 + d] = mem[(size_t)n*128 + d] * (1.f - em) + am;
    }
  }
}

// bwm[d] = sum_n bw[n]*mem_new[n,d]; fwm likewise  (single block)
__global__ __launch_bounds__(1024) void k_bwmfwm(const float* __restrict__ memn,
    const float* __restrict__ bw, const float* __restrict__ fw,
    float* __restrict__ bwm, float* __restrict__ fwm)
{
  __shared__ float sb[8][128], sf[8][128];
  int d = threadIdx.x & 127, g = threadIdx.x >> 7;
  float ab = 0.f, af = 0.f;
  for (int n = g; n < 2048; n += 8){
    float m = memn[(size_t)n*128 + d];
    ab = fmaf(bw[n], m, ab);
    af = fmaf(fw[n], m, af);
  }
  sb[g][d] = ab; sf[g][d] = af;
  __syncthreads();
  if (g == 0){
    float s1 = 0.f, s2 = 0.f;
    #pragma unroll
    for (int i = 0; i < 8; i++){ s1 += sb[i][d]; s2 += sf[i][d]; }
    bwm[d] = s1; fwm[d] = s2;
  }
}

// read_out[row,d] = rm0[row]*(P[row,:]@mem_new)[d] + rm1[row]*bwm[d] + rm2[row]*fwm[d]
__global__ __launch_bounds__(128) void k_readout(const float* __restrict__ P,
    const float* __restrict__ memn, const float* __restrict__ rm0, const float* __restrict__ rm1,
    const float* __restrict__ rm2, const float* __restrict__ bwm, const float* __restrict__ fwm,
    float* __restrict__ ro)
{
  __shared__ float Ps[4][128];
  int r0 = blockIdx.x*4, d = threadIdx.x;
  float acc[4] = {0.f, 0.f, 0.f, 0.f};
  for (int nc = 0; nc < 2048; nc += 128){
    #pragma unroll
    for (int rr = 0; rr < 4; rr++) Ps[rr][d] = P[(size_t)(r0+rr)*2048 + nc + d];
    __syncthreads();
    #pragma unroll 8
    for (int n = 0; n < 128; n++){
      float m = memn[(size_t)(nc+n)*128 + d];
      #pragma unroll
      for (int rr = 0; rr < 4; rr++) acc[rr] = fmaf(Ps[rr][n], m, acc[rr]);
    }
    __syncthreads();
  }
  #pragma unroll
  for (int rr = 0; rr < 4; rr++){
    int row = r0 + rr;
    ro[(size_t)row*128 + d] = rm0[row]*acc[rr] + rm1[row]*bwm[d] + rm2[row]*fwm[d];
  }
}

// hro = concat(h, read_out) per batch row
__global__ void k_hro(const float* __restrict__ h, const float* __restrict__ ro, float* __restrict__ hro){
  int idx = blockIdx.x*256 + threadIdx.x;   // 256*1536
  int b = idx / 1536, k = idx - b*1536;
  hro[idx] = (k < 1024) ? h[b*1024 + k] : ro[b*512 + k - 1024];
}

// ---------------- launcher ----------------

extern "C" void kernel_launch(void* const* d_in, const int* in_sizes, int n_in,
                              void* d_out, int out_size, void* d_ws, size_t ws_size,
                              hipStream_t stream)
{
  const float* x     = (const float*)d_in[0];
  const float* mem   = (const float*)d_in[1];
  const float* usage = (const float*)d_in[2];
  const float* link  = (const float*)d_in[3];
  const float* W_ih  = (const float*)d_in[4];
  // d_in[5] = W_hh: unused (h0 = 0)
  const float* b_ih  = (const float*)d_in[6];
  const float* b_hh  = (const float*)d_in[7];
  const float* W_if  = (const float*)d_in[8];
  const float* b_if  = (const float*)d_in[9];
  const float* W_out = (const float*)d_in[10];
  const float* b_out = (const float*)d_in[11];
  float* out = (float*)d_out;
  float* ws  = (float*)d_ws;

  float* cm     = ws + 0;         // 128
  float* rn_mem = ws + 128;       // 2048
  float* rn_new = ws + 2176;      // 2048
  float* rsl    = ws + 4224;      // 2048 rowsum(link)
  float* csl    = ws + 6272;      // 2048 colsum(link)
  float* tb     = ws + 8320;      // 256
  float* bw     = ws + 8576;      // 2048
  float* fw     = ws + 10624;     // 2048
  float* bwm    = ws + 12672;     // 128
  float* fwm    = ws + 12800;     // 128
  float* wg     = ws + 12928;     // 256
  float* ag     = ws + 13184;     // 256
  float* invwv  = ws + 13440;     // 256
  float* rm0    = ws + 13696;     // 1024
  float* rm1    = ws + 14720;     // 1024
  float* rm2    = ws + 15744;     // 1024
  float* alloc  = ws + 16768;     // 2048
  float* wv     = ws + 18816;     // 32768  (B x 128)
  float* ev     = ws + 51584;     // 32768
  float* av     = ws + 84352;     // 32768
  float* rks    = ws + 117120;    // 131072 (B*R x 128)
  float* cin    = ws + 248192;    // 393216 (B x 1536)
  float* g      = ws + 641408;    // 1048576 (B x 4096)
  float* h      = ws + 1689984;   // 262144 (B x 1024)
  float* itf    = ws + 1952128;   // 201472 (B x 787)
  float* ww     = ws + 2153856;   // 524288 (B x 2048): cw logits -> cw -> write_w
  float* memn   = ws + 2678144;   // 262144 (2048 x 128)
  float* sim    = ws + 2940288;   // 2097152 (B*R x 2048): logits -> softmax P
  float* ro     = ws + 5037440;   // 131072 (B x R*D)
  float* hro    = ws + 5168512;   // 393216 (B x 1536)
  // total = 5,561,728 floats = 22.2 MB

  // stage 1: controller input
  k_colmean   <<<1, 1024, 0, stream>>>(mem, cm);
  k_rownorm128<<<512, 256, 0, stream>>>(mem, rn_mem, 2048);
  k_cin       <<<1536, 256, 0, stream>>>(x, cm, cin);

  // stage 2: LSTM controller
  gemm_nt<<<dim3(64,4), 256, 0, stream>>>(cin, W_ih, g, 256, 4096, 1536, b_ih, b_hh, nullptr, nullptr);
  k_lstm <<<1024, 256, 0, stream>>>(g, h);

  // stage 3: interface
  gemm_nt<<<dim3(13,4), 256, 0, stream>>>(h, W_if, itf, 256, 787, 1024, b_if, nullptr, nullptr, nullptr);
  k_parse<<<256, 128, 0, stream>>>(itf, wv, ev, av, wg, ag, invwv, rm0, rm1, rm2, rks);

  // stage 4: write weighting
  k_alloc<<<2048, 256, 0, stream>>>(usage, alloc);
  gemm_nt<<<dim3(32,4), 256, 0, stream>>>(wv, mem, ww, 256, 2048, 128, nullptr, nullptr, invwv, rn_mem);
  k_softmax2048<<<256, 256, 0, stream>>>(ww);
  k_writew<<<2048, 256, 0, stream>>>(ww, alloc, wg, ag);

  // stage 5: link-derived read vectors (link_new never materialized)
  k_rowsum<<<512, 256, 0, stream>>>(link, rsl, 2048, 2048);
  k_zero  <<<8, 256, 0, stream>>>(csl, 2048);
  k_colsum2048<<<dim3(8,16), 256, 0, stream>>>(link, csl);
  k_rowsum<<<64, 256, 0, stream>>>(ww, tb, 256, 2048);
  k_bwfw  <<<8, 1024, 0, stream>>>(ww, tb, rsl, csl, bw, fw);

  // stage 6: memory update
  k_memupdate <<<dim3(2,32), 256, 0, stream>>>(ww, ev, av, mem, memn);
  k_rownorm128<<<512, 256, 0, stream>>>(memn, rn_new, 2048);
  k_bwmfwm    <<<1, 1024, 0, stream>>>(memn, bw, fw, bwm, fwm);

  // stage 7: read addressing + read output
  gemm_nt<<<dim3(32,16), 256, 0, stream>>>(rks, memn, sim, 1024, 2048, 128, nullptr, nullptr, nullptr, rn_new);
  k_softmax2048<<<1024, 256, 0, stream>>>(sim);
  k_readout<<<256, 128, 0, stream>>>(sim, memn, rm0, rm1, rm2, bwm, fwm, ro);

  // stage 8: output projection
  k_hro  <<<1536, 256, 0, stream>>>(h, ro, hro);
  gemm_nt<<<dim3(16,4), 256, 0, stream>>>(hro, W_out, out, 256, 1024, 1536, b_out, nullptr, nullptr, nullptr);

  (void)in_sizes; (void)n_in; (void)out_size; (void)ws_size;
}

// Round 3
// 569.720 us; speedup vs baseline: 1.5111x; 1.2863x over previous
//
#include <hip/hip_runtime.h>
#include <cmath>

#define DEVI __device__ __forceinline__

DEVI float sigm(float x){ return 1.f/(1.f+expf(-x)); }

// ---------------- small utility kernels ----------------

__global__ void k_zero(float* __restrict__ p, int n){
  int i = blockIdx.x*256 + threadIdx.x;
  if (i < n) p[i] = 0.f;
}

// partial column sums of memory (2048 x 128) -> cm[128] (atomic, cm pre-zeroed)
// 32 blocks x 64 rows; cm ends up holding the SUM (scale applied in k_cin)
__global__ __launch_bounds__(256) void k_colmean_part(const float* __restrict__ mem, float* __restrict__ cm){
  __shared__ float s[2][128];
  int d = threadIdx.x & 127, g = threadIdx.x >> 7;
  int n0 = blockIdx.x*64;
  float a = 0.f;
  #pragma unroll 4
  for (int i = g; i < 64; i += 2) a += mem[(size_t)(n0+i)*128 + d];
  s[g][d] = a;
  __syncthreads();
  if (g == 0) atomicAdd(&cm[d], s[0][d] + s[1][d]);
}

// inverse L2 norm of each 128-wide row (wave per row)
__global__ __launch_bounds__(256) void k_rownorm128(const float* __restrict__ A, float* __restrict__ invn, int rows){
  int w = (blockIdx.x*blockDim.x + threadIdx.x) >> 6;
  int lane = threadIdx.x & 63;
  if (w >= rows) return;
  const float* a = A + (size_t)w*128;
  float x0 = a[lane], x1 = a[lane+64];
  float s = x0*x0 + x1*x1;
  #pragma unroll
  for (int o = 32; o > 0; o >>= 1) s += __shfl_down(s, o);
  if (lane == 0) invn[w] = 1.f / fmaxf(sqrtf(s), 1e-12f);
}

// cin[b,k] = k<1024 ? x[b,k] : cm[(k-1024)%128]/2048
__global__ void k_cin(const float* __restrict__ x, const float* __restrict__ cm, float* __restrict__ cin){
  int idx = blockIdx.x*256 + threadIdx.x;     // 256*1536
  int b = idx / 1536, k = idx - b*1536;
  cin[idx] = (k < 1024) ? x[b*1024 + k] : cm[(k-1024) & 127] * (1.f/2048.f);
}

// ---------------- generic NT GEMM: C[M,N] = A[M,K] @ B[N,K]^T (epilogue opts) ----------------
// K must be a multiple of 16. 64x64 tile, 256 threads, 4x4 microtile.
__global__ __launch_bounds__(256) void gemm_nt(
    const float* __restrict__ A, const float* __restrict__ Bm, float* __restrict__ C,
    int M, int N, int K,
    const float* __restrict__ bias1, const float* __restrict__ bias2,
    const float* __restrict__ rowscale, const float* __restrict__ colscale)
{
  __shared__ float As[16][68];
  __shared__ float Bs[16][68];
  const int m0 = blockIdx.y*64, n0 = blockIdx.x*64;
  const int tid = threadIdx.x;
  const int tx = tid & 15, ty = tid >> 4;
  const int r = tid >> 2, kq = (tid & 3) << 2;
  float acc[4][4] = {};
  for (int k0 = 0; k0 < K; k0 += 16){
    float4 va = make_float4(0,0,0,0), vb = make_float4(0,0,0,0);
    int gm = m0 + r, gn = n0 + r, gk = k0 + kq;
    if (gm < M) va = *(const float4*)(A  + (size_t)gm*K + gk);
    if (gn < N) vb = *(const float4*)(Bm + (size_t)gn*K + gk);
    As[kq+0][r]=va.x; As[kq+1][r]=va.y; As[kq+2][r]=va.z; As[kq+3][r]=va.w;
    Bs[kq+0][r]=vb.x; Bs[kq+1][r]=vb.y; Bs[kq+2][r]=vb.z; Bs[kq+3][r]=vb.w;
    __syncthreads();
    #pragma unroll
    for (int k = 0; k < 16; k++){
      float a[4], b[4];
      #pragma unroll
      for (int i = 0; i < 4; i++) a[i] = As[k][ty*4+i];
      #pragma unroll
      for (int j = 0; j < 4; j++) b[j] = Bs[k][tx*4+j];
      #pragma unroll
      for (int i = 0; i < 4; i++)
        #pragma unroll
        for (int j = 0; j < 4; j++) acc[i][j] = fmaf(a[i], b[j], acc[i][j]);
    }
    __syncthreads();
  }
  #pragma unroll
  for (int i = 0; i < 4; i++){
    int m = m0 + ty*4 + i;
    if (m >= M) continue;
    float rs = rowscale ? rowscale[m] : 1.f;
    #pragma unroll
    for (int j = 0; j < 4; j++){
      int n = n0 + tx*4 + j;
      if (n >= N) continue;
      float v = acc[i][j] * rs;
      if (colscale) v *= colscale[n];
      if (bias1)    v += bias1[n];
      if (bias2)    v += bias2[n];
      C[(size_t)m*N + n] = v;
    }
  }
}

// LSTM gate activation: h from g (B x 4096), torch gate order i,f,g,o; c0=h0=0
__global__ void k_lstm(const float* __restrict__ g, float* __restrict__ h){
  int idx = blockIdx.x*256 + threadIdx.x;    // 256*1024
  int b = idx >> 10, j = idx & 1023;
  const float* gr = g + (size_t)b*4096;
  float c = sigm(gr[j]) * tanhf(gr[2048 + j]);
  h[idx] = sigm(gr[3072 + j]) * tanhf(c);
}

// block reduce over 128 threads (2 waves), result broadcast to all threads
DEVI float blockReduce128(float v, float* lds2){
  #pragma unroll
  for (int o = 32; o > 0; o >>= 1) v += __shfl_xor(v, o);
  int w = threadIdx.x >> 6;
  __syncthreads();
  if ((threadIdx.x & 63) == 0) lds2[w] = v;
  __syncthreads();
  return lds2[0] + lds2[1];
}

// parse interface vector itf (B x 787) into all components
__global__ __launch_bounds__(128) void k_parse(const float* __restrict__ itf,
    float* __restrict__ wv, float* __restrict__ ev, float* __restrict__ av,
    float* __restrict__ wg_, float* __restrict__ ag_, float* __restrict__ invwv,
    float* __restrict__ rm0, float* __restrict__ rm1, float* __restrict__ rm2,
    float* __restrict__ rks)
{
  __shared__ float red[2];
  int b = blockIdx.x, t = threadIdx.x;
  const float* it = itf + (size_t)b*787;
  float wg = sigm(it[256]);
  float ag = sigm(it[257]);
  if (t == 0){ wg_[b] = wg; ag_[b] = ag; }
  float w = it[t];                       // write value
  wv[b*128 + t] = w;
  av[b*128 + t] = w * wg;
  ev[b*128 + t] = sigm(it[128 + t]) * wg;
  float ss = blockReduce128(w*w, red);
  if (t == 0) invwv[b] = 1.f / fmaxf(sqrtf(ss), 1e-12f);
  if (t < 4){
    int rr = t;
    float m0v = it[259 + rr*3 + 0], m1v = it[259 + rr*3 + 1], m2v = it[259 + rr*3 + 2];
    float mx = fmaxf(m0v, fmaxf(m1v, m2v));
    float e0 = expf(m0v - mx), e1 = expf(m1v - mx), e2 = expf(m2v - mx);
    float inv = 1.f / (e0 + e1 + e2);
    rm0[b*4 + rr] = e0*inv; rm1[b*4 + rr] = e1*inv; rm2[b*4 + rr] = e2*inv;
  }
  #pragma unroll
  for (int rr = 0; rr < 4; rr++){
    float kv = it[275 + rr*128 + t];
    float ks = blockReduce128(kv*kv, red);
    float sx = it[271 + rr];
    float str = fmaxf(sx, 0.f) + log1pf(expf(-fabsf(sx)));  // softplus
    float invk = 1.f / fmaxf(sqrtf(ks), 1e-12f);
    rks[((size_t)b*4 + rr)*128 + t] = kv * invk * str;      // normalized key * strength
  }
}

// allocation weighting, sort-free: alloc[n] = u[n] * prod_{m stably-before n}(1-u[m])
// one block per n; 256 threads do a strided partial product + multiply-reduce.
__global__ __launch_bounds__(256) void k_alloc(const float* __restrict__ usage, float* __restrict__ out){
  __shared__ float red[4];
  int n = blockIdx.x, t = threadIdx.x;
  float un = usage[n];
  float prod = 1.f;
  #pragma unroll
  for (int i = 0; i < 8; i++){
    int m = t + i*256;
    float um = usage[m];
    bool before = (um < un) || (um == un && m < n);
    prod *= before ? (1.f - um) : 1.f;
  }
  #pragma unroll
  for (int o = 32; o > 0; o >>= 1) prod *= __shfl_xor(prod, o);
  if ((t & 63) == 0) red[t >> 6] = prod;
  __syncthreads();
  if (t == 0) out[n] = un * (red[0]*red[1]) * (red[2]*red[3]);
}

// in-place row softmax, rows of length 2048, one block (256 thr) per row
__global__ __launch_bounds__(256) void k_softmax2048(float* __restrict__ P){
  __shared__ float red[4];
  float* p = P + (size_t)blockIdx.x*2048;
  int t = threadIdx.x;
  float r[8];
  float mx = -3.4e38f;
  #pragma unroll
  for (int i = 0; i < 8; i++){ r[i] = p[t + i*256]; mx = fmaxf(mx, r[i]); }
  #pragma unroll
  for (int o = 32; o > 0; o >>= 1) mx = fmaxf(mx, __shfl_xor(mx, o));
  if ((t & 63) == 0) red[t >> 6] = mx;
  __syncthreads();
  mx = fmaxf(fmaxf(red[0], red[1]), fmaxf(red[2], red[3]));
  float s = 0.f;
  #pragma unroll
  for (int i = 0; i < 8; i++){ r[i] = expf(r[i] - mx); s += r[i]; }
  #pragma unroll
  for (int o = 32; o > 0; o >>= 1) s += __shfl_xor(s, o);
  __syncthreads();
  if ((t & 63) == 0) red[t >> 6] = s;
  __syncthreads();
  s = red[0] + red[1] + red[2] + red[3];
  float inv = 1.f / s;
  #pragma unroll
  for (int i = 0; i < 8; i++) p[t + i*256] = r[i]*inv;
}

// ww[b,n] = wg[b] * (0.5*cw[b,n] + 0.5*alloc[n]*ag[b])   (in place over cw)
__global__ void k_writew(float* __restrict__ cw, const float* __restrict__ alloc,
                         const float* __restrict__ wg, const float* __restrict__ ag){
  int idx = blockIdx.x*256 + threadIdx.x;  // 256*2048
  int b = idx >> 11, n = idx & 2047;
  cw[idx] = wg[b] * (0.5f*cw[idx] + 0.5f*alloc[n]*ag[b]);
}

// generic row sums (wave per row)
__global__ void k_rowsum(const float* __restrict__ A, float* __restrict__ out, int rows, int cols){
  int w = (blockIdx.x*blockDim.x + threadIdx.x) >> 6;
  int lane = threadIdx.x & 63;
  if (w >= rows) return;
  const float* a = A + (size_t)w*cols;
  float s = 0.f;
  for (int c = lane; c < cols; c += 64) s += a[c];
  #pragma unroll
  for (int o = 32; o > 0; o >>= 1) s += __shfl_down(s, o);
  if (lane == 0) out[w] = s;
}

// column sums of a (2048 x 2048) matrix via partial + atomicAdd (out must be zeroed)
__global__ void k_colsum2048(const float* __restrict__ A, float* __restrict__ out){
  int c = blockIdx.x*256 + threadIdx.x;
  int r0 = blockIdx.y*128;
  float s = 0.f;
  for (int rr = 0; rr < 128; rr++) s += A[(size_t)(r0+rr)*2048 + c];
  atomicAdd(&out[c], s);
}

// bw[m] = (0.9*colsum_link[m] + 0.1*lusum[m]) / N ; fw with rowsum_link. lu symmetric.
// 1024 threads: 4-way batch split (z) + LDS reduce, 256 m-columns per block.
__global__ __launch_bounds__(1024) void k_bwfw(const float* __restrict__ ww, const float* __restrict__ tb,
                       const float* __restrict__ rowsum, const float* __restrict__ colsum,
                       float* __restrict__ bw, float* __restrict__ fw){
  __shared__ float sq[4][256], sd[4][256];
  int t = threadIdx.x & 255, z = threadIdx.x >> 8;
  int m = blockIdx.x*256 + t;   // 8 blocks
  float q = 0.f, dd = 0.f;
  for (int b = z*64; b < z*64 + 64; b++){
    float w = ww[(size_t)b*2048 + m];
    q  = fmaf(tb[b], w, q);
    dd = fmaf(w, w, dd);
  }
  sq[z][t] = q; sd[z][t] = dd;
  __syncthreads();
  if (z == 0){
    q  = sq[0][t] + sq[1][t] + sq[2][t] + sq[3][t];
    dd = sd[0][t] + sd[1][t] + sd[2][t] + sd[3][t];
    float lus = (q - dd) * (1.f/256.f);     // colsum(lu)[m] - lu[m,m]
    bw[m] = (0.9f*colsum[m] + 0.1f*lus) * (1.f/2048.f);
    fw[m] = (0.9f*rowsum[m] + 0.1f*lus) * (1.f/2048.f);
  }
}

// mem_new = memory*(1 - ww^T@ev/B) + ww^T@av/B   (TN gemm, M=2048 n, N=128 d, K=256 b)
__global__ __launch_bounds__(256) void k_memupdate(const float* __restrict__ ww,
    const float* __restrict__ ev, const float* __restrict__ av,
    const float* __restrict__ mem, float* __restrict__ memn)
{
  __shared__ float Ws[16][68], Es[16][68], Vs[16][68];
  int m0 = blockIdx.y*64, n0 = blockIdx.x*64;
  int tid = threadIdx.x, tx = tid & 15, ty = tid >> 4;
  int kk = tid >> 4, col = (tid & 15) << 2;
  float ae[4][4] = {}, aa[4][4] = {};
  for (int k0 = 0; k0 < 256; k0 += 16){
    float4 vw  = *(const float4*)(ww + (size_t)(k0+kk)*2048 + m0 + col);
    float4 vev = *(const float4*)(ev + (size_t)(k0+kk)*128  + n0 + col);
    float4 vav = *(const float4*)(av + (size_t)(k0+kk)*128  + n0 + col);
    Ws[kk][col]=vw.x;  Ws[kk][col+1]=vw.y;  Ws[kk][col+2]=vw.z;  Ws[kk][col+3]=vw.w;
    Es[kk][col]=vev.x; Es[kk][col+1]=vev.y; Es[kk][col+2]=vev.z; Es[kk][col+3]=vev.w;
    Vs[kk][col]=vav.x; Vs[kk][col+1]=vav.y; Vs[kk][col+2]=vav.z; Vs[kk][col+3]=vav.w;
    __syncthreads();
    #pragma unroll
    for (int k = 0; k < 16; k++){
      float a[4], e[4], v[4];
      #pragma unroll
      for (int i = 0; i < 4; i++) a[i] = Ws[k][ty*4+i];
      #pragma unroll
      for (int j = 0; j < 4; j++){ e[j] = Es[k][tx*4+j]; v[j] = Vs[k][tx*4+j]; }
      #pragma unroll
      for (int i = 0; i < 4; i++)
        #pragma unroll
        for (int j = 0; j < 4; j++){
          ae[i][j] = fmaf(a[i], e[j], ae[i][j]);
          aa[i][j] = fmaf(a[i], v[j], aa[i][j]);
        }
    }
    __syncthreads();
  }
  #pragma unroll
  for (int i = 0; i < 4; i++){
    int n = m0 + ty*4 + i;
    #pragma unroll
    for (int j = 0; j < 4; j++){
      int d = n0 + tx*4 + j;
      float em = ae[i][j] * (1.f/256.f);
      float am = aa[i][j] * (1.f/256.f);
      memn[(size_t)n*128 + d] = mem[(size_t)n*128 + d] * (1.f - em) + am;
    }
  }
}

// partial bwm[d] = sum_n bw[n]*mem_new[n,d] (atomic, pre-zeroed); fwm likewise
// 32 blocks x 64 rows
__global__ __launch_bounds__(256) void k_bwmfwm_part(const float* __restrict__ memn,
    const float* __restrict__ bw, const float* __restrict__ fw,
    float* __restrict__ bwm, float* __restrict__ fwm)
{
  __shared__ float sb[2][128], sf[2][128];
  int d = threadIdx.x & 127, g = threadIdx.x >> 7;
  int n0 = blockIdx.x*64;
  float ab = 0.f, af = 0.f;
  #pragma unroll 4
  for (int i = g; i < 64; i += 2){
    float m = memn[(size_t)(n0+i)*128 + d];
    ab = fmaf(bw[n0+i], m, ab);
    af = fmaf(fw[n0+i], m, af);
  }
  sb[g][d] = ab; sf[g][d] = af;
  __syncthreads();
  if (g == 0){
    atomicAdd(&bwm[d], sb[0][d] + sb[1][d]);
    atomicAdd(&fwm[d], sf[0][d] + sf[1][d]);
  }
}

// read_out[row,d] = rm0[row]*(P[row,:]@mem_new)[d] + rm1[row]*bwm[d] + rm2[row]*fwm[d]
__global__ __launch_bounds__(128) void k_readout(const float* __restrict__ P,
    const float* __restrict__ memn, const float* __restrict__ rm0, const float* __restrict__ rm1,
    const float* __restrict__ rm2, const float* __restrict__ bwm, const float* __restrict__ fwm,
    float* __restrict__ ro)
{
  __shared__ float Ps[4][128];
  int r0 = blockIdx.x*4, d = threadIdx.x;
  float acc[4] = {0.f, 0.f, 0.f, 0.f};
  for (int nc = 0; nc < 2048; nc += 128){
    #pragma unroll
    for (int rr = 0; rr < 4; rr++) Ps[rr][d] = P[(size_t)(r0+rr)*2048 + nc + d];
    __syncthreads();
    #pragma unroll 8
    for (int n = 0; n < 128; n++){
      float m = memn[(size_t)(nc+n)*128 + d];
      #pragma unroll
      for (int rr = 0; rr < 4; rr++) acc[rr] = fmaf(Ps[rr][n], m, acc[rr]);
    }
    __syncthreads();
  }
  #pragma unroll
  for (int rr = 0; rr < 4; rr++){
    int row = r0 + rr;
    ro[(size_t)row*128 + d] = rm0[row]*acc[rr] + rm1[row]*bwm[d] + rm2[row]*fwm[d];
  }
}

// hro = concat(h, read_out) per batch row
__global__ void k_hro(const float* __restrict__ h, const float* __restrict__ ro, float* __restrict__ hro){
  int idx = blockIdx.x*256 + threadIdx.x;   // 256*1536
  int b = idx / 1536, k = idx - b*1536;
  hro[idx] = (k < 1024) ? h[b*1024 + k] : ro[b*512 + k - 1024];
}

// ---------------- launcher ----------------

extern "C" void kernel_launch(void* const* d_in, const int* in_sizes, int n_in,
                              void* d_out, int out_size, void* d_ws, size_t ws_size,
                              hipStream_t stream)
{
  const float* x     = (const float*)d_in[0];
  const float* mem   = (const float*)d_in[1];
  const float* usage = (const float*)d_in[2];
  const float* link  = (const float*)d_in[3];
  const float* W_ih  = (const float*)d_in[4];
  // d_in[5] = W_hh: unused (h0 = 0)
  const float* b_ih  = (const float*)d_in[6];
  const float* b_hh  = (const float*)d_in[7];
  const float* W_if  = (const float*)d_in[8];
  const float* b_if  = (const float*)d_in[9];
  const float* W_out = (const float*)d_in[10];
  const float* b_out = (const float*)d_in[11];
  float* out = (float*)d_out;
  float* ws  = (float*)d_ws;

  // atomic accumulators first (one contiguous zero region of 2432 floats)
  float* cm     = ws + 0;         // 128  (column SUM of memory)
  float* csl    = ws + 128;       // 2048 colsum(link)
  float* bwm    = ws + 2176;      // 128
  float* fwm    = ws + 2304;      // 128
  float* rn_mem = ws + 2432;      // 2048
  float* rn_new = ws + 4480;      // 2048
  float* rsl    = ws + 6528;      // 2048 rowsum(link)
  float* tb     = ws + 8576;      // 256
  float* bw     = ws + 8832;      // 2048
  float* fw     = ws + 10880;     // 2048
  float* wg     = ws + 12928;     // 256
  float* ag     = ws + 13184;     // 256
  float* invwv  = ws + 13440;     // 256
  float* rm0    = ws + 13696;     // 1024
  float* rm1    = ws + 14720;     // 1024
  float* rm2    = ws + 15744;     // 1024
  float* alloc  = ws + 16768;     // 2048
  float* wv     = ws + 18816;     // 32768  (B x 128)
  float* ev     = ws + 51584;     // 32768
  float* av     = ws + 84352;     // 32768
  float* rks    = ws + 117120;    // 131072 (B*R x 128)
  float* cin    = ws + 248192;    // 393216 (B x 1536)
  float* g      = ws + 641408;    // 1048576 (B x 4096)
  float* h      = ws + 1689984;   // 262144 (B x 1024)
  float* itf    = ws + 1952128;   // 201472 (B x 787)
  float* ww     = ws + 2153856;   // 524288 (B x 2048): cw logits -> cw -> write_w
  float* memn   = ws + 2678144;   // 262144 (2048 x 128)
  float* sim    = ws + 2940288;   // 2097152 (B*R x 2048): logits -> softmax P
  float* ro     = ws + 5037440;   // 131072 (B x R*D)
  float* hro    = ws + 5168512;   // 393216 (B x 1536)
  // total = 5,561,728 floats = 22.2 MB

  // stage 0: zero all atomic accumulators (cm, csl, bwm, fwm contiguous)
  k_zero<<<10, 256, 0, stream>>>(ws, 2432);

  // stage 1: controller input
  k_colmean_part<<<32, 256, 0, stream>>>(mem, cm);
  k_rownorm128  <<<512, 256, 0, stream>>>(mem, rn_mem, 2048);
  k_cin         <<<1536, 256, 0, stream>>>(x, cm, cin);

  // stage 2: LSTM controller
  gemm_nt<<<dim3(64,4), 256, 0, stream>>>(cin, W_ih, g, 256, 4096, 1536, b_ih, b_hh, nullptr, nullptr);
  k_lstm <<<1024, 256, 0, stream>>>(g, h);

  // stage 3: interface
  gemm_nt<<<dim3(13,4), 256, 0, stream>>>(h, W_if, itf, 256, 787, 1024, b_if, nullptr, nullptr, nullptr);
  k_parse<<<256, 128, 0, stream>>>(itf, wv, ev, av, wg, ag, invwv, rm0, rm1, rm2, rks);

  // stage 4: write weighting
  k_alloc<<<2048, 256, 0, stream>>>(usage, alloc);
  gemm_nt<<<dim3(32,4), 256, 0, stream>>>(wv, mem, ww, 256, 2048, 128, nullptr, nullptr, invwv, rn_mem);
  k_softmax2048<<<256, 256, 0, stream>>>(ww);
  k_writew<<<2048, 256, 0, stream>>>(ww, alloc, wg, ag);

  // stage 5: link-derived read vectors (link_new never materialized)
  k_rowsum<<<512, 256, 0, stream>>>(link, rsl, 2048, 2048);
  k_colsum2048<<<dim3(8,16), 256, 0, stream>>>(link, csl);
  k_rowsum<<<64, 256, 0, stream>>>(ww, tb, 256, 2048);
  k_bwfw  <<<8, 1024, 0, stream>>>(ww, tb, rsl, csl, bw, fw);

  // stage 6: memory update
  k_memupdate <<<dim3(2,32), 256, 0, stream>>>(ww, ev, av, mem, memn);
  k_rownorm128<<<512, 256, 0, stream>>>(memn, rn_new, 2048);
  k_bwmfwm_part<<<32, 256, 0, stream>>>(memn, bw, fw, bwm, fwm);

  // stage 7: read addressing + read output
  gemm_nt<<<dim3(32,16), 256, 0, stream>>>(rks, memn, sim, 1024, 2048, 128, nullptr, nullptr, nullptr, rn_new);
  k_softmax2048<<<1024, 256, 0, stream>>>(sim);
  k_readout<<<256, 128, 0, stream>>>(sim, memn, rm0, rm1, rm2, bwm, fwm, ro);

  // stage 8: output projection
  k_hro  <<<1536, 256, 0, stream>>>(h, ro, hro);
  gemm_nt<<<dim3(16,4), 256, 0, stream>>>(hro, W_out, out, 256, 1024, 1536, b_out, nullptr, nullptr, nullptr);

  (void)in_sizes; (void)n_in; (void)out_size; (void)ws_size;
}

// Round 4
// 509.315 us; speedup vs baseline: 1.6903x; 1.1186x over previous
//
#include <hip/hip_runtime.h>
#include <cmath>

#define DEVI __device__ __forceinline__

DEVI float sigm(float x){ return 1.f/(1.f+expf(-x)); }

// ---------------- small utility kernels ----------------

__global__ void k_zero(float* __restrict__ p, int n){
  int i = blockIdx.x*256 + threadIdx.x;
  if (i < n) p[i] = 0.f;
}

// partial column sums of memory (2048 x 128) -> cm[128] (atomic, cm pre-zeroed)
__global__ __launch_bounds__(256) void k_colmean_part(const float* __restrict__ mem, float* __restrict__ cm){
  __shared__ float s[2][128];
  int d = threadIdx.x & 127, g = threadIdx.x >> 7;
  int n0 = blockIdx.x*64;
  float a = 0.f;
  #pragma unroll 4
  for (int i = g; i < 64; i += 2) a += mem[(size_t)(n0+i)*128 + d];
  s[g][d] = a;
  __syncthreads();
  if (g == 0) atomicAdd(&cm[d], s[0][d] + s[1][d]);
}

// inverse L2 norm of each 128-wide row (wave per row)
__global__ __launch_bounds__(256) void k_rownorm128(const float* __restrict__ A, float* __restrict__ invn, int rows){
  int w = (blockIdx.x*blockDim.x + threadIdx.x) >> 6;
  int lane = threadIdx.x & 63;
  if (w >= rows) return;
  const float* a = A + (size_t)w*128;
  float x0 = a[lane], x1 = a[lane+64];
  float s = x0*x0 + x1*x1;
  #pragma unroll
  for (int o = 32; o > 0; o >>= 1) s += __shfl_down(s, o);
  if (lane == 0) invn[w] = 1.f / fmaxf(sqrtf(s), 1e-12f);
}

// cin[b,k] = k<1024 ? x[b,k] : cm[(k-1024)%128]/2048
__global__ void k_cin(const float* __restrict__ x, const float* __restrict__ cm, float* __restrict__ cin){
  int idx = blockIdx.x*256 + threadIdx.x;     // 256*1536
  int b = idx / 1536, k = idx - b*1536;
  cin[idx] = (k < 1024) ? x[b*1024 + k] : cm[(k-1024) & 127] * (1.f/2048.f);
}

// ---------------- NT GEMM: C[M,N] = A[M,K] @ B[N,K]^T ----------------
// 32x64 tile, 256 threads, 2x4 microtile, dual-buffered LDS + register prefetch.
// Requirements: M % 32 == 0, K % 16 == 0. N guarded.
__global__ __launch_bounds__(256) void gemm_nt(
    const float* __restrict__ A, const float* __restrict__ Bm, float* __restrict__ C,
    int M, int N, int K,
    const float* __restrict__ bias1, const float* __restrict__ bias2,
    const float* __restrict__ rowscale, const float* __restrict__ colscale)
{
  __shared__ float As[2][16][36];
  __shared__ float Bs[2][16][68];
  const int m0 = blockIdx.y*32, n0 = blockIdx.x*64;
  const int tid = threadIdx.x;
  const int tx = tid & 15, ty = tid >> 4;      // compute map: cols tx*4+j, rows ty*2+i
  const int r = tid >> 2, kq = (tid & 3) << 2; // load map
  const int T = K >> 4;
  const int gn = n0 + r;
  const bool bok = (gn < N);
  const float* Aptr = A + (size_t)(m0 + (r & 31))*K + kq;  // tid<128 -> rows 0..31
  const float* Bptr = bok ? (Bm + (size_t)gn*K + kq) : Bm;

  float4 va, vb;
  // prologue: tile 0
  if (tid < 128) va = *(const float4*)(Aptr);
  vb = bok ? *(const float4*)(Bptr) : make_float4(0,0,0,0);
  if (tid < 128){
    As[0][kq+0][r]=va.x; As[0][kq+1][r]=va.y; As[0][kq+2][r]=va.z; As[0][kq+3][r]=va.w;
  }
  Bs[0][kq+0][r]=vb.x; Bs[0][kq+1][r]=vb.y; Bs[0][kq+2][r]=vb.z; Bs[0][kq+3][r]=vb.w;
  __syncthreads();

  float acc[2][4] = {};
  for (int t = 0; t < T; t++){
    const int cur = t & 1, nxt = cur ^ 1;
    if (t+1 < T){
      if (tid < 128) va = *(const float4*)(Aptr + (t+1)*16);
      vb = bok ? *(const float4*)(Bptr + (t+1)*16) : make_float4(0,0,0,0);
    }
    #pragma unroll
    for (int k = 0; k < 16; k++){
      float a0 = As[cur][k][ty*2+0];
      float a1 = As[cur][k][ty*2+1];
      float b0 = Bs[cur][k][tx*4+0];
      float b1 = Bs[cur][k][tx*4+1];
      float b2 = Bs[cur][k][tx*4+2];
      float b3 = Bs[cur][k][tx*4+3];
      acc[0][0] = fmaf(a0,b0,acc[0][0]); acc[0][1] = fmaf(a0,b1,acc[0][1]);
      acc[0][2] = fmaf(a0,b2,acc[0][2]); acc[0][3] = fmaf(a0,b3,acc[0][3]);
      acc[1][0] = fmaf(a1,b0,acc[1][0]); acc[1][1] = fmaf(a1,b1,acc[1][1]);
      acc[1][2] = fmaf(a1,b2,acc[1][2]); acc[1][3] = fmaf(a1,b3,acc[1][3]);
    }
    if (t+1 < T){
      if (tid < 128){
        As[nxt][kq+0][r]=va.x; As[nxt][kq+1][r]=va.y; As[nxt][kq+2][r]=va.z; As[nxt][kq+3][r]=va.w;
      }
      Bs[nxt][kq+0][r]=vb.x; Bs[nxt][kq+1][r]=vb.y; Bs[nxt][kq+2][r]=vb.z; Bs[nxt][kq+3][r]=vb.w;
    }
    __syncthreads();
  }

  #pragma unroll
  for (int i = 0; i < 2; i++){
    int m = m0 + ty*2 + i;
    float rs = rowscale ? rowscale[m] : 1.f;
    #pragma unroll
    for (int j = 0; j < 4; j++){
      int n = n0 + tx*4 + j;
      if (n >= N) continue;
      float v = acc[i][j] * rs;
      if (colscale) v *= colscale[n];
      if (bias1)    v += bias1[n];
      if (bias2)    v += bias2[n];
      C[(size_t)m*N + n] = v;
    }
  }
}

// LSTM gate activation: h from g (B x 4096), torch gate order i,f,g,o; c0=h0=0
__global__ void k_lstm(const float* __restrict__ g, float* __restrict__ h){
  int idx = blockIdx.x*256 + threadIdx.x;    // 256*1024
  int b = idx >> 10, j = idx & 1023;
  const float* gr = g + (size_t)b*4096;
  float c = sigm(gr[j]) * tanhf(gr[2048 + j]);
  h[idx] = sigm(gr[3072 + j]) * tanhf(c);
}

// block reduce over 128 threads (2 waves), result broadcast to all threads
DEVI float blockReduce128(float v, float* lds2){
  #pragma unroll
  for (int o = 32; o > 0; o >>= 1) v += __shfl_xor(v, o);
  int w = threadIdx.x >> 6;
  __syncthreads();
  if ((threadIdx.x & 63) == 0) lds2[w] = v;
  __syncthreads();
  return lds2[0] + lds2[1];
}

// parse interface vector itf (B x 787) into all components
__global__ __launch_bounds__(128) void k_parse(const float* __restrict__ itf,
    float* __restrict__ wv, float* __restrict__ ev, float* __restrict__ av,
    float* __restrict__ wg_, float* __restrict__ ag_, float* __restrict__ invwv,
    float* __restrict__ rm0, float* __restrict__ rm1, float* __restrict__ rm2,
    float* __restrict__ rks)
{
  __shared__ float red[2];
  int b = blockIdx.x, t = threadIdx.x;
  const float* it = itf + (size_t)b*787;
  float wg = sigm(it[256]);
  float ag = sigm(it[257]);
  if (t == 0){ wg_[b] = wg; ag_[b] = ag; }
  float w = it[t];                       // write value
  wv[b*128 + t] = w;
  av[b*128 + t] = w * wg;
  ev[b*128 + t] = sigm(it[128 + t]) * wg;
  float ss = blockReduce128(w*w, red);
  if (t == 0) invwv[b] = 1.f / fmaxf(sqrtf(ss), 1e-12f);
  if (t < 4){
    int rr = t;
    float m0v = it[259 + rr*3 + 0], m1v = it[259 + rr*3 + 1], m2v = it[259 + rr*3 + 2];
    float mx = fmaxf(m0v, fmaxf(m1v, m2v));
    float e0 = expf(m0v - mx), e1 = expf(m1v - mx), e2 = expf(m2v - mx);
    float inv = 1.f / (e0 + e1 + e2);
    rm0[b*4 + rr] = e0*inv; rm1[b*4 + rr] = e1*inv; rm2[b*4 + rr] = e2*inv;
  }
  #pragma unroll
  for (int rr = 0; rr < 4; rr++){
    float kv = it[275 + rr*128 + t];
    float ks = blockReduce128(kv*kv, red);
    float sx = it[271 + rr];
    float str = fmaxf(sx, 0.f) + log1pf(expf(-fabsf(sx)));  // softplus
    float invk = 1.f / fmaxf(sqrtf(ks), 1e-12f);
    rks[((size_t)b*4 + rr)*128 + t] = kv * invk * str;      // normalized key * strength
  }
}

// allocation weighting, sort-free: alloc[n] = u[n] * prod_{m stably-before n}(1-u[m])
__global__ __launch_bounds__(256) void k_alloc(const float* __restrict__ usage, float* __restrict__ out){
  __shared__ float red[4];
  int n = blockIdx.x, t = threadIdx.x;
  float un = usage[n];
  float prod = 1.f;
  #pragma unroll
  for (int i = 0; i < 8; i++){
    int m = t + i*256;
    float um = usage[m];
    bool before = (um < un) || (um == un && m < n);
    prod *= before ? (1.f - um) : 1.f;
  }
  #pragma unroll
  for (int o = 32; o > 0; o >>= 1) prod *= __shfl_xor(prod, o);
  if ((t & 63) == 0) red[t >> 6] = prod;
  __syncthreads();
  if (t == 0) out[n] = un * (red[0]*red[1]) * (red[2]*red[3]);
}

// in-place row softmax, rows of length 2048, one block (256 thr) per row
__global__ __launch_bounds__(256) void k_softmax2048(float* __restrict__ P){
  __shared__ float red[4];
  float* p = P + (size_t)blockIdx.x*2048;
  int t = threadIdx.x;
  float r[8];
  float mx = -3.4e38f;
  #pragma unroll
  for (int i = 0; i < 8; i++){ r[i] = p[t + i*256]; mx = fmaxf(mx, r[i]); }
  #pragma unroll
  for (int o = 32; o > 0; o >>= 1) mx = fmaxf(mx, __shfl_xor(mx, o));
  if ((t & 63) == 0) red[t >> 6] = mx;
  __syncthreads();
  mx = fmaxf(fmaxf(red[0], red[1]), fmaxf(red[2], red[3]));
  float s = 0.f;
  #pragma unroll
  for (int i = 0; i < 8; i++){ r[i] = expf(r[i] - mx); s += r[i]; }
  #pragma unroll
  for (int o = 32; o > 0; o >>= 1) s += __shfl_xor(s, o);
  __syncthreads();
  if ((t & 63) == 0) red[t >> 6] = s;
  __syncthreads();
  s = red[0] + red[1] + red[2] + red[3];
  float inv = 1.f / s;
  #pragma unroll
  for (int i = 0; i < 8; i++) p[t + i*256] = r[i]*inv;
}

// ww[b,n] = wg[b] * (0.5*cw[b,n] + 0.5*alloc[n]*ag[b])   (in place over cw)
__global__ void k_writew(float* __restrict__ cw, const float* __restrict__ alloc,
                         const float* __restrict__ wg, const float* __restrict__ ag){
  int idx = blockIdx.x*256 + threadIdx.x;  // 256*2048
  int b = idx >> 11, n = idx & 2047;
  cw[idx] = wg[b] * (0.5f*cw[idx] + 0.5f*alloc[n]*ag[b]);
}

// generic row sums (wave per row)
__global__ void k_rowsum(const float* __restrict__ A, float* __restrict__ out, int rows, int cols){
  int w = (blockIdx.x*blockDim.x + threadIdx.x) >> 6;
  int lane = threadIdx.x & 63;
  if (w >= rows) return;
  const float* a = A + (size_t)w*cols;
  float s = 0.f;
  for (int c = lane; c < cols; c += 64) s += a[c];
  #pragma unroll
  for (int o = 32; o > 0; o >>= 1) s += __shfl_down(s, o);
  if (lane == 0) out[w] = s;
}

// column sums of a (2048 x 2048) matrix via partial + atomicAdd (out must be zeroed)
__global__ void k_colsum2048(const float* __restrict__ A, float* __restrict__ out){
  int c = blockIdx.x*256 + threadIdx.x;
  int r0 = blockIdx.y*128;
  float s = 0.f;
  for (int rr = 0; rr < 128; rr++) s += A[(size_t)(r0+rr)*2048 + c];
  atomicAdd(&out[c], s);
}

// bw[m] = (0.9*colsum_link[m] + 0.1*lusum[m]) / N ; fw with rowsum_link. lu symmetric.
__global__ __launch_bounds__(1024) void k_bwfw(const float* __restrict__ ww, const float* __restrict__ tb,
                       const float* __restrict__ rowsum, const float* __restrict__ colsum,
                       float* __restrict__ bw, float* __restrict__ fw){
  __shared__ float sq[4][256], sd[4][256];
  int t = threadIdx.x & 255, z = threadIdx.x >> 8;
  int m = blockIdx.x*256 + t;   // 8 blocks
  float q = 0.f, dd = 0.f;
  for (int b = z*64; b < z*64 + 64; b++){
    float w = ww[(size_t)b*2048 + m];
    q  = fmaf(tb[b], w, q);
    dd = fmaf(w, w, dd);
  }
  sq[z][t] = q; sd[z][t] = dd;
  __syncthreads();
  if (z == 0){
    q  = sq[0][t] + sq[1][t] + sq[2][t] + sq[3][t];
    dd = sd[0][t] + sd[1][t] + sd[2][t] + sd[3][t];
    float lus = (q - dd) * (1.f/256.f);     // colsum(lu)[m] - lu[m,m]
    bw[m] = (0.9f*colsum[m] + 0.1f*lus) * (1.f/2048.f);
    fw[m] = (0.9f*rowsum[m] + 0.1f*lus) * (1.f/2048.f);
  }
}

// mem_new = memory*(1 - ww^T@ev/B) + ww^T@av/B   (TN gemm, M=2048 n, N=128 d, K=256 b)
__global__ __launch_bounds__(256) void k_memupdate(const float* __restrict__ ww,
    const float* __restrict__ ev, const float* __restrict__ av,
    const float* __restrict__ mem, float* __restrict__ memn)
{
  __shared__ float Ws[16][68], Es[16][68], Vs[16][68];
  int m0 = blockIdx.y*64, n0 = blockIdx.x*64;
  int tid = threadIdx.x, tx = tid & 15, ty = tid >> 4;
  int kk = tid >> 4, col = (tid & 15) << 2;
  float ae[4][4] = {}, aa[4][4] = {};
  for (int k0 = 0; k0 < 256; k0 += 16){
    float4 vw  = *(const float4*)(ww + (size_t)(k0+kk)*2048 + m0 + col);
    float4 vev = *(const float4*)(ev + (size_t)(k0+kk)*128  + n0 + col);
    float4 vav = *(const float4*)(av + (size_t)(k0+kk)*128  + n0 + col);
    Ws[kk][col]=vw.x;  Ws[kk][col+1]=vw.y;  Ws[kk][col+2]=vw.z;  Ws[kk][col+3]=vw.w;
    Es[kk][col]=vev.x; Es[kk][col+1]=vev.y; Es[kk][col+2]=vev.z; Es[kk][col+3]=vev.w;
    Vs[kk][col]=vav.x; Vs[kk][col+1]=vav.y; Vs[kk][col+2]=vav.z; Vs[kk][col+3]=vav.w;
    __syncthreads();
    #pragma unroll
    for (int k = 0; k < 16; k++){
      float a[4], e[4], v[4];
      #pragma unroll
      for (int i = 0; i < 4; i++) a[i] = Ws[k][ty*4+i];
      #pragma unroll
      for (int j = 0; j < 4; j++){ e[j] = Es[k][tx*4+j]; v[j] = Vs[k][tx*4+j]; }
      #pragma unroll
      for (int i = 0; i < 4; i++)
        #pragma unroll
        for (int j = 0; j < 4; j++){
          ae[i][j] = fmaf(a[i], e[j], ae[i][j]);
          aa[i][j] = fmaf(a[i], v[j], aa[i][j]);
        }
    }
    __syncthreads();
  }
  #pragma unroll
  for (int i = 0; i < 4; i++){
    int n = m0 + ty*4 + i;
    #pragma unroll
    for (int j = 0; j < 4; j++){
      int d = n0 + tx*4 + j;
      float em = ae[i][j] * (1.f/256.f);
      float am = aa[i][j] * (1.f/256.f);
      memn[(size_t)n*128 + d] = mem[(size_t)n*128 + d] * (1.f - em) + am;
    }
  }
}

// partial bwm[d] = sum_n bw[n]*mem_new[n,d] (atomic, pre-zeroed); fwm likewise
__global__ __launch_bounds__(256) void k_bwmfwm_part(const float* __restrict__ memn,
    const float* __restrict__ bw, const float* __restrict__ fw,
    float* __restrict__ bwm, float* __restrict__ fwm)
{
  __shared__ float sb[2][128], sf[2][128];
  int d = threadIdx.x & 127, g = threadIdx.x >> 7;
  int n0 = blockIdx.x*64;
  float ab = 0.f, af = 0.f;
  #pragma unroll 4
  for (int i = g; i < 64; i += 2){
    float m = memn[(size_t)(n0+i)*128 + d];
    ab = fmaf(bw[n0+i], m, ab);
    af = fmaf(fw[n0+i], m, af);
  }
  sb[g][d] = ab; sf[g][d] = af;
  __syncthreads();
  if (g == 0){
    atomicAdd(&bwm[d], sb[0][d] + sb[1][d]);
    atomicAdd(&fwm[d], sf[0][d] + sf[1][d]);
  }
}

// read_out[row,d] = rm0[row]*(P[row,:]@mem_new)[d] + rm1[row]*bwm[d] + rm2[row]*fwm[d]
__global__ __launch_bounds__(128) void k_readout(const float* __restrict__ P,
    const float* __restrict__ memn, const float* __restrict__ rm0, const float* __restrict__ rm1,
    const float* __restrict__ rm2, const float* __restrict__ bwm, const float* __restrict__ fwm,
    float* __restrict__ ro)
{
  __shared__ float Ps[4][128];
  int r0 = blockIdx.x*4, d = threadIdx.x;
  float acc[4] = {0.f, 0.f, 0.f, 0.f};
  for (int nc = 0; nc < 2048; nc += 128){
    #pragma unroll
    for (int rr = 0; rr < 4; rr++) Ps[rr][d] = P[(size_t)(r0+rr)*2048 + nc + d];
    __syncthreads();
    #pragma unroll 8
    for (int n = 0; n < 128; n++){
      float m = memn[(size_t)(nc+n)*128 + d];
      #pragma unroll
      for (int rr = 0; rr < 4; rr++) acc[rr] = fmaf(Ps[rr][n], m, acc[rr]);
    }
    __syncthreads();
  }
  #pragma unroll
  for (int rr = 0; rr < 4; rr++){
    int row = r0 + rr;
    ro[(size_t)row*128 + d] = rm0[row]*acc[rr] + rm1[row]*bwm[d] + rm2[row]*fwm[d];
  }
}

// hro = concat(h, read_out) per batch row
__global__ void k_hro(const float* __restrict__ h, const float* __restrict__ ro, float* __restrict__ hro){
  int idx = blockIdx.x*256 + threadIdx.x;   // 256*1536
  int b = idx / 1536, k = idx - b*1536;
  hro[idx] = (k < 1024) ? h[b*1024 + k] : ro[b*512 + k - 1024];
}

// ---------------- launcher ----------------

extern "C" void kernel_launch(void* const* d_in, const int* in_sizes, int n_in,
                              void* d_out, int out_size, void* d_ws, size_t ws_size,
                              hipStream_t stream)
{
  const float* x     = (const float*)d_in[0];
  const float* mem   = (const float*)d_in[1];
  const float* usage = (const float*)d_in[2];
  const float* link  = (const float*)d_in[3];
  const float* W_ih  = (const float*)d_in[4];
  // d_in[5] = W_hh: unused (h0 = 0)
  const float* b_ih  = (const float*)d_in[6];
  const float* b_hh  = (const float*)d_in[7];
  const float* W_if  = (const float*)d_in[8];
  const float* b_if  = (const float*)d_in[9];
  const float* W_out = (const float*)d_in[10];
  const float* b_out = (const float*)d_in[11];
  float* out = (float*)d_out;
  float* ws  = (float*)d_ws;

  // atomic accumulators first (one contiguous zero region of 2432 floats)
  float* cm     = ws + 0;         // 128  (column SUM of memory)
  float* csl    = ws + 128;       // 2048 colsum(link)
  float* bwm    = ws + 2176;      // 128
  float* fwm    = ws + 2304;      // 128
  float* rn_mem = ws + 2432;      // 2048
  float* rn_new = ws + 4480;      // 2048
  float* rsl    = ws + 6528;      // 2048 rowsum(link)
  float* tb     = ws + 8576;      // 256
  float* bw     = ws + 8832;      // 2048
  float* fw     = ws + 10880;     // 2048
  float* wg     = ws + 12928;     // 256
  float* ag     = ws + 13184;     // 256
  float* invwv  = ws + 13440;     // 256
  float* rm0    = ws + 13696;     // 1024
  float* rm1    = ws + 14720;     // 1024
  float* rm2    = ws + 15744;     // 1024
  float* alloc  = ws + 16768;     // 2048
  float* wv     = ws + 18816;     // 32768  (B x 128)
  float* ev     = ws + 51584;     // 32768
  float* av     = ws + 84352;     // 32768
  float* rks    = ws + 117120;    // 131072 (B*R x 128)
  float* cin    = ws + 248192;    // 393216 (B x 1536)
  float* g      = ws + 641408;    // 1048576 (B x 4096)
  float* h      = ws + 1689984;   // 262144 (B x 1024)
  float* itf    = ws + 1952128;   // 201472 (B x 787)
  float* ww     = ws + 2153856;   // 524288 (B x 2048): cw logits -> cw -> write_w
  float* memn   = ws + 2678144;   // 262144 (2048 x 128)
  float* sim    = ws + 2940288;   // 2097152 (B*R x 2048): logits -> softmax P
  float* ro     = ws + 5037440;   // 131072 (B x R*D)
  float* hro    = ws + 5168512;   // 393216 (B x 1536)
  // total = 5,561,728 floats = 22.2 MB

  // stage 0: zero all atomic accumulators (cm, csl, bwm, fwm contiguous)
  k_zero<<<10, 256, 0, stream>>>(ws, 2432);

  // stage 1: controller input
  k_colmean_part<<<32, 256, 0, stream>>>(mem, cm);
  k_rownorm128  <<<512, 256, 0, stream>>>(mem, rn_mem, 2048);
  k_cin         <<<1536, 256, 0, stream>>>(x, cm, cin);

  // stage 2: LSTM controller  (grid: N/64 x M/32)
  gemm_nt<<<dim3(64,8), 256, 0, stream>>>(cin, W_ih, g, 256, 4096, 1536, b_ih, b_hh, nullptr, nullptr);
  k_lstm <<<1024, 256, 0, stream>>>(g, h);

  // stage 3: interface
  gemm_nt<<<dim3(13,8), 256, 0, stream>>>(h, W_if, itf, 256, 787, 1024, b_if, nullptr, nullptr, nullptr);
  k_parse<<<256, 128, 0, stream>>>(itf, wv, ev, av, wg, ag, invwv, rm0, rm1, rm2, rks);

  // stage 4: write weighting
  k_alloc<<<2048, 256, 0, stream>>>(usage, alloc);
  gemm_nt<<<dim3(32,8), 256, 0, stream>>>(wv, mem, ww, 256, 2048, 128, nullptr, nullptr, invwv, rn_mem);
  k_softmax2048<<<256, 256, 0, stream>>>(ww);
  k_writew<<<2048, 256, 0, stream>>>(ww, alloc, wg, ag);

  // stage 5: link-derived read vectors (link_new never materialized)
  k_rowsum<<<512, 256, 0, stream>>>(link, rsl, 2048, 2048);
  k_colsum2048<<<dim3(8,16), 256, 0, stream>>>(link, csl);
  k_rowsum<<<64, 256, 0, stream>>>(ww, tb, 256, 2048);
  k_bwfw  <<<8, 1024, 0, stream>>>(ww, tb, rsl, csl, bw, fw);

  // stage 6: memory update
  k_memupdate <<<dim3(2,32), 256, 0, stream>>>(ww, ev, av, mem, memn);
  k_rownorm128<<<512, 256, 0, stream>>>(memn, rn_new, 2048);
  k_bwmfwm_part<<<32, 256, 0, stream>>>(memn, bw, fw, bwm, fwm);

  // stage 7: read addressing + read output
  gemm_nt<<<dim3(32,32), 256, 0, stream>>>(rks, memn, sim, 1024, 2048, 128, nullptr, nullptr, nullptr, rn_new);
  k_softmax2048<<<1024, 256, 0, stream>>>(sim);
  k_readout<<<256, 128, 0, stream>>>(sim, memn, rm0, rm1, rm2, bwm, fwm, ro);

  // stage 8: output projection
  k_hro  <<<1536, 256, 0, stream>>>(h, ro, hro);
  gemm_nt<<<dim3(16,8), 256, 0, stream>>>(hro, W_out, out, 256, 1024, 1536, b_out, nullptr, nullptr, nullptr);

  (void)in_sizes; (void)n_in; (void)out_size; (void)ws_size;
}

// Round 5
// 451.795 us; speedup vs baseline: 1.9055x; 1.1273x over previous
//
#include <hip/hip_runtime.h>
#include <cmath>

#define DEVI __device__ __forceinline__

DEVI float sigm(float x){ return 1.f/(1.f+expf(-x)); }

// ---------------- small utility kernels ----------------

__global__ void k_zero(float* __restrict__ p, int n){
  int i = blockIdx.x*256 + threadIdx.x;
  if (i < n) p[i] = 0.f;
}

// partial column sums of memory (2048 x 128) -> cm[128] (atomic, cm pre-zeroed)
__global__ __launch_bounds__(256) void k_colmean_part(const float* __restrict__ mem, float* __restrict__ cm){
  __shared__ float s[2][128];
  int d = threadIdx.x & 127, g = threadIdx.x >> 7;
  int n0 = blockIdx.x*64;
  float a = 0.f;
  #pragma unroll 4
  for (int i = g; i < 64; i += 2) a += mem[(size_t)(n0+i)*128 + d];
  s[g][d] = a;
  __syncthreads();
  if (g == 0) atomicAdd(&cm[d], s[0][d] + s[1][d]);
}

// inverse L2 norm of each 128-wide row (wave per row)
__global__ __launch_bounds__(256) void k_rownorm128(const float* __restrict__ A, float* __restrict__ invn, int rows){
  int w = (blockIdx.x*blockDim.x + threadIdx.x) >> 6;
  int lane = threadIdx.x & 63;
  if (w >= rows) return;
  const float* a = A + (size_t)w*128;
  float x0 = a[lane], x1 = a[lane+64];
  float s = x0*x0 + x1*x1;
  #pragma unroll
  for (int o = 32; o > 0; o >>= 1) s += __shfl_down(s, o);
  if (lane == 0) invn[w] = 1.f / fmaxf(sqrtf(s), 1e-12f);
}

// cin[b,k] = k<1024 ? x[b,k] : cm[(k-1024)%128]/2048
__global__ void k_cin(const float* __restrict__ x, const float* __restrict__ cm, float* __restrict__ cin){
  int idx = blockIdx.x*256 + threadIdx.x;     // 256*1536
  int b = idx / 1536, k = idx - b*1536;
  cin[idx] = (k < 1024) ? x[b*1024 + k] : cm[(k-1024) & 127] * (1.f/2048.f);
}

// ---------------- NT GEMM: C[M,N] = A[M,K] @ B[N,K]^T ----------------
// 32x64 tile, 256 threads, 2x4 microtile, dual-buffered LDS + register prefetch.
__global__ __launch_bounds__(256) void gemm_nt(
    const float* __restrict__ A, const float* __restrict__ Bm, float* __restrict__ C,
    int M, int N, int K,
    const float* __restrict__ bias1, const float* __restrict__ bias2,
    const float* __restrict__ rowscale, const float* __restrict__ colscale)
{
  __shared__ float As[2][16][36];
  __shared__ float Bs[2][16][68];
  const int m0 = blockIdx.y*32, n0 = blockIdx.x*64;
  const int tid = threadIdx.x;
  const int tx = tid & 15, ty = tid >> 4;
  const int r = tid >> 2, kq = (tid & 3) << 2;
  const int T = K >> 4;
  const int gn = n0 + r;
  const bool bok = (gn < N);
  const float* Aptr = A + (size_t)(m0 + (r & 31))*K + kq;
  const float* Bptr = bok ? (Bm + (size_t)gn*K + kq) : Bm;

  float4 va, vb;
  if (tid < 128) va = *(const float4*)(Aptr);
  vb = bok ? *(const float4*)(Bptr) : make_float4(0,0,0,0);
  if (tid < 128){
    As[0][kq+0][r]=va.x; As[0][kq+1][r]=va.y; As[0][kq+2][r]=va.z; As[0][kq+3][r]=va.w;
  }
  Bs[0][kq+0][r]=vb.x; Bs[0][kq+1][r]=vb.y; Bs[0][kq+2][r]=vb.z; Bs[0][kq+3][r]=vb.w;
  __syncthreads();

  float acc[2][4] = {};
  for (int t = 0; t < T; t++){
    const int cur = t & 1, nxt = cur ^ 1;
    if (t+1 < T){
      if (tid < 128) va = *(const float4*)(Aptr + (t+1)*16);
      vb = bok ? *(const float4*)(Bptr + (t+1)*16) : make_float4(0,0,0,0);
    }
    #pragma unroll
    for (int k = 0; k < 16; k++){
      float a0 = As[cur][k][ty*2+0];
      float a1 = As[cur][k][ty*2+1];
      float b0 = Bs[cur][k][tx*4+0];
      float b1 = Bs[cur][k][tx*4+1];
      float b2 = Bs[cur][k][tx*4+2];
      float b3 = Bs[cur][k][tx*4+3];
      acc[0][0] = fmaf(a0,b0,acc[0][0]); acc[0][1] = fmaf(a0,b1,acc[0][1]);
      acc[0][2] = fmaf(a0,b2,acc[0][2]); acc[0][3] = fmaf(a0,b3,acc[0][3]);
      acc[1][0] = fmaf(a1,b0,acc[1][0]); acc[1][1] = fmaf(a1,b1,acc[1][1]);
      acc[1][2] = fmaf(a1,b2,acc[1][2]); acc[1][3] = fmaf(a1,b3,acc[1][3]);
    }
    if (t+1 < T){
      if (tid < 128){
        As[nxt][kq+0][r]=va.x; As[nxt][kq+1][r]=va.y; As[nxt][kq+2][r]=va.z; As[nxt][kq+3][r]=va.w;
      }
      Bs[nxt][kq+0][r]=vb.x; Bs[nxt][kq+1][r]=vb.y; Bs[nxt][kq+2][r]=vb.z; Bs[nxt][kq+3][r]=vb.w;
    }
    __syncthreads();
  }

  #pragma unroll
  for (int i = 0; i < 2; i++){
    int m = m0 + ty*2 + i;
    float rs = rowscale ? rowscale[m] : 1.f;
    #pragma unroll
    for (int j = 0; j < 4; j++){
      int n = n0 + tx*4 + j;
      if (n >= N) continue;
      float v = acc[i][j] * rs;
      if (colscale) v *= colscale[n];
      if (bias1)    v += bias1[n];
      if (bias2)    v += bias2[n];
      C[(size_t)m*N + n] = v;
    }
  }
}

// ---------------- split-K NN GEMM for ro-partials: part[kc] = P_chunk @ Mn_chunk ----
// P: (1024 x 2048) row-major; Mn: (2048 x 128) row-major.
// grid.x = kchunk (8, 256 each), grid.y = rowtile (64, 16 rows each).
// 256 threads, 2x4 microtile (16 rows x 128 cols), dual-buffer + prefetch.
__global__ __launch_bounds__(256) void k_pv(const float* __restrict__ P, const float* __restrict__ Mn,
                                            float* __restrict__ part)
{
  __shared__ float Ps[2][16][20];    // [k][row], pad to 20
  __shared__ float Ms[2][16][132];   // [k][col], pad to 132
  const int kc0 = blockIdx.x*256, r0 = blockIdx.y*16;
  const int tid = threadIdx.x;
  const int tx = tid & 31, ty = tid >> 5;       // cols tx*4+j, rows ty*2+i
  const int pr = tid >> 2, pk = (tid & 3) << 2; // P load map (tid<64)
  const int mk = tid >> 4, mc = (tid & 15) << 3;// M load map
  const float* Pptr = P + (size_t)(r0 + (pr & 15))*2048 + kc0 + pk;
  const float* Mptr = Mn + (size_t)(kc0 + mk)*128 + mc;

  float4 vp, vm0, vm1;
  if (tid < 64) vp = *(const float4*)(Pptr);
  vm0 = *(const float4*)(Mptr);
  vm1 = *(const float4*)(Mptr + 4);
  if (tid < 64){
    Ps[0][pk+0][pr]=vp.x; Ps[0][pk+1][pr]=vp.y; Ps[0][pk+2][pr]=vp.z; Ps[0][pk+3][pr]=vp.w;
  }
  *(float4*)&Ms[0][mk][mc]   = vm0;
  *(float4*)&Ms[0][mk][mc+4] = vm1;
  __syncthreads();

  float acc[2][4] = {};
  #pragma unroll 2
  for (int t = 0; t < 16; t++){
    const int cur = t & 1, nxt = cur ^ 1;
    if (t+1 < 16){
      if (tid < 64) vp = *(const float4*)(Pptr + (t+1)*16);
      vm0 = *(const float4*)(Mptr + (size_t)(t+1)*16*128);
      vm1 = *(const float4*)(Mptr + (size_t)(t+1)*16*128 + 4);
    }
    #pragma unroll
    for (int k = 0; k < 16; k++){
      float a0 = Ps[cur][k][ty*2+0];
      float a1 = Ps[cur][k][ty*2+1];
      float b0 = Ms[cur][k][tx*4+0];
      float b1 = Ms[cur][k][tx*4+1];
      float b2 = Ms[cur][k][tx*4+2];
      float b3 = Ms[cur][k][tx*4+3];
      acc[0][0] = fmaf(a0,b0,acc[0][0]); acc[0][1] = fmaf(a0,b1,acc[0][1]);
      acc[0][2] = fmaf(a0,b2,acc[0][2]); acc[0][3] = fmaf(a0,b3,acc[0][3]);
      acc[1][0] = fmaf(a1,b0,acc[1][0]); acc[1][1] = fmaf(a1,b1,acc[1][1]);
      acc[1][2] = fmaf(a1,b2,acc[1][2]); acc[1][3] = fmaf(a1,b3,acc[1][3]);
    }
    if (t+1 < 16){
      if (tid < 64){
        Ps[nxt][pk+0][pr]=vp.x; Ps[nxt][pk+1][pr]=vp.y; Ps[nxt][pk+2][pr]=vp.z; Ps[nxt][pk+3][pr]=vp.w;
      }
      *(float4*)&Ms[nxt][mk][mc]   = vm0;
      *(float4*)&Ms[nxt][mk][mc+4] = vm1;
    }
    __syncthreads();
  }

  float* dst = part + (size_t)blockIdx.x*131072;
  #pragma unroll
  for (int i = 0; i < 2; i++){
    int row = r0 + ty*2 + i;
    float4 v = make_float4(acc[i][0], acc[i][1], acc[i][2], acc[i][3]);
    *(float4*)&dst[(size_t)row*128 + tx*4] = v;
  }
}

// combine split-K partials + read-mode mix:
// ro[row,d] = rm0[row]*sum_kc part[kc,row,d] + rm1[row]*bwm[d] + rm2[row]*fwm[d]
__global__ void k_rocomb(const float* __restrict__ part, const float* __restrict__ rm0,
                         const float* __restrict__ rm1, const float* __restrict__ rm2,
                         const float* __restrict__ bwm, const float* __restrict__ fwm,
                         float* __restrict__ ro){
  int idx = blockIdx.x*256 + threadIdx.x;   // 131072
  int row = idx >> 7, d = idx & 127;
  float s = 0.f;
  #pragma unroll
  for (int kc = 0; kc < 8; kc++) s += part[(size_t)kc*131072 + idx];
  ro[idx] = rm0[row]*s + rm1[row]*bwm[d] + rm2[row]*fwm[d];
}

// LSTM gate activation: h from g (B x 4096), torch gate order i,f,g,o; c0=h0=0
__global__ void k_lstm(const float* __restrict__ g, float* __restrict__ h){
  int idx = blockIdx.x*256 + threadIdx.x;    // 256*1024
  int b = idx >> 10, j = idx & 1023;
  const float* gr = g + (size_t)b*4096;
  float c = sigm(gr[j]) * tanhf(gr[2048 + j]);
  h[idx] = sigm(gr[3072 + j]) * tanhf(c);
}

// block reduce over 128 threads (2 waves), result broadcast to all threads
DEVI float blockReduce128(float v, float* lds2){
  #pragma unroll
  for (int o = 32; o > 0; o >>= 1) v += __shfl_xor(v, o);
  int w = threadIdx.x >> 6;
  __syncthreads();
  if ((threadIdx.x & 63) == 0) lds2[w] = v;
  __syncthreads();
  return lds2[0] + lds2[1];
}

// parse interface vector itf (B x 787) into all components
__global__ __launch_bounds__(128) void k_parse(const float* __restrict__ itf,
    float* __restrict__ wv, float* __restrict__ ev, float* __restrict__ av,
    float* __restrict__ wg_, float* __restrict__ ag_, float* __restrict__ invwv,
    float* __restrict__ rm0, float* __restrict__ rm1, float* __restrict__ rm2,
    float* __restrict__ rks)
{
  __shared__ float red[2];
  int b = blockIdx.x, t = threadIdx.x;
  const float* it = itf + (size_t)b*787;
  float wg = sigm(it[256]);
  float ag = sigm(it[257]);
  if (t == 0){ wg_[b] = wg; ag_[b] = ag; }
  float w = it[t];                       // write value
  wv[b*128 + t] = w;
  av[b*128 + t] = w * wg;
  ev[b*128 + t] = sigm(it[128 + t]) * wg;
  float ss = blockReduce128(w*w, red);
  if (t == 0) invwv[b] = 1.f / fmaxf(sqrtf(ss), 1e-12f);
  if (t < 4){
    int rr = t;
    float m0v = it[259 + rr*3 + 0], m1v = it[259 + rr*3 + 1], m2v = it[259 + rr*3 + 2];
    float mx = fmaxf(m0v, fmaxf(m1v, m2v));
    float e0 = expf(m0v - mx), e1 = expf(m1v - mx), e2 = expf(m2v - mx);
    float inv = 1.f / (e0 + e1 + e2);
    rm0[b*4 + rr] = e0*inv; rm1[b*4 + rr] = e1*inv; rm2[b*4 + rr] = e2*inv;
  }
  #pragma unroll
  for (int rr = 0; rr < 4; rr++){
    float kv = it[275 + rr*128 + t];
    float ks = blockReduce128(kv*kv, red);
    float sx = it[271 + rr];
    float str = fmaxf(sx, 0.f) + log1pf(expf(-fabsf(sx)));  // softplus
    float invk = 1.f / fmaxf(sqrtf(ks), 1e-12f);
    rks[((size_t)b*4 + rr)*128 + t] = kv * invk * str;      // normalized key * strength
  }
}

// allocation weighting, sort-free: alloc[n] = u[n] * prod_{m stably-before n}(1-u[m])
__global__ __launch_bounds__(256) void k_alloc(const float* __restrict__ usage, float* __restrict__ out){
  __shared__ float red[4];
  int n = blockIdx.x, t = threadIdx.x;
  float un = usage[n];
  float prod = 1.f;
  #pragma unroll
  for (int i = 0; i < 8; i++){
    int m = t + i*256;
    float um = usage[m];
    bool before = (um < un) || (um == un && m < n);
    prod *= before ? (1.f - um) : 1.f;
  }
  #pragma unroll
  for (int o = 32; o > 0; o >>= 1) prod *= __shfl_xor(prod, o);
  if ((t & 63) == 0) red[t >> 6] = prod;
  __syncthreads();
  if (t == 0) out[n] = un * (red[0]*red[1]) * (red[2]*red[3]);
}

// in-place row softmax, rows of length 2048, one block (256 thr) per row
__global__ __launch_bounds__(256) void k_softmax2048(float* __restrict__ P){
  __shared__ float red[4];
  float* p = P + (size_t)blockIdx.x*2048;
  int t = threadIdx.x;
  float r[8];
  float mx = -3.4e38f;
  #pragma unroll
  for (int i = 0; i < 8; i++){ r[i] = p[t + i*256]; mx = fmaxf(mx, r[i]); }
  #pragma unroll
  for (int o = 32; o > 0; o >>= 1) mx = fmaxf(mx, __shfl_xor(mx, o));
  if ((t & 63) == 0) red[t >> 6] = mx;
  __syncthreads();
  mx = fmaxf(fmaxf(red[0], red[1]), fmaxf(red[2], red[3]));
  float s = 0.f;
  #pragma unroll
  for (int i = 0; i < 8; i++){ r[i] = expf(r[i] - mx); s += r[i]; }
  #pragma unroll
  for (int o = 32; o > 0; o >>= 1) s += __shfl_xor(s, o);
  __syncthreads();
  if ((t & 63) == 0) red[t >> 6] = s;
  __syncthreads();
  s = red[0] + red[1] + red[2] + red[3];
  float inv = 1.f / s;
  #pragma unroll
  for (int i = 0; i < 8; i++) p[t + i*256] = r[i]*inv;
}

// ww[b,n] = wg[b] * (0.5*cw[b,n] + 0.5*alloc[n]*ag[b])   (in place over cw)
__global__ void k_writew(float* __restrict__ cw, const float* __restrict__ alloc,
                         const float* __restrict__ wg, const float* __restrict__ ag){
  int idx = blockIdx.x*256 + threadIdx.x;  // 256*2048
  int b = idx >> 11, n = idx & 2047;
  cw[idx] = wg[b] * (0.5f*cw[idx] + 0.5f*alloc[n]*ag[b]);
}

// generic row sums (wave per row)
__global__ void k_rowsum(const float* __restrict__ A, float* __restrict__ out, int rows, int cols){
  int w = (blockIdx.x*blockDim.x + threadIdx.x) >> 6;
  int lane = threadIdx.x & 63;
  if (w >= rows) return;
  const float* a = A + (size_t)w*cols;
  float s = 0.f;
  for (int c = lane; c < cols; c += 64) s += a[c];
  #pragma unroll
  for (int o = 32; o > 0; o >>= 1) s += __shfl_down(s, o);
  if (lane == 0) out[w] = s;
}

// column sums of a (2048 x 2048) matrix via partial + atomicAdd (out must be zeroed)
__global__ void k_colsum2048(const float* __restrict__ A, float* __restrict__ out){
  int c = blockIdx.x*256 + threadIdx.x;
  int r0 = blockIdx.y*128;
  float s = 0.f;
  for (int rr = 0; rr < 128; rr++) s += A[(size_t)(r0+rr)*2048 + c];
  atomicAdd(&out[c], s);
}

// bw[m] = (0.9*colsum_link[m] + 0.1*lusum[m]) / N ; fw with rowsum_link. lu symmetric.
__global__ __launch_bounds__(1024) void k_bwfw(const float* __restrict__ ww, const float* __restrict__ tb,
                       const float* __restrict__ rowsum, const float* __restrict__ colsum,
                       float* __restrict__ bw, float* __restrict__ fw){
  __shared__ float sq[4][256], sd[4][256];
  int t = threadIdx.x & 255, z = threadIdx.x >> 8;
  int m = blockIdx.x*256 + t;   // 8 blocks
  float q = 0.f, dd = 0.f;
  for (int b = z*64; b < z*64 + 64; b++){
    float w = ww[(size_t)b*2048 + m];
    q  = fmaf(tb[b], w, q);
    dd = fmaf(w, w, dd);
  }
  sq[z][t] = q; sd[z][t] = dd;
  __syncthreads();
  if (z == 0){
    q  = sq[0][t] + sq[1][t] + sq[2][t] + sq[3][t];
    dd = sd[0][t] + sd[1][t] + sd[2][t] + sd[3][t];
    float lus = (q - dd) * (1.f/256.f);     // colsum(lu)[m] - lu[m,m]
    bw[m] = (0.9f*colsum[m] + 0.1f*lus) * (1.f/2048.f);
    fw[m] = (0.9f*rowsum[m] + 0.1f*lus) * (1.f/2048.f);
  }
}

// mem_new = memory*(1 - ww^T@ev/B) + ww^T@av/B   (TN gemm, M=2048 n, N=128 d, K=256 b)
__global__ __launch_bounds__(256) void k_memupdate(const float* __restrict__ ww,
    const float* __restrict__ ev, const float* __restrict__ av,
    const float* __restrict__ mem, float* __restrict__ memn)
{
  __shared__ float Ws[16][68], Es[16][68], Vs[16][68];
  int m0 = blockIdx.y*64, n0 = blockIdx.x*64;
  int tid = threadIdx.x, tx = tid & 15, ty = tid >> 4;
  int kk = tid >> 4, col = (tid & 15) << 2;
  float ae[4][4] = {}, aa[4][4] = {};
  for (int k0 = 0; k0 < 256; k0 += 16){
    float4 vw  = *(const float4*)(ww + (size_t)(k0+kk)*2048 + m0 + col);
    float4 vev = *(const float4*)(ev + (size_t)(k0+kk)*128  + n0 + col);
    float4 vav = *(const float4*)(av + (size_t)(k0+kk)*128  + n0 + col);
    Ws[kk][col]=vw.x;  Ws[kk][col+1]=vw.y;  Ws[kk][col+2]=vw.z;  Ws[kk][col+3]=vw.w;
    Es[kk][col]=vev.x; Es[kk][col+1]=vev.y; Es[kk][col+2]=vev.z; Es[kk][col+3]=vev.w;
    Vs[kk][col]=vav.x; Vs[kk][col+1]=vav.y; Vs[kk][col+2]=vav.z; Vs[kk][col+3]=vav.w;
    __syncthreads();
    #pragma unroll
    for (int k = 0; k < 16; k++){
      float a[4], e[4], v[4];
      #pragma unroll
      for (int i = 0; i < 4; i++) a[i] = Ws[k][ty*4+i];
      #pragma unroll
      for (int j = 0; j < 4; j++){ e[j] = Es[k][tx*4+j]; v[j] = Vs[k][tx*4+j]; }
      #pragma unroll
      for (int i = 0; i < 4; i++)
        #pragma unroll
        for (int j = 0; j < 4; j++){
          ae[i][j] = fmaf(a[i], e[j], ae[i][j]);
          aa[i][j] = fmaf(a[i], v[j], aa[i][j]);
        }
    }
    __syncthreads();
  }
  #pragma unroll
  for (int i = 0; i < 4; i++){
    int n = m0 + ty*4 + i;
    #pragma unroll
    for (int j = 0; j < 4; j++){
      int d = n0 + tx*4 + j;
      float em = ae[i][j] * (1.f/256.f);
      float am = aa[i][j] * (1.f/256.f);
      memn[(size_t)n*128 + d] = mem[(size_t)n*128 + d] * (1.f - em) + am;
    }
  }
}

// partial bwm[d] = sum_n bw[n]*mem_new[n,d] (atomic, pre-zeroed); fwm likewise
__global__ __launch_bounds__(256) void k_bwmfwm_part(const float* __restrict__ memn,
    const float* __restrict__ bw, const float* __restrict__ fw,
    float* __restrict__ bwm, float* __restrict__ fwm)
{
  __shared__ float sb[2][128], sf[2][128];
  int d = threadIdx.x & 127, g = threadIdx.x >> 7;
  int n0 = blockIdx.x*64;
  float ab = 0.f, af = 0.f;
  #pragma unroll 4
  for (int i = g; i < 64; i += 2){
    float m = memn[(size_t)(n0+i)*128 + d];
    ab = fmaf(bw[n0+i], m, ab);
    af = fmaf(fw[n0+i], m, af);
  }
  sb[g][d] = ab; sf[g][d] = af;
  __syncthreads();
  if (g == 0){
    atomicAdd(&bwm[d], sb[0][d] + sb[1][d]);
    atomicAdd(&fwm[d], sf[0][d] + sf[1][d]);
  }
}

// hro = concat(h, read_out) per batch row
__global__ void k_hro(const float* __restrict__ h, const float* __restrict__ ro, float* __restrict__ hro){
  int idx = blockIdx.x*256 + threadIdx.x;   // 256*1536
  int b = idx / 1536, k = idx - b*1536;
  hro[idx] = (k < 1024) ? h[b*1024 + k] : ro[b*512 + k - 1024];
}

// ---------------- launcher ----------------

extern "C" void kernel_launch(void* const* d_in, const int* in_sizes, int n_in,
                              void* d_out, int out_size, void* d_ws, size_t ws_size,
                              hipStream_t stream)
{
  const float* x     = (const float*)d_in[0];
  const float* mem   = (const float*)d_in[1];
  const float* usage = (const float*)d_in[2];
  const float* link  = (const float*)d_in[3];
  const float* W_ih  = (const float*)d_in[4];
  // d_in[5] = W_hh: unused (h0 = 0)
  const float* b_ih  = (const float*)d_in[6];
  const float* b_hh  = (const float*)d_in[7];
  const float* W_if  = (const float*)d_in[8];
  const float* b_if  = (const float*)d_in[9];
  const float* W_out = (const float*)d_in[10];
  const float* b_out = (const float*)d_in[11];
  float* out = (float*)d_out;
  float* ws  = (float*)d_ws;

  // atomic accumulators first (one contiguous zero region of 2432 floats)
  float* cm     = ws + 0;         // 128  (column SUM of memory)
  float* csl    = ws + 128;       // 2048 colsum(link)
  float* bwm    = ws + 2176;      // 128
  float* fwm    = ws + 2304;      // 128
  float* rn_mem = ws + 2432;      // 2048
  float* rn_new = ws + 4480;      // 2048
  float* rsl    = ws + 6528;      // 2048 rowsum(link)
  float* tb     = ws + 8576;      // 256
  float* bw     = ws + 8832;      // 2048
  float* fw     = ws + 10880;     // 2048
  float* wg     = ws + 12928;     // 256
  float* ag     = ws + 13184;     // 256
  float* invwv  = ws + 13440;     // 256
  float* rm0    = ws + 13696;     // 1024
  float* rm1    = ws + 14720;     // 1024
  float* rm2    = ws + 15744;     // 1024
  float* alloc  = ws + 16768;     // 2048
  float* wv     = ws + 18816;     // 32768  (B x 128)
  float* ev     = ws + 51584;     // 32768
  float* av     = ws + 84352;     // 32768
  float* rks    = ws + 117120;    // 131072 (B*R x 128)
  float* cin    = ws + 248192;    // 393216 (B x 1536)
  float* g      = ws + 641408;    // 1048576 (B x 4096); dead after k_lstm -> reused as k_pv partials (8x131072)
  float* h      = ws + 1689984;   // 262144 (B x 1024)
  float* itf    = ws + 1952128;   // 201472 (B x 787)
  float* ww     = ws + 2153856;   // 524288 (B x 2048): cw logits -> cw -> write_w
  float* memn   = ws + 2678144;   // 262144 (2048 x 128)
  float* sim    = ws + 2940288;   // 2097152 (B*R x 2048): logits -> softmax P
  float* ro     = ws + 5037440;   // 131072 (B x R*D)
  float* hro    = ws + 5168512;   // 393216 (B x 1536)
  // total = 5,561,728 floats = 22.2 MB

  // stage 0: zero all atomic accumulators (cm, csl, bwm, fwm contiguous)
  k_zero<<<10, 256, 0, stream>>>(ws, 2432);

  // stage 1: controller input
  k_colmean_part<<<32, 256, 0, stream>>>(mem, cm);
  k_rownorm128  <<<512, 256, 0, stream>>>(mem, rn_mem, 2048);
  k_cin         <<<1536, 256, 0, stream>>>(x, cm, cin);

  // stage 2: LSTM controller  (grid: N/64 x M/32)
  gemm_nt<<<dim3(64,8), 256, 0, stream>>>(cin, W_ih, g, 256, 4096, 1536, b_ih, b_hh, nullptr, nullptr);
  k_lstm <<<1024, 256, 0, stream>>>(g, h);

  // stage 3: interface
  gemm_nt<<<dim3(13,8), 256, 0, stream>>>(h, W_if, itf, 256, 787, 1024, b_if, nullptr, nullptr, nullptr);
  k_parse<<<256, 128, 0, stream>>>(itf, wv, ev, av, wg, ag, invwv, rm0, rm1, rm2, rks);

  // stage 4: write weighting
  k_alloc<<<2048, 256, 0, stream>>>(usage, alloc);
  gemm_nt<<<dim3(32,8), 256, 0, stream>>>(wv, mem, ww, 256, 2048, 128, nullptr, nullptr, invwv, rn_mem);
  k_softmax2048<<<256, 256, 0, stream>>>(ww);
  k_writew<<<2048, 256, 0, stream>>>(ww, alloc, wg, ag);

  // stage 5: link-derived read vectors (link_new never materialized)
  k_rowsum<<<512, 256, 0, stream>>>(link, rsl, 2048, 2048);
  k_colsum2048<<<dim3(8,16), 256, 0, stream>>>(link, csl);
  k_rowsum<<<64, 256, 0, stream>>>(ww, tb, 256, 2048);
  k_bwfw  <<<8, 1024, 0, stream>>>(ww, tb, rsl, csl, bw, fw);

  // stage 6: memory update
  k_memupdate <<<dim3(2,32), 256, 0, stream>>>(ww, ev, av, mem, memn);
  k_rownorm128<<<512, 256, 0, stream>>>(memn, rn_new, 2048);
  k_bwmfwm_part<<<32, 256, 0, stream>>>(memn, bw, fw, bwm, fwm);

  // stage 7: read addressing + read output (split-K PV into g, then combine)
  gemm_nt<<<dim3(32,32), 256, 0, stream>>>(rks, memn, sim, 1024, 2048, 128, nullptr, nullptr, nullptr, rn_new);
  k_softmax2048<<<1024, 256, 0, stream>>>(sim);
  k_pv    <<<dim3(8,64), 256, 0, stream>>>(sim, memn, g);
  k_rocomb<<<512, 256, 0, stream>>>(g, rm0, rm1, rm2, bwm, fwm, ro);

  // stage 8: output projection
  k_hro  <<<1536, 256, 0, stream>>>(h, ro, hro);
  gemm_nt<<<dim3(16,8), 256, 0, stream>>>(hro, W_out, out, 256, 1024, 1536, b_out, nullptr, nullptr, nullptr);

  (void)in_sizes; (void)n_in; (void)out_size; (void)ws_size;
}

// Round 6
// 356.534 us; speedup vs baseline: 2.4146x; 1.2672x over previous
//
#include <hip/hip_runtime.h>
#include <cmath>

#define DEVI __device__ __forceinline__

DEVI float sigm(float x){ return 1.f/(1.f+expf(-x)); }

typedef __attribute__((ext_vector_type(8))) short short8;
typedef __attribute__((ext_vector_type(8))) unsigned short us8v;
typedef __attribute__((ext_vector_type(4))) float float4v;

// ---------------- small utility kernels ----------------

__global__ void k_zero(float* __restrict__ p, int n){
  int i = blockIdx.x*256 + threadIdx.x;
  if (i < n) p[i] = 0.f;
}

// partial column sums of memory (2048 x 128) -> cm[128] (atomic, cm pre-zeroed)
__global__ __launch_bounds__(256) void k_colmean_part(const float* __restrict__ mem, float* __restrict__ cm){
  __shared__ float s[2][128];
  int d = threadIdx.x & 127, g = threadIdx.x >> 7;
  int n0 = blockIdx.x*64;
  float a = 0.f;
  #pragma unroll 4
  for (int i = g; i < 64; i += 2) a += mem[(size_t)(n0+i)*128 + d];
  s[g][d] = a;
  __syncthreads();
  if (g == 0) atomicAdd(&cm[d], s[0][d] + s[1][d]);
}

// inverse L2 norm of each 128-wide row (wave per row)
__global__ __launch_bounds__(256) void k_rownorm128(const float* __restrict__ A, float* __restrict__ invn, int rows){
  int w = (blockIdx.x*blockDim.x + threadIdx.x) >> 6;
  int lane = threadIdx.x & 63;
  if (w >= rows) return;
  const float* a = A + (size_t)w*128;
  float x0 = a[lane], x1 = a[lane+64];
  float s = x0*x0 + x1*x1;
  #pragma unroll
  for (int o = 32; o > 0; o >>= 1) s += __shfl_down(s, o);
  if (lane == 0) invn[w] = 1.f / fmaxf(sqrtf(s), 1e-12f);
}

// cin[b,k] = k<1024 ? x[b,k] : cm[(k-1024)%128]/2048
__global__ void k_cin(const float* __restrict__ x, const float* __restrict__ cm, float* __restrict__ cin){
  int idx = blockIdx.x*256 + threadIdx.x;     // 256*1536
  int b = idx / 1536, k = idx - b*1536;
  cin[idx] = (k < 1024) ? x[b*1024 + k] : cm[(k-1024) & 127] * (1.f/2048.f);
}

// ---------------- fp32 NT GEMM (kept for K=128 cases with scales) ----------------
// 32x64 tile, 256 threads, 2x4 microtile, dual-buffered LDS + register prefetch.
__global__ __launch_bounds__(256) void gemm_nt(
    const float* __restrict__ A, const float* __restrict__ Bm, float* __restrict__ C,
    int M, int N, int K,
    const float* __restrict__ bias1, const float* __restrict__ bias2,
    const float* __restrict__ rowscale, const float* __restrict__ colscale)
{
  __shared__ float As[2][16][36];
  __shared__ float Bs[2][16][68];
  const int m0 = blockIdx.y*32, n0 = blockIdx.x*64;
  const int tid = threadIdx.x;
  const int tx = tid & 15, ty = tid >> 4;
  const int r = tid >> 2, kq = (tid & 3) << 2;
  const int T = K >> 4;
  const int gn = n0 + r;
  const bool bok = (gn < N);
  const float* Aptr = A + (size_t)(m0 + (r & 31))*K + kq;
  const float* Bptr = bok ? (Bm + (size_t)gn*K + kq) : Bm;

  float4 va, vb;
  if (tid < 128) va = *(const float4*)(Aptr);
  vb = bok ? *(const float4*)(Bptr) : make_float4(0,0,0,0);
  if (tid < 128){
    As[0][kq+0][r]=va.x; As[0][kq+1][r]=va.y; As[0][kq+2][r]=va.z; As[0][kq+3][r]=va.w;
  }
  Bs[0][kq+0][r]=vb.x; Bs[0][kq+1][r]=vb.y; Bs[0][kq+2][r]=vb.z; Bs[0][kq+3][r]=vb.w;
  __syncthreads();

  float acc[2][4] = {};
  for (int t = 0; t < T; t++){
    const int cur = t & 1, nxt = cur ^ 1;
    if (t+1 < T){
      if (tid < 128) va = *(const float4*)(Aptr + (t+1)*16);
      vb = bok ? *(const float4*)(Bptr + (t+1)*16) : make_float4(0,0,0,0);
    }
    #pragma unroll
    for (int k = 0; k < 16; k++){
      float a0 = As[cur][k][ty*2+0];
      float a1 = As[cur][k][ty*2+1];
      float b0 = Bs[cur][k][tx*4+0];
      float b1 = Bs[cur][k][tx*4+1];
      float b2 = Bs[cur][k][tx*4+2];
      float b3 = Bs[cur][k][tx*4+3];
      acc[0][0] = fmaf(a0,b0,acc[0][0]); acc[0][1] = fmaf(a0,b1,acc[0][1]);
      acc[0][2] = fmaf(a0,b2,acc[0][2]); acc[0][3] = fmaf(a0,b3,acc[0][3]);
      acc[1][0] = fmaf(a1,b0,acc[1][0]); acc[1][1] = fmaf(a1,b1,acc[1][1]);
      acc[1][2] = fmaf(a1,b2,acc[1][2]); acc[1][3] = fmaf(a1,b3,acc[1][3]);
    }
    if (t+1 < T){
      if (tid < 128){
        As[nxt][kq+0][r]=va.x; As[nxt][kq+1][r]=va.y; As[nxt][kq+2][r]=va.z; As[nxt][kq+3][r]=va.w;
      }
      Bs[nxt][kq+0][r]=vb.x; Bs[nxt][kq+1][r]=vb.y; Bs[nxt][kq+2][r]=vb.z; Bs[nxt][kq+3][r]=vb.w;
    }
    __syncthreads();
  }

  #pragma unroll
  for (int i = 0; i < 2; i++){
    int m = m0 + ty*2 + i;
    float rs = rowscale ? rowscale[m] : 1.f;
    #pragma unroll
    for (int j = 0; j < 4; j++){
      int n = n0 + tx*4 + j;
      if (n >= N) continue;
      float v = acc[i][j] * rs;
      if (colscale) v *= colscale[n];
      if (bias1)    v += bias1[n];
      if (bias2)    v += bias2[n];
      C[(size_t)m*N + n] = v;
    }
  }
}

// ---------------- split-bf16 MFMA NT GEMM: C = A @ B^T + bias1 + bias2 ----------------
// fp32 in HBM; staged to LDS as bf16 hi+lo; 3 MFMAs (hh, hl, lh) per 16x16x32 tile.
// BM=32, BN=64, BK=32, 256 threads (4 waves). M%32==0, K%32==0 required; N guarded.
DEVI us8v cvt_hi8(const float* f){
  us8v h;
  #pragma unroll
  for (int j = 0; j < 8; j++) h[j] = (unsigned short)(__float_as_uint(f[j]) >> 16);
  return h;
}
DEVI us8v cvt_lo8(const float* f){
  us8v l;
  #pragma unroll
  for (int j = 0; j < 8; j++){
    float hi = __uint_as_float(__float_as_uint(f[j]) & 0xFFFF0000u);
    l[j] = (unsigned short)(__float_as_uint(f[j] - hi) >> 16);
  }
  return l;
}

__global__ __launch_bounds__(256) void gemm_nt_bf16s(
    const float* __restrict__ A, const float* __restrict__ Bm, float* __restrict__ C,
    int M, int N, int K,
    const float* __restrict__ bias1, const float* __restrict__ bias2)
{
  __shared__ unsigned short Ah[2][4][32][8], Al[2][4][32][8];   // 4+4 KB
  __shared__ unsigned short Bh[2][4][64][8], Bl[2][4][64][8];   // 8+8 KB
  const int tid = threadIdx.x;
  const int m0 = blockIdx.y*32, n0 = blockIdx.x*64;
  const int T = K >> 5;
  // staging maps
  const int rowA = (tid >> 2) & 31, qA = tid & 3;   // tid<128 active for A
  const int nB = tid >> 2, qB = tid & 3;            // all 256 for B
  const float* Aptr = A + (size_t)(m0 + rowA)*K + qA*8;
  int nBc = n0 + nB; if (nBc >= N) nBc = N - 1;     // clamp; guarded at store
  const float* Bptr = Bm + (size_t)nBc*K + qB*8;
  // fragment maps
  const int wv = tid >> 6, lane = tid & 63;
  const int fq = lane >> 4, fr = lane & 15;
  const int m16 = (wv & 1)*16, nb = (wv >> 1)*32;

  float ga[8], gb[8];
  if (tid < 128){ *(float4*)&ga[0] = *(const float4*)(Aptr); *(float4*)&ga[4] = *(const float4*)(Aptr + 4); }
  *(float4*)&gb[0] = *(const float4*)(Bptr); *(float4*)&gb[4] = *(const float4*)(Bptr + 4);
  if (tid < 128){
    *(us8v*)&Ah[0][qA][rowA][0] = cvt_hi8(ga);
    *(us8v*)&Al[0][qA][rowA][0] = cvt_lo8(ga);
  }
  *(us8v*)&Bh[0][qB][nB][0] = cvt_hi8(gb);
  *(us8v*)&Bl[0][qB][nB][0] = cvt_lo8(gb);
  __syncthreads();

  float4v acc0 = {0.f,0.f,0.f,0.f}, acc1 = {0.f,0.f,0.f,0.f};
  for (int t = 0; t < T; t++){
    const int cur = t & 1, nxt = cur ^ 1;
    if (t+1 < T){
      if (tid < 128){ *(float4*)&ga[0] = *(const float4*)(Aptr + (t+1)*32); *(float4*)&ga[4] = *(const float4*)(Aptr + (t+1)*32 + 4); }
      *(float4*)&gb[0] = *(const float4*)(Bptr + (t+1)*32); *(float4*)&gb[4] = *(const float4*)(Bptr + (t+1)*32 + 4);
    }
    short8 ah  = *(short8*)&Ah[cur][fq][m16+fr][0];
    short8 alo = *(short8*)&Al[cur][fq][m16+fr][0];
    short8 b0h = *(short8*)&Bh[cur][fq][nb+fr][0];
    short8 b0l = *(short8*)&Bl[cur][fq][nb+fr][0];
    short8 b1h = *(short8*)&Bh[cur][fq][nb+16+fr][0];
    short8 b1l = *(short8*)&Bl[cur][fq][nb+16+fr][0];
    acc0 = __builtin_amdgcn_mfma_f32_16x16x32_bf16(ah,  b0h, acc0, 0, 0, 0);
    acc1 = __builtin_amdgcn_mfma_f32_16x16x32_bf16(ah,  b1h, acc1, 0, 0, 0);
    acc0 = __builtin_amdgcn_mfma_f32_16x16x32_bf16(ah,  b0l, acc0, 0, 0, 0);
    acc1 = __builtin_amdgcn_mfma_f32_16x16x32_bf16(ah,  b1l, acc1, 0, 0, 0);
    acc0 = __builtin_amdgcn_mfma_f32_16x16x32_bf16(alo, b0h, acc0, 0, 0, 0);
    acc1 = __builtin_amdgcn_mfma_f32_16x16x32_bf16(alo, b1h, acc1, 0, 0, 0);
    if (t+1 < T){
      if (tid < 128){
        *(us8v*)&Ah[nxt][qA][rowA][0] = cvt_hi8(ga);
        *(us8v*)&Al[nxt][qA][rowA][0] = cvt_lo8(ga);
      }
      *(us8v*)&Bh[nxt][qB][nB][0] = cvt_hi8(gb);
      *(us8v*)&Bl[nxt][qB][nB][0] = cvt_lo8(gb);
    }
    __syncthreads();
  }

  // epilogue: C/D layout col=lane&15, row=(lane>>4)*4+reg (m89/m91-verified)
  const int colA = n0 + nb + fr, colB = colA + 16;
  #pragma unroll
  for (int i = 0; i < 4; i++){
    int m = m0 + m16 + fq*4 + i;
    if (colA < N){
      float v = acc0[i];
      if (bias1) v += bias1[colA];
      if (bias2) v += bias2[colA];
      C[(size_t)m*N + colA] = v;
    }
    if (colB < N){
      float v = acc1[i];
      if (bias1) v += bias1[colB];
      if (bias2) v += bias2[colB];
      C[(size_t)m*N + colB] = v;
    }
  }
}

// ---------------- split-K NN GEMM for ro-partials: part[kc] = P_chunk @ Mn_chunk ----
__global__ __launch_bounds__(256) void k_pv(const float* __restrict__ P, const float* __restrict__ Mn,
                                            float* __restrict__ part)
{
  __shared__ float Ps[2][16][20];
  __shared__ float Ms[2][16][132];
  const int kc0 = blockIdx.x*256, r0 = blockIdx.y*16;
  const int tid = threadIdx.x;
  const int tx = tid & 31, ty = tid >> 5;
  const int pr = tid >> 2, pk = (tid & 3) << 2;
  const int mk = tid >> 4, mc = (tid & 15) << 3;
  const float* Pptr = P + (size_t)(r0 + (pr & 15))*2048 + kc0 + pk;
  const float* Mptr = Mn + (size_t)(kc0 + mk)*128 + mc;

  float4 vp, vm0, vm1;
  if (tid < 64) vp = *(const float4*)(Pptr);
  vm0 = *(const float4*)(Mptr);
  vm1 = *(const float4*)(Mptr + 4);
  if (tid < 64){
    Ps[0][pk+0][pr]=vp.x; Ps[0][pk+1][pr]=vp.y; Ps[0][pk+2][pr]=vp.z; Ps[0][pk+3][pr]=vp.w;
  }
  *(float4*)&Ms[0][mk][mc]   = vm0;
  *(float4*)&Ms[0][mk][mc+4] = vm1;
  __syncthreads();

  float acc[2][4] = {};
  #pragma unroll 2
  for (int t = 0; t < 16; t++){
    const int cur = t & 1, nxt = cur ^ 1;
    if (t+1 < 16){
      if (tid < 64) vp = *(const float4*)(Pptr + (t+1)*16);
      vm0 = *(const float4*)(Mptr + (size_t)(t+1)*16*128);
      vm1 = *(const float4*)(Mptr + (size_t)(t+1)*16*128 + 4);
    }
    #pragma unroll
    for (int k = 0; k < 16; k++){
      float a0 = Ps[cur][k][ty*2+0];
      float a1 = Ps[cur][k][ty*2+1];
      float b0 = Ms[cur][k][tx*4+0];
      float b1 = Ms[cur][k][tx*4+1];
      float b2 = Ms[cur][k][tx*4+2];
      float b3 = Ms[cur][k][tx*4+3];
      acc[0][0] = fmaf(a0,b0,acc[0][0]); acc[0][1] = fmaf(a0,b1,acc[0][1]);
      acc[0][2] = fmaf(a0,b2,acc[0][2]); acc[0][3] = fmaf(a0,b3,acc[0][3]);
      acc[1][0] = fmaf(a1,b0,acc[1][0]); acc[1][1] = fmaf(a1,b1,acc[1][1]);
      acc[1][2] = fmaf(a1,b2,acc[1][2]); acc[1][3] = fmaf(a1,b3,acc[1][3]);
    }
    if (t+1 < 16){
      if (tid < 64){
        Ps[nxt][pk+0][pr]=vp.x; Ps[nxt][pk+1][pr]=vp.y; Ps[nxt][pk+2][pr]=vp.z; Ps[nxt][pk+3][pr]=vp.w;
      }
      *(float4*)&Ms[nxt][mk][mc]   = vm0;
      *(float4*)&Ms[nxt][mk][mc+4] = vm1;
    }
    __syncthreads();
  }

  float* dst = part + (size_t)blockIdx.x*131072;
  #pragma unroll
  for (int i = 0; i < 2; i++){
    int row = r0 + ty*2 + i;
    float4 v = make_float4(acc[i][0], acc[i][1], acc[i][2], acc[i][3]);
    *(float4*)&dst[(size_t)row*128 + tx*4] = v;
  }
}

// combine split-K partials + read-mode mix
__global__ void k_rocomb(const float* __restrict__ part, const float* __restrict__ rm0,
                         const float* __restrict__ rm1, const float* __restrict__ rm2,
                         const float* __restrict__ bwm, const float* __restrict__ fwm,
                         float* __restrict__ ro){
  int idx = blockIdx.x*256 + threadIdx.x;   // 131072
  int row = idx >> 7, d = idx & 127;
  float s = 0.f;
  #pragma unroll
  for (int kc = 0; kc < 8; kc++) s += part[(size_t)kc*131072 + idx];
  ro[idx] = rm0[row]*s + rm1[row]*bwm[d] + rm2[row]*fwm[d];
}

// LSTM gate activation
__global__ void k_lstm(const float* __restrict__ g, float* __restrict__ h){
  int idx = blockIdx.x*256 + threadIdx.x;    // 256*1024
  int b = idx >> 10, j = idx & 1023;
  const float* gr = g + (size_t)b*4096;
  float c = sigm(gr[j]) * tanhf(gr[2048 + j]);
  h[idx] = sigm(gr[3072 + j]) * tanhf(c);
}

DEVI float blockReduce128(float v, float* lds2){
  #pragma unroll
  for (int o = 32; o > 0; o >>= 1) v += __shfl_xor(v, o);
  int w = threadIdx.x >> 6;
  __syncthreads();
  if ((threadIdx.x & 63) == 0) lds2[w] = v;
  __syncthreads();
  return lds2[0] + lds2[1];
}

// parse interface vector itf (B x 787)
__global__ __launch_bounds__(128) void k_parse(const float* __restrict__ itf,
    float* __restrict__ wv, float* __restrict__ ev, float* __restrict__ av,
    float* __restrict__ wg_, float* __restrict__ ag_, float* __restrict__ invwv,
    float* __restrict__ rm0, float* __restrict__ rm1, float* __restrict__ rm2,
    float* __restrict__ rks)
{
  __shared__ float red[2];
  int b = blockIdx.x, t = threadIdx.x;
  const float* it = itf + (size_t)b*787;
  float wg = sigm(it[256]);
  float ag = sigm(it[257]);
  if (t == 0){ wg_[b] = wg; ag_[b] = ag; }
  float w = it[t];
  wv[b*128 + t] = w;
  av[b*128 + t] = w * wg;
  ev[b*128 + t] = sigm(it[128 + t]) * wg;
  float ss = blockReduce128(w*w, red);
  if (t == 0) invwv[b] = 1.f / fmaxf(sqrtf(ss), 1e-12f);
  if (t < 4){
    int rr = t;
    float m0v = it[259 + rr*3 + 0], m1v = it[259 + rr*3 + 1], m2v = it[259 + rr*3 + 2];
    float mx = fmaxf(m0v, fmaxf(m1v, m2v));
    float e0 = expf(m0v - mx), e1 = expf(m1v - mx), e2 = expf(m2v - mx);
    float inv = 1.f / (e0 + e1 + e2);
    rm0[b*4 + rr] = e0*inv; rm1[b*4 + rr] = e1*inv; rm2[b*4 + rr] = e2*inv;
  }
  #pragma unroll
  for (int rr = 0; rr < 4; rr++){
    float kv = it[275 + rr*128 + t];
    float ks = blockReduce128(kv*kv, red);
    float sx = it[271 + rr];
    float str = fmaxf(sx, 0.f) + log1pf(expf(-fabsf(sx)));
    float invk = 1.f / fmaxf(sqrtf(ks), 1e-12f);
    rks[((size_t)b*4 + rr)*128 + t] = kv * invk * str;
  }
}

// allocation weighting, sort-free
__global__ __launch_bounds__(256) void k_alloc(const float* __restrict__ usage, float* __restrict__ out){
  __shared__ float red[4];
  int n = blockIdx.x, t = threadIdx.x;
  float un = usage[n];
  float prod = 1.f;
  #pragma unroll
  for (int i = 0; i < 8; i++){
    int m = t + i*256;
    float um = usage[m];
    bool before = (um < un) || (um == un && m < n);
    prod *= before ? (1.f - um) : 1.f;
  }
  #pragma unroll
  for (int o = 32; o > 0; o >>= 1) prod *= __shfl_xor(prod, o);
  if ((t & 63) == 0) red[t >> 6] = prod;
  __syncthreads();
  if (t == 0) out[n] = un * (red[0]*red[1]) * (red[2]*red[3]);
}

// in-place row softmax, rows of length 2048
__global__ __launch_bounds__(256) void k_softmax2048(float* __restrict__ P){
  __shared__ float red[4];
  float* p = P + (size_t)blockIdx.x*2048;
  int t = threadIdx.x;
  float r[8];
  float mx = -3.4e38f;
  #pragma unroll
  for (int i = 0; i < 8; i++){ r[i] = p[t + i*256]; mx = fmaxf(mx, r[i]); }
  #pragma unroll
  for (int o = 32; o > 0; o >>= 1) mx = fmaxf(mx, __shfl_xor(mx, o));
  if ((t & 63) == 0) red[t >> 6] = mx;
  __syncthreads();
  mx = fmaxf(fmaxf(red[0], red[1]), fmaxf(red[2], red[3]));
  float s = 0.f;
  #pragma unroll
  for (int i = 0; i < 8; i++){ r[i] = expf(r[i] - mx); s += r[i]; }
  #pragma unroll
  for (int o = 32; o > 0; o >>= 1) s += __shfl_xor(s, o);
  __syncthreads();
  if ((t & 63) == 0) red[t >> 6] = s;
  __syncthreads();
  s = red[0] + red[1] + red[2] + red[3];
  float inv = 1.f / s;
  #pragma unroll
  for (int i = 0; i < 8; i++) p[t + i*256] = r[i]*inv;
}

// ww[b,n] = wg[b] * (0.5*cw[b,n] + 0.5*alloc[n]*ag[b])
__global__ void k_writew(float* __restrict__ cw, const float* __restrict__ alloc,
                         const float* __restrict__ wg, const float* __restrict__ ag){
  int idx = blockIdx.x*256 + threadIdx.x;
  int b = idx >> 11, n = idx & 2047;
  cw[idx] = wg[b] * (0.5f*cw[idx] + 0.5f*alloc[n]*ag[b]);
}

// generic row sums (wave per row)
__global__ void k_rowsum(const float* __restrict__ A, float* __restrict__ out, int rows, int cols){
  int w = (blockIdx.x*blockDim.x + threadIdx.x) >> 6;
  int lane = threadIdx.x & 63;
  if (w >= rows) return;
  const float* a = A + (size_t)w*cols;
  float s = 0.f;
  for (int c = lane; c < cols; c += 64) s += a[c];
  #pragma unroll
  for (int o = 32; o > 0; o >>= 1) s += __shfl_down(s, o);
  if (lane == 0) out[w] = s;
}

// column sums of a (2048 x 2048) matrix (out pre-zeroed)
__global__ void k_colsum2048(const float* __restrict__ A, float* __restrict__ out){
  int c = blockIdx.x*256 + threadIdx.x;
  int r0 = blockIdx.y*128;
  float s = 0.f;
  for (int rr = 0; rr < 128; rr++) s += A[(size_t)(r0+rr)*2048 + c];
  atomicAdd(&out[c], s);
}

// bw/fw from link sums + lu sums
__global__ __launch_bounds__(1024) void k_bwfw(const float* __restrict__ ww, const float* __restrict__ tb,
                       const float* __restrict__ rowsum, const float* __restrict__ colsum,
                       float* __restrict__ bw, float* __restrict__ fw){
  __shared__ float sq[4][256], sd[4][256];
  int t = threadIdx.x & 255, z = threadIdx.x >> 8;
  int m = blockIdx.x*256 + t;
  float q = 0.f, dd = 0.f;
  for (int b = z*64; b < z*64 + 64; b++){
    float w = ww[(size_t)b*2048 + m];
    q  = fmaf(tb[b], w, q);
    dd = fmaf(w, w, dd);
  }
  sq[z][t] = q; sd[z][t] = dd;
  __syncthreads();
  if (z == 0){
    q  = sq[0][t] + sq[1][t] + sq[2][t] + sq[3][t];
    dd = sd[0][t] + sd[1][t] + sd[2][t] + sd[3][t];
    float lus = (q - dd) * (1.f/256.f);
    bw[m] = (0.9f*colsum[m] + 0.1f*lus) * (1.f/2048.f);
    fw[m] = (0.9f*rowsum[m] + 0.1f*lus) * (1.f/2048.f);
  }
}

// mem_new = memory*(1 - ww^T@ev/B) + ww^T@av/B
__global__ __launch_bounds__(256) void k_memupdate(const float* __restrict__ ww,
    const float* __restrict__ ev, const float* __restrict__ av,
    const float* __restrict__ mem, float* __restrict__ memn)
{
  __shared__ float Ws[16][68], Es[16][68], Vs[16][68];
  int m0 = blockIdx.y*64, n0 = blockIdx.x*64;
  int tid = threadIdx.x, tx = tid & 15, ty = tid >> 4;
  int kk = tid >> 4, col = (tid & 15) << 2;
  float ae[4][4] = {}, aa[4][4] = {};
  for (int k0 = 0; k0 < 256; k0 += 16){
    float4 vw  = *(const float4*)(ww + (size_t)(k0+kk)*2048 + m0 + col);
    float4 vev = *(const float4*)(ev + (size_t)(k0+kk)*128  + n0 + col);
    float4 vav = *(const float4*)(av + (size_t)(k0+kk)*128  + n0 + col);
    Ws[kk][col]=vw.x;  Ws[kk][col+1]=vw.y;  Ws[kk][col+2]=vw.z;  Ws[kk][col+3]=vw.w;
    Es[kk][col]=vev.x; Es[kk][col+1]=vev.y; Es[kk][col+2]=vev.z; Es[kk][col+3]=vev.w;
    Vs[kk][col]=vav.x; Vs[kk][col+1]=vav.y; Vs[kk][col+2]=vav.z; Vs[kk][col+3]=vav.w;
    __syncthreads();
    #pragma unroll
    for (int k = 0; k < 16; k++){
      float a[4], e[4], v[4];
      #pragma unroll
      for (int i = 0; i < 4; i++) a[i] = Ws[k][ty*4+i];
      #pragma unroll
      for (int j = 0; j < 4; j++){ e[j] = Es[k][tx*4+j]; v[j] = Vs[k][tx*4+j]; }
      #pragma unroll
      for (int i = 0; i < 4; i++)
        #pragma unroll
        for (int j = 0; j < 4; j++){
          ae[i][j] = fmaf(a[i], e[j], ae[i][j]);
          aa[i][j] = fmaf(a[i], v[j], aa[i][j]);
        }
    }
    __syncthreads();
  }
  #pragma unroll
  for (int i = 0; i < 4; i++){
    int n = m0 + ty*4 + i;
    #pragma unroll
    for (int j = 0; j < 4; j++){
      int d = n0 + tx*4 + j;
      float em = ae[i][j] * (1.f/256.f);
      float am = aa[i][j] * (1.f/256.f);
      memn[(size_t)n*128 + d] = mem[(size_t)n*128 + d] * (1.f - em) + am;
    }
  }
}

// partial bwm/fwm (atomic, pre-zeroed)
__global__ __launch_bounds__(256) void k_bwmfwm_part(const float* __restrict__ memn,
    const float* __restrict__ bw, const float* __restrict__ fw,
    float* __restrict__ bwm, float* __restrict__ fwm)
{
  __shared__ float sb[2][128], sf[2][128];
  int d = threadIdx.x & 127, g = threadIdx.x >> 7;
  int n0 = blockIdx.x*64;
  float ab = 0.f, af = 0.f;
  #pragma unroll 4
  for (int i = g; i < 64; i += 2){
    float m = memn[(size_t)(n0+i)*128 + d];
    ab = fmaf(bw[n0+i], m, ab);
    af = fmaf(fw[n0+i], m, af);
  }
  sb[g][d] = ab; sf[g][d] = af;
  __syncthreads();
  if (g == 0){
    atomicAdd(&bwm[d], sb[0][d] + sb[1][d]);
    atomicAdd(&fwm[d], sf[0][d] + sf[1][d]);
  }
}

// hro = concat(h, read_out)
__global__ void k_hro(const float* __restrict__ h, const float* __restrict__ ro, float* __restrict__ hro){
  int idx = blockIdx.x*256 + threadIdx.x;
  int b = idx / 1536, k = idx - b*1536;
  hro[idx] = (k < 1024) ? h[b*1024 + k] : ro[b*512 + k - 1024];
}

// ---------------- launcher ----------------

extern "C" void kernel_launch(void* const* d_in, const int* in_sizes, int n_in,
                              void* d_out, int out_size, void* d_ws, size_t ws_size,
                              hipStream_t stream)
{
  const float* x     = (const float*)d_in[0];
  const float* mem   = (const float*)d_in[1];
  const float* usage = (const float*)d_in[2];
  const float* link  = (const float*)d_in[3];
  const float* W_ih  = (const float*)d_in[4];
  // d_in[5] = W_hh: unused (h0 = 0)
  const float* b_ih  = (const float*)d_in[6];
  const float* b_hh  = (const float*)d_in[7];
  const float* W_if  = (const float*)d_in[8];
  const float* b_if  = (const float*)d_in[9];
  const float* W_out = (const float*)d_in[10];
  const float* b_out = (const float*)d_in[11];
  float* out = (float*)d_out;
  float* ws  = (float*)d_ws;

  float* cm     = ws + 0;         // 128  (column SUM of memory)
  float* csl    = ws + 128;       // 2048 colsum(link)
  float* bwm    = ws + 2176;      // 128
  float* fwm    = ws + 2304;      // 128
  float* rn_mem = ws + 2432;      // 2048
  float* rn_new = ws + 4480;      // 2048
  float* rsl    = ws + 6528;      // 2048 rowsum(link)
  float* tb     = ws + 8576;      // 256
  float* bw     = ws + 8832;      // 2048
  float* fw     = ws + 10880;     // 2048
  float* wg     = ws + 12928;     // 256
  float* ag     = ws + 13184;     // 256
  float* invwv  = ws + 13440;     // 256
  float* rm0    = ws + 13696;     // 1024
  float* rm1    = ws + 14720;     // 1024
  float* rm2    = ws + 15744;     // 1024
  float* alloc  = ws + 16768;     // 2048
  float* wv     = ws + 18816;     // 32768  (B x 128)
  float* ev     = ws + 51584;     // 32768
  float* av     = ws + 84352;     // 32768
  float* rks    = ws + 117120;    // 131072 (B*R x 128)
  float* cin    = ws + 248192;    // 393216 (B x 1536)
  float* g      = ws + 641408;    // 1048576 (B x 4096); reused as k_pv partials
  float* h      = ws + 1689984;   // 262144 (B x 1024)
  float* itf    = ws + 1952128;   // 201472 (B x 787)
  float* ww     = ws + 2153856;   // 524288 (B x 2048)
  float* memn   = ws + 2678144;   // 262144 (2048 x 128)
  float* sim    = ws + 2940288;   // 2097152 (B*R x 2048)
  float* ro     = ws + 5037440;   // 131072 (B x R*D)
  float* hro    = ws + 5168512;   // 393216 (B x 1536)

  // stage 0: zero atomic accumulators
  k_zero<<<10, 256, 0, stream>>>(ws, 2432);

  // stage 1: controller input
  k_colmean_part<<<32, 256, 0, stream>>>(mem, cm);
  k_rownorm128  <<<512, 256, 0, stream>>>(mem, rn_mem, 2048);
  k_cin         <<<1536, 256, 0, stream>>>(x, cm, cin);

  // stage 2: LSTM controller (split-bf16 MFMA)
  gemm_nt_bf16s<<<dim3(64,8), 256, 0, stream>>>(cin, W_ih, g, 256, 4096, 1536, b_ih, b_hh);
  k_lstm <<<1024, 256, 0, stream>>>(g, h);

  // stage 3: interface (split-bf16 MFMA)
  gemm_nt_bf16s<<<dim3(13,8), 256, 0, stream>>>(h, W_if, itf, 256, 787, 1024, b_if, nullptr);
  k_parse<<<256, 128, 0, stream>>>(itf, wv, ev, av, wg, ag, invwv, rm0, rm1, rm2, rks);

  // stage 4: write weighting
  k_alloc<<<2048, 256, 0, stream>>>(usage, alloc);
  gemm_nt<<<dim3(32,8), 256, 0, stream>>>(wv, mem, ww, 256, 2048, 128, nullptr, nullptr, invwv, rn_mem);
  k_softmax2048<<<256, 256, 0, stream>>>(ww);
  k_writew<<<2048, 256, 0, stream>>>(ww, alloc, wg, ag);

  // stage 5: link-derived read vectors
  k_rowsum<<<512, 256, 0, stream>>>(link, rsl, 2048, 2048);
  k_colsum2048<<<dim3(8,16), 256, 0, stream>>>(link, csl);
  k_rowsum<<<64, 256, 0, stream>>>(ww, tb, 256, 2048);
  k_bwfw  <<<8, 1024, 0, stream>>>(ww, tb, rsl, csl, bw, fw);

  // stage 6: memory update
  k_memupdate <<<dim3(2,32), 256, 0, stream>>>(ww, ev, av, mem, memn);
  k_rownorm128<<<512, 256, 0, stream>>>(memn, rn_new, 2048);
  k_bwmfwm_part<<<32, 256, 0, stream>>>(memn, bw, fw, bwm, fwm);

  // stage 7: read addressing + read output
  gemm_nt<<<dim3(32,32), 256, 0, stream>>>(rks, memn, sim, 1024, 2048, 128, nullptr, nullptr, nullptr, rn_new);
  k_softmax2048<<<1024, 256, 0, stream>>>(sim);
  k_pv    <<<dim3(8,64), 256, 0, stream>>>(sim, memn, g);
  k_rocomb<<<512, 256, 0, stream>>>(g, rm0, rm1, rm2, bwm, fwm, ro);

  // stage 8: output projection (split-bf16 MFMA)
  k_hro  <<<1536, 256, 0, stream>>>(h, ro, hro);
  gemm_nt_bf16s<<<dim3(16,8), 256, 0, stream>>>(hro, W_out, out, 256, 1024, 1536, b_out, nullptr);

  (void)in_sizes; (void)n_in; (void)out_size; (void)ws_size;
}

// Round 7
// 353.241 us; speedup vs baseline: 2.4371x; 1.0093x over previous
//
#include <hip/hip_runtime.h>
#include <cmath>

#define DEVI __device__ __forceinline__

DEVI float sigm(float x){ return 1.f/(1.f+expf(-x)); }

typedef __attribute__((ext_vector_type(8))) _Float16 half8;
typedef __attribute__((ext_vector_type(4))) float float4v;

// ---------------- small utility kernels ----------------

__global__ void k_zero(float* __restrict__ p, int n){
  int i = blockIdx.x*256 + threadIdx.x;
  if (i < n) p[i] = 0.f;
}

// partial column sums of memory (2048 x 128) -> cm[128] (atomic, cm pre-zeroed)
__global__ __launch_bounds__(256) void k_colmean_part(const float* __restrict__ mem, float* __restrict__ cm){
  __shared__ float s[2][128];
  int d = threadIdx.x & 127, g = threadIdx.x >> 7;
  int n0 = blockIdx.x*64;
  float a = 0.f;
  #pragma unroll 4
  for (int i = g; i < 64; i += 2) a += mem[(size_t)(n0+i)*128 + d];
  s[g][d] = a;
  __syncthreads();
  if (g == 0) atomicAdd(&cm[d], s[0][d] + s[1][d]);
}

// inverse L2 norm of each 128-wide row (wave per row)
__global__ __launch_bounds__(256) void k_rownorm128(const float* __restrict__ A, float* __restrict__ invn, int rows){
  int w = (blockIdx.x*blockDim.x + threadIdx.x) >> 6;
  int lane = threadIdx.x & 63;
  if (w >= rows) return;
  const float* a = A + (size_t)w*128;
  float x0 = a[lane], x1 = a[lane+64];
  float s = x0*x0 + x1*x1;
  #pragma unroll
  for (int o = 32; o > 0; o >>= 1) s += __shfl_down(s, o);
  if (lane == 0) invn[w] = 1.f / fmaxf(sqrtf(s), 1e-12f);
}

// cin[b,k] = k<1024 ? x[b,k] : cm[(k-1024)%128]/2048
__global__ void k_cin(const float* __restrict__ x, const float* __restrict__ cm, float* __restrict__ cin){
  int idx = blockIdx.x*256 + threadIdx.x;     // 256*1536
  int b = idx / 1536, k = idx - b*1536;
  cin[idx] = (k < 1024) ? x[b*1024 + k] : cm[(k-1024) & 127] * (1.f/2048.f);
}

// ---------------- fp32 NT GEMM (kept for content-addressing GEMMs, K=128) --------
__global__ __launch_bounds__(256) void gemm_nt(
    const float* __restrict__ A, const float* __restrict__ Bm, float* __restrict__ C,
    int M, int N, int K,
    const float* __restrict__ bias1, const float* __restrict__ bias2,
    const float* __restrict__ rowscale, const float* __restrict__ colscale)
{
  __shared__ float As[2][16][36];
  __shared__ float Bs[2][16][68];
  const int m0 = blockIdx.y*32, n0 = blockIdx.x*64;
  const int tid = threadIdx.x;
  const int tx = tid & 15, ty = tid >> 4;
  const int r = tid >> 2, kq = (tid & 3) << 2;
  const int T = K >> 4;
  const int gn = n0 + r;
  const bool bok = (gn < N);
  const float* Aptr = A + (size_t)(m0 + (r & 31))*K + kq;
  const float* Bptr = bok ? (Bm + (size_t)gn*K + kq) : Bm;

  float4 va, vb;
  if (tid < 128) va = *(const float4*)(Aptr);
  vb = bok ? *(const float4*)(Bptr) : make_float4(0,0,0,0);
  if (tid < 128){
    As[0][kq+0][r]=va.x; As[0][kq+1][r]=va.y; As[0][kq+2][r]=va.z; As[0][kq+3][r]=va.w;
  }
  Bs[0][kq+0][r]=vb.x; Bs[0][kq+1][r]=vb.y; Bs[0][kq+2][r]=vb.z; Bs[0][kq+3][r]=vb.w;
  __syncthreads();

  float acc[2][4] = {};
  for (int t = 0; t < T; t++){
    const int cur = t & 1, nxt = cur ^ 1;
    if (t+1 < T){
      if (tid < 128) va = *(const float4*)(Aptr + (t+1)*16);
      vb = bok ? *(const float4*)(Bptr + (t+1)*16) : make_float4(0,0,0,0);
    }
    #pragma unroll
    for (int k = 0; k < 16; k++){
      float a0 = As[cur][k][ty*2+0];
      float a1 = As[cur][k][ty*2+1];
      float b0 = Bs[cur][k][tx*4+0];
      float b1 = Bs[cur][k][tx*4+1];
      float b2 = Bs[cur][k][tx*4+2];
      float b3 = Bs[cur][k][tx*4+3];
      acc[0][0] = fmaf(a0,b0,acc[0][0]); acc[0][1] = fmaf(a0,b1,acc[0][1]);
      acc[0][2] = fmaf(a0,b2,acc[0][2]); acc[0][3] = fmaf(a0,b3,acc[0][3]);
      acc[1][0] = fmaf(a1,b0,acc[1][0]); acc[1][1] = fmaf(a1,b1,acc[1][1]);
      acc[1][2] = fmaf(a1,b2,acc[1][2]); acc[1][3] = fmaf(a1,b3,acc[1][3]);
    }
    if (t+1 < T){
      if (tid < 128){
        As[nxt][kq+0][r]=va.x; As[nxt][kq+1][r]=va.y; As[nxt][kq+2][r]=va.z; As[nxt][kq+3][r]=va.w;
      }
      Bs[nxt][kq+0][r]=vb.x; Bs[nxt][kq+1][r]=vb.y; Bs[nxt][kq+2][r]=vb.z; Bs[nxt][kq+3][r]=vb.w;
    }
    __syncthreads();
  }

  #pragma unroll
  for (int i = 0; i < 2; i++){
    int m = m0 + ty*2 + i;
    float rs = rowscale ? rowscale[m] : 1.f;
    #pragma unroll
    for (int j = 0; j < 4; j++){
      int n = n0 + tx*4 + j;
      if (n >= N) continue;
      float v = acc[i][j] * rs;
      if (colscale) v *= colscale[n];
      if (bias1)    v += bias1[n];
      if (bias2)    v += bias2[n];
      C[(size_t)m*N + n] = v;
    }
  }
}

// ---------------- fp16 MFMA NT GEMM: C = A @ B^T + bias1 + bias2 ----------------
// fp32 in HBM, staged to LDS as fp16; one mfma_f32_16x16x32_f16 per 16x16x32 tile.
// BM=32, BN=64, BK=64, 256 threads (4 waves). M%32==0, K%64==0 required; N guarded.
// LDS layout [quad][row][8k contiguous] -> ds_read_b128 frag reads conflict-free;
// staging maps keep row in the LOW lane bits -> uniform bank coverage on writes.
__global__ __launch_bounds__(256) void gemm_nt_f16(
    const float* __restrict__ A, const float* __restrict__ Bm, float* __restrict__ C,
    int M, int N, int K,
    const float* __restrict__ bias1, const float* __restrict__ bias2)
{
  __shared__ _Float16 Ah[2][8][32][8];   // 8 KB
  __shared__ _Float16 Bh[2][8][64][8];   // 16 KB
  const int tid = threadIdx.x;
  const int m0 = blockIdx.y*32, n0 = blockIdx.x*64;
  const int T = K >> 6;
  // A staging: row in low bits
  const int rowA = tid & 31, qA = tid >> 5;              // thread -> quad qA, 8 floats
  const float* Aptr = A + (size_t)(m0 + rowA)*K + qA*8;
  // B staging: row in low bits, two quads per thread
  const int rowB = tid & 63, qh = tid >> 6;              // quads 2qh, 2qh+1 (16 floats)
  int nBc = n0 + rowB; if (nBc >= N) nBc = N - 1;        // clamp; guarded at store
  const float* Bptr = Bm + (size_t)nBc*K + qh*16;
  // fragment maps
  const int wv = tid >> 6, lane = tid & 63;
  const int fq = lane >> 4, fr = lane & 15;
  const int m16 = (wv & 1)*16, nb = (wv >> 1)*32;

  float ga[8], gb[16];
  half8 ha, hb0, hb1;
  #define CVT_STAGE(buf)                                                        \
    { _Pragma("unroll") for (int j = 0; j < 8; j++)  ha[j]  = (_Float16)ga[j];  \
      _Pragma("unroll") for (int j = 0; j < 8; j++)  hb0[j] = (_Float16)gb[j];  \
      _Pragma("unroll") for (int j = 0; j < 8; j++)  hb1[j] = (_Float16)gb[8+j];\
      *(half8*)&Ah[buf][qA][rowA][0]      = ha;                                 \
      *(half8*)&Bh[buf][2*qh  ][rowB][0]  = hb0;                                \
      *(half8*)&Bh[buf][2*qh+1][rowB][0]  = hb1; }

  // prologue: tile 0
  *(float4*)&ga[0] = *(const float4*)(Aptr);
  *(float4*)&ga[4] = *(const float4*)(Aptr + 4);
  *(float4*)&gb[0]  = *(const float4*)(Bptr);
  *(float4*)&gb[4]  = *(const float4*)(Bptr + 4);
  *(float4*)&gb[8]  = *(const float4*)(Bptr + 8);
  *(float4*)&gb[12] = *(const float4*)(Bptr + 12);
  CVT_STAGE(0)
  __syncthreads();

  float4v acc0 = {0.f,0.f,0.f,0.f}, acc1 = {0.f,0.f,0.f,0.f};
  for (int t = 0; t < T; t++){
    const int cur = t & 1, nxt = cur ^ 1;
    if (t+1 < T){   // issue next-tile loads immediately after barrier
      const float* Ap = Aptr + (t+1)*64;
      const float* Bp = Bptr + (t+1)*64;
      *(float4*)&ga[0] = *(const float4*)(Ap);
      *(float4*)&ga[4] = *(const float4*)(Ap + 4);
      *(float4*)&gb[0]  = *(const float4*)(Bp);
      *(float4*)&gb[4]  = *(const float4*)(Bp + 4);
      *(float4*)&gb[8]  = *(const float4*)(Bp + 8);
      *(float4*)&gb[12] = *(const float4*)(Bp + 12);
    }
    #pragma unroll
    for (int s = 0; s < 2; s++){
      half8 a  = *(half8*)&Ah[cur][s*4+fq][m16+fr][0];
      half8 b0 = *(half8*)&Bh[cur][s*4+fq][nb+fr][0];
      half8 b1 = *(half8*)&Bh[cur][s*4+fq][nb+16+fr][0];
      acc0 = __builtin_amdgcn_mfma_f32_16x16x32_f16(a, b0, acc0, 0, 0, 0);
      acc1 = __builtin_amdgcn_mfma_f32_16x16x32_f16(a, b1, acc1, 0, 0, 0);
    }
    if (t+1 < T) CVT_STAGE(nxt)
    __syncthreads();
  }
  #undef CVT_STAGE

  // epilogue: C/D layout col=lane&15, row=(lane>>4)*4+reg (m89/m91-verified)
  const int colA = n0 + nb + fr, colB = colA + 16;
  #pragma unroll
  for (int i = 0; i < 4; i++){
    int m = m0 + m16 + fq*4 + i;
    if (colA < N){
      float v = acc0[i];
      if (bias1) v += bias1[colA];
      if (bias2) v += bias2[colA];
      C[(size_t)m*N + colA] = v;
    }
    if (colB < N){
      float v = acc1[i];
      if (bias1) v += bias1[colB];
      if (bias2) v += bias2[colB];
      C[(size_t)m*N + colB] = v;
    }
  }
}

// ---------------- split-K NN GEMM for ro-partials: part[kc] = P_chunk @ Mn_chunk ----
__global__ __launch_bounds__(256) void k_pv(const float* __restrict__ P, const float* __restrict__ Mn,
                                            float* __restrict__ part)
{
  __shared__ float Ps[2][16][20];
  __shared__ float Ms[2][16][132];
  const int kc0 = blockIdx.x*256, r0 = blockIdx.y*16;
  const int tid = threadIdx.x;
  const int tx = tid & 31, ty = tid >> 5;
  const int pr = tid >> 2, pk = (tid & 3) << 2;
  const int mk = tid >> 4, mc = (tid & 15) << 3;
  const float* Pptr = P + (size_t)(r0 + (pr & 15))*2048 + kc0 + pk;
  const float* Mptr = Mn + (size_t)(kc0 + mk)*128 + mc;

  float4 vp, vm0, vm1;
  if (tid < 64) vp = *(const float4*)(Pptr);
  vm0 = *(const float4*)(Mptr);
  vm1 = *(const float4*)(Mptr + 4);
  if (tid < 64){
    Ps[0][pk+0][pr]=vp.x; Ps[0][pk+1][pr]=vp.y; Ps[0][pk+2][pr]=vp.z; Ps[0][pk+3][pr]=vp.w;
  }
  *(float4*)&Ms[0][mk][mc]   = vm0;
  *(float4*)&Ms[0][mk][mc+4] = vm1;
  __syncthreads();

  float acc[2][4] = {};
  #pragma unroll 2
  for (int t = 0; t < 16; t++){
    const int cur = t & 1, nxt = cur ^ 1;
    if (t+1 < 16){
      if (tid < 64) vp = *(const float4*)(Pptr + (t+1)*16);
      vm0 = *(const float4*)(Mptr + (size_t)(t+1)*16*128);
      vm1 = *(const float4*)(Mptr + (size_t)(t+1)*16*128 + 4);
    }
    #pragma unroll
    for (int k = 0; k < 16; k++){
      float a0 = Ps[cur][k][ty*2+0];
      float a1 = Ps[cur][k][ty*2+1];
      float b0 = Ms[cur][k][tx*4+0];
      float b1 = Ms[cur][k][tx*4+1];
      float b2 = Ms[cur][k][tx*4+2];
      float b3 = Ms[cur][k][tx*4+3];
      acc[0][0] = fmaf(a0,b0,acc[0][0]); acc[0][1] = fmaf(a0,b1,acc[0][1]);
      acc[0][2] = fmaf(a0,b2,acc[0][2]); acc[0][3] = fmaf(a0,b3,acc[0][3]);
      acc[1][0] = fmaf(a1,b0,acc[1][0]); acc[1][1] = fmaf(a1,b1,acc[1][1]);
      acc[1][2] = fmaf(a1,b2,acc[1][2]); acc[1][3] = fmaf(a1,b3,acc[1][3]);
    }
    if (t+1 < 16){
      if (tid < 64){
        Ps[nxt][pk+0][pr]=vp.x; Ps[nxt][pk+1][pr]=vp.y; Ps[nxt][pk+2][pr]=vp.z; Ps[nxt][pk+3][pr]=vp.w;
      }
      *(float4*)&Ms[nxt][mk][mc]   = vm0;
      *(float4*)&Ms[nxt][mk][mc+4] = vm1;
    }
    __syncthreads();
  }

  float* dst = part + (size_t)blockIdx.x*131072;
  #pragma unroll
  for (int i = 0; i < 2; i++){
    int row = r0 + ty*2 + i;
    float4 v = make_float4(acc[i][0], acc[i][1], acc[i][2], acc[i][3]);
    *(float4*)&dst[(size_t)row*128 + tx*4] = v;
  }
}

// combine split-K partials + read-mode mix
__global__ void k_rocomb(const float* __restrict__ part, const float* __restrict__ rm0,
                         const float* __restrict__ rm1, const float* __restrict__ rm2,
                         const float* __restrict__ bwm, const float* __restrict__ fwm,
                         float* __restrict__ ro){
  int idx = blockIdx.x*256 + threadIdx.x;   // 131072
  int row = idx >> 7, d = idx & 127;
  float s = 0.f;
  #pragma unroll
  for (int kc = 0; kc < 8; kc++) s += part[(size_t)kc*131072 + idx];
  ro[idx] = rm0[row]*s + rm1[row]*bwm[d] + rm2[row]*fwm[d];
}

// LSTM gate activation
__global__ void k_lstm(const float* __restrict__ g, float* __restrict__ h){
  int idx = blockIdx.x*256 + threadIdx.x;    // 256*1024
  int b = idx >> 10, j = idx & 1023;
  const float* gr = g + (size_t)b*4096;
  float c = sigm(gr[j]) * tanhf(gr[2048 + j]);
  h[idx] = sigm(gr[3072 + j]) * tanhf(c);
}

DEVI float blockReduce128(float v, float* lds2){
  #pragma unroll
  for (int o = 32; o > 0; o >>= 1) v += __shfl_xor(v, o);
  int w = threadIdx.x >> 6;
  __syncthreads();
  if ((threadIdx.x & 63) == 0) lds2[w] = v;
  __syncthreads();
  return lds2[0] + lds2[1];
}

// parse interface vector itf (B x 787)
__global__ __launch_bounds__(128) void k_parse(const float* __restrict__ itf,
    float* __restrict__ wv, float* __restrict__ ev, float* __restrict__ av,
    float* __restrict__ wg_, float* __restrict__ ag_, float* __restrict__ invwv,
    float* __restrict__ rm0, float* __restrict__ rm1, float* __restrict__ rm2,
    float* __restrict__ rks)
{
  __shared__ float red[2];
  int b = blockIdx.x, t = threadIdx.x;
  const float* it = itf + (size_t)b*787;
  float wg = sigm(it[256]);
  float ag = sigm(it[257]);
  if (t == 0){ wg_[b] = wg; ag_[b] = ag; }
  float w = it[t];
  wv[b*128 + t] = w;
  av[b*128 + t] = w * wg;
  ev[b*128 + t] = sigm(it[128 + t]) * wg;
  float ss = blockReduce128(w*w, red);
  if (t == 0) invwv[b] = 1.f / fmaxf(sqrtf(ss), 1e-12f);
  if (t < 4){
    int rr = t;
    float m0v = it[259 + rr*3 + 0], m1v = it[259 + rr*3 + 1], m2v = it[259 + rr*3 + 2];
    float mx = fmaxf(m0v, fmaxf(m1v, m2v));
    float e0 = expf(m0v - mx), e1 = expf(m1v - mx), e2 = expf(m2v - mx);
    float inv = 1.f / (e0 + e1 + e2);
    rm0[b*4 + rr] = e0*inv; rm1[b*4 + rr] = e1*inv; rm2[b*4 + rr] = e2*inv;
  }
  #pragma unroll
  for (int rr = 0; rr < 4; rr++){
    float kv = it[275 + rr*128 + t];
    float ks = blockReduce128(kv*kv, red);
    float sx = it[271 + rr];
    float str = fmaxf(sx, 0.f) + log1pf(expf(-fabsf(sx)));
    float invk = 1.f / fmaxf(sqrtf(ks), 1e-12f);
    rks[((size_t)b*4 + rr)*128 + t] = kv * invk * str;
  }
}

// allocation weighting, sort-free
__global__ __launch_bounds__(256) void k_alloc(const float* __restrict__ usage, float* __restrict__ out){
  __shared__ float red[4];
  int n = blockIdx.x, t = threadIdx.x;
  float un = usage[n];
  float prod = 1.f;
  #pragma unroll
  for (int i = 0; i < 8; i++){
    int m = t + i*256;
    float um = usage[m];
    bool before = (um < un) || (um == un && m < n);
    prod *= before ? (1.f - um) : 1.f;
  }
  #pragma unroll
  for (int o = 32; o > 0; o >>= 1) prod *= __shfl_xor(prod, o);
  if ((t & 63) == 0) red[t >> 6] = prod;
  __syncthreads();
  if (t == 0) out[n] = un * (red[0]*red[1]) * (red[2]*red[3]);
}

// in-place row softmax, rows of length 2048
__global__ __launch_bounds__(256) void k_softmax2048(float* __restrict__ P){
  __shared__ float red[4];
  float* p = P + (size_t)blockIdx.x*2048;
  int t = threadIdx.x;
  float r[8];
  float mx = -3.4e38f;
  #pragma unroll
  for (int i = 0; i < 8; i++){ r[i] = p[t + i*256]; mx = fmaxf(mx, r[i]); }
  #pragma unroll
  for (int o = 32; o > 0; o >>= 1) mx = fmaxf(mx, __shfl_xor(mx, o));
  if ((t & 63) == 0) red[t >> 6] = mx;
  __syncthreads();
  mx = fmaxf(fmaxf(red[0], red[1]), fmaxf(red[2], red[3]));
  float s = 0.f;
  #pragma unroll
  for (int i = 0; i < 8; i++){ r[i] = expf(r[i] - mx); s += r[i]; }
  #pragma unroll
  for (int o = 32; o > 0; o >>= 1) s += __shfl_xor(s, o);
  __syncthreads();
  if ((t & 63) == 0) red[t >> 6] = s;
  __syncthreads();
  s = red[0] + red[1] + red[2] + red[3];
  float inv = 1.f / s;
  #pragma unroll
  for (int i = 0; i < 8; i++) p[t + i*256] = r[i]*inv;
}

// ww[b,n] = wg[b] * (0.5*cw[b,n] + 0.5*alloc[n]*ag[b])
__global__ void k_writew(float* __restrict__ cw, const float* __restrict__ alloc,
                         const float* __restrict__ wg, const float* __restrict__ ag){
  int idx = blockIdx.x*256 + threadIdx.x;
  int b = idx >> 11, n = idx & 2047;
  cw[idx] = wg[b] * (0.5f*cw[idx] + 0.5f*alloc[n]*ag[b]);
}

// generic row sums (wave per row)
__global__ void k_rowsum(const float* __restrict__ A, float* __restrict__ out, int rows, int cols){
  int w = (blockIdx.x*blockDim.x + threadIdx.x) >> 6;
  int lane = threadIdx.x & 63;
  if (w >= rows) return;
  const float* a = A + (size_t)w*cols;
  float s = 0.f;
  for (int c = lane; c < cols; c += 64) s += a[c];
  #pragma unroll
  for (int o = 32; o > 0; o >>= 1) s += __shfl_down(s, o);
  if (lane == 0) out[w] = s;
}

// column sums of a (2048 x 2048) matrix (out pre-zeroed)
__global__ void k_colsum2048(const float* __restrict__ A, float* __restrict__ out){
  int c = blockIdx.x*256 + threadIdx.x;
  int r0 = blockIdx.y*128;
  float s = 0.f;
  for (int rr = 0; rr < 128; rr++) s += A[(size_t)(r0+rr)*2048 + c];
  atomicAdd(&out[c], s);
}

// bw/fw from link sums + lu sums
__global__ __launch_bounds__(1024) void k_bwfw(const float* __restrict__ ww, const float* __restrict__ tb,
                       const float* __restrict__ rowsum, const float* __restrict__ colsum,
                       float* __restrict__ bw, float* __restrict__ fw){
  __shared__ float sq[4][256], sd[4][256];
  int t = threadIdx.x & 255, z = threadIdx.x >> 8;
  int m = blockIdx.x*256 + t;
  float q = 0.f, dd = 0.f;
  for (int b = z*64; b < z*64 + 64; b++){
    float w = ww[(size_t)b*2048 + m];
    q  = fmaf(tb[b], w, q);
    dd = fmaf(w, w, dd);
  }
  sq[z][t] = q; sd[z][t] = dd;
  __syncthreads();
  if (z == 0){
    q  = sq[0][t] + sq[1][t] + sq[2][t] + sq[3][t];
    dd = sd[0][t] + sd[1][t] + sd[2][t] + sd[3][t];
    float lus = (q - dd) * (1.f/256.f);
    bw[m] = (0.9f*colsum[m] + 0.1f*lus) * (1.f/2048.f);
    fw[m] = (0.9f*rowsum[m] + 0.1f*lus) * (1.f/2048.f);
  }
}

// mem_new = memory*(1 - ww^T@ev/B) + ww^T@av/B
__global__ __launch_bounds__(256) void k_memupdate(const float* __restrict__ ww,
    const float* __restrict__ ev, const float* __restrict__ av,
    const float* __restrict__ mem, float* __restrict__ memn)
{
  __shared__ float Ws[16][68], Es[16][68], Vs[16][68];
  int m0 = blockIdx.y*64, n0 = blockIdx.x*64;
  int tid = threadIdx.x, tx = tid & 15, ty = tid >> 4;
  int kk = tid >> 4, col = (tid & 15) << 2;
  float ae[4][4] = {}, aa[4][4] = {};
  for (int k0 = 0; k0 < 256; k0 += 16){
    float4 vw  = *(const float4*)(ww + (size_t)(k0+kk)*2048 + m0 + col);
    float4 vev = *(const float4*)(ev + (size_t)(k0+kk)*128  + n0 + col);
    float4 vav = *(const float4*)(av + (size_t)(k0+kk)*128  + n0 + col);
    Ws[kk][col]=vw.x;  Ws[kk][col+1]=vw.y;  Ws[kk][col+2]=vw.z;  Ws[kk][col+3]=vw.w;
    Es[kk][col]=vev.x; Es[kk][col+1]=vev.y; Es[kk][col+2]=vev.z; Es[kk][col+3]=vev.w;
    Vs[kk][col]=vav.x; Vs[kk][col+1]=vav.y; Vs[kk][col+2]=vav.z; Vs[kk][col+3]=vav.w;
    __syncthreads();
    #pragma unroll
    for (int k = 0; k < 16; k++){
      float a[4], e[4], v[4];
      #pragma unroll
      for (int i = 0; i < 4; i++) a[i] = Ws[k][ty*4+i];
      #pragma unroll
      for (int j = 0; j < 4; j++){ e[j] = Es[k][tx*4+j]; v[j] = Vs[k][tx*4+j]; }
      #pragma unroll
      for (int i = 0; i < 4; i++)
        #pragma unroll
        for (int j = 0; j < 4; j++){
          ae[i][j] = fmaf(a[i], e[j], ae[i][j]);
          aa[i][j] = fmaf(a[i], v[j], aa[i][j]);
        }
    }
    __syncthreads();
  }
  #pragma unroll
  for (int i = 0; i < 4; i++){
    int n = m0 + ty*4 + i;
    #pragma unroll
    for (int j = 0; j < 4; j++){
      int d = n0 + tx*4 + j;
      float em = ae[i][j] * (1.f/256.f);
      float am = aa[i][j] * (1.f/256.f);
      memn[(size_t)n*128 + d] = mem[(size_t)n*128 + d] * (1.f - em) + am;
    }
  }
}

// partial bwm/fwm (atomic, pre-zeroed)
__global__ __launch_bounds__(256) void k_bwmfwm_part(const float* __restrict__ memn,
    const float* __restrict__ bw, const float* __restrict__ fw,
    float* __restrict__ bwm, float* __restrict__ fwm)
{
  __shared__ float sb[2][128], sf[2][128];
  int d = threadIdx.x & 127, g = threadIdx.x >> 7;
  int n0 = blockIdx.x*64;
  float ab = 0.f, af = 0.f;
  #pragma unroll 4
  for (int i = g; i < 64; i += 2){
    float m = memn[(size_t)(n0+i)*128 + d];
    ab = fmaf(bw[n0+i], m, ab);
    af = fmaf(fw[n0+i], m, af);
  }
  sb[g][d] = ab; sf[g][d] = af;
  __syncthreads();
  if (g == 0){
    atomicAdd(&bwm[d], sb[0][d] + sb[1][d]);
    atomicAdd(&fwm[d], sf[0][d] + sf[1][d]);
  }
}

// hro = concat(h, read_out)
__global__ void k_hro(const float* __restrict__ h, const float* __restrict__ ro, float* __restrict__ hro){
  int idx = blockIdx.x*256 + threadIdx.x;
  int b = idx / 1536, k = idx - b*1536;
  hro[idx] = (k < 1024) ? h[b*1024 + k] : ro[b*512 + k - 1024];
}

// ---------------- launcher ----------------

extern "C" void kernel_launch(void* const* d_in, const int* in_sizes, int n_in,
                              void* d_out, int out_size, void* d_ws, size_t ws_size,
                              hipStream_t stream)
{
  const float* x     = (const float*)d_in[0];
  const float* mem   = (const float*)d_in[1];
  const float* usage = (const float*)d_in[2];
  const float* link  = (const float*)d_in[3];
  const float* W_ih  = (const float*)d_in[4];
  // d_in[5] = W_hh: unused (h0 = 0)
  const float* b_ih  = (const float*)d_in[6];
  const float* b_hh  = (const float*)d_in[7];
  const float* W_if  = (const float*)d_in[8];
  const float* b_if  = (const float*)d_in[9];
  const float* W_out = (const float*)d_in[10];
  const float* b_out = (const float*)d_in[11];
  float* out = (float*)d_out;
  float* ws  = (float*)d_ws;

  float* cm     = ws + 0;         // 128  (column SUM of memory)
  float* csl    = ws + 128;       // 2048 colsum(link)
  float* bwm    = ws + 2176;      // 128
  float* fwm    = ws + 2304;      // 128
  float* rn_mem = ws + 2432;      // 2048
  float* rn_new = ws + 4480;      // 2048
  float* rsl    = ws + 6528;      // 2048 rowsum(link)
  float* tb     = ws + 8576;      // 256
  float* bw     = ws + 8832;      // 2048
  float* fw     = ws + 10880;     // 2048
  float* wg     = ws + 12928;     // 256
  float* ag     = ws + 13184;     // 256
  float* invwv  = ws + 13440;     // 256
  float* rm0    = ws + 13696;     // 1024
  float* rm1    = ws + 14720;     // 1024
  float* rm2    = ws + 15744;     // 1024
  float* alloc  = ws + 16768;     // 2048
  float* wv     = ws + 18816;     // 32768  (B x 128)
  float* ev     = ws + 51584;     // 32768
  float* av     = ws + 84352;     // 32768
  float* rks    = ws + 117120;    // 131072 (B*R x 128)
  float* cin    = ws + 248192;    // 393216 (B x 1536)
  float* g      = ws + 641408;    // 1048576 (B x 4096); reused as k_pv partials
  float* h      = ws + 1689984;   // 262144 (B x 1024)
  float* itf    = ws + 1952128;   // 201472 (B x 787)
  float* ww     = ws + 2153856;   // 524288 (B x 2048)
  float* memn   = ws + 2678144;   // 262144 (2048 x 128)
  float* sim    = ws + 2940288;   // 2097152 (B*R x 2048)
  float* ro     = ws + 5037440;   // 131072 (B x R*D)
  float* hro    = ws + 5168512;   // 393216 (B x 1536)

  // stage 0: zero atomic accumulators
  k_zero<<<10, 256, 0, stream>>>(ws, 2432);

  // stage 1: controller input
  k_colmean_part<<<32, 256, 0, stream>>>(mem, cm);
  k_rownorm128  <<<512, 256, 0, stream>>>(mem, rn_mem, 2048);
  k_cin         <<<1536, 256, 0, stream>>>(x, cm, cin);

  // stage 2: LSTM controller (fp16 MFMA)
  gemm_nt_f16<<<dim3(64,8), 256, 0, stream>>>(cin, W_ih, g, 256, 4096, 1536, b_ih, b_hh);
  k_lstm <<<1024, 256, 0, stream>>>(g, h);

  // stage 3: interface (fp16 MFMA)
  gemm_nt_f16<<<dim3(13,8), 256, 0, stream>>>(h, W_if, itf, 256, 787, 1024, b_if, nullptr);
  k_parse<<<256, 128, 0, stream>>>(itf, wv, ev, av, wg, ag, invwv, rm0, rm1, rm2, rks);

  // stage 4: write weighting
  k_alloc<<<2048, 256, 0, stream>>>(usage, alloc);
  gemm_nt<<<dim3(32,8), 256, 0, stream>>>(wv, mem, ww, 256, 2048, 128, nullptr, nullptr, invwv, rn_mem);
  k_softmax2048<<<256, 256, 0, stream>>>(ww);
  k_writew<<<2048, 256, 0, stream>>>(ww, alloc, wg, ag);

  // stage 5: link-derived read vectors
  k_rowsum<<<512, 256, 0, stream>>>(link, rsl, 2048, 2048);
  k_colsum2048<<<dim3(8,16), 256, 0, stream>>>(link, csl);
  k_rowsum<<<64, 256, 0, stream>>>(ww, tb, 256, 2048);
  k_bwfw  <<<8, 1024, 0, stream>>>(ww, tb, rsl, csl, bw, fw);

  // stage 6: memory update
  k_memupdate <<<dim3(2,32), 256, 0, stream>>>(ww, ev, av, mem, memn);
  k_rownorm128<<<512, 256, 0, stream>>>(memn, rn_new, 2048);
  k_bwmfwm_part<<<32, 256, 0, stream>>>(memn, bw, fw, bwm, fwm);

  // stage 7: read addressing + read output
  gemm_nt<<<dim3(32,32), 256, 0, stream>>>(rks, memn, sim, 1024, 2048, 128, nullptr, nullptr, nullptr, rn_new);
  k_softmax2048<<<1024, 256, 0, stream>>>(sim);
  k_pv    <<<dim3(8,64), 256, 0, stream>>>(sim, memn, g);
  k_rocomb<<<512, 256, 0, stream>>>(g, rm0, rm1, rm2, bwm, fwm, ro);

  // stage 8: output projection (fp16 MFMA)
  k_hro  <<<1536, 256, 0, stream>>>(h, ro, hro);
  gemm_nt_f16<<<dim3(16,8), 256, 0, stream>>>(hro, W_out, out, 256, 1024, 1536, b_out, nullptr);

  (void)in_sizes; (void)n_in; (void)out_size; (void)ws_size;
}

// Round 8
// 290.381 us; speedup vs baseline: 2.9647x; 1.2165x over previous
//
#include <hip/hip_runtime.h>
#include <cmath>

#define DEVI __device__ __forceinline__

DEVI float sigm(float x){ return 1.f/(1.f+expf(-x)); }

typedef __attribute__((ext_vector_type(8))) _Float16 half8;
typedef __attribute__((ext_vector_type(4))) float float4v;

__global__ void k_zero(float* __restrict__ p, int n){
  int i = blockIdx.x*256 + threadIdx.x;
  if (i < n) p[i] = 0.f;
}

// fp32 -> fp16 cast, 8 elems/thread
__global__ void k_cast16(const float* __restrict__ in, _Float16* __restrict__ out, int n8){
  int i = blockIdx.x*256 + threadIdx.x;
  if (i >= n8) return;
  const float* p = in + (size_t)i*8;
  half8 h;
  #pragma unroll
  for (int j = 0; j < 8; j++) h[j] = (_Float16)p[j];
  *(half8*)(out + (size_t)i*8) = h;
}

// partial column sums of memory (2048 x 128) -> cm[128] (atomic, cm pre-zeroed)
__global__ __launch_bounds__(256) void k_colmean_part(const float* __restrict__ mem, float* __restrict__ cm){
  __shared__ float s[2][128];
  int d = threadIdx.x & 127, g = threadIdx.x >> 7;
  int n0 = blockIdx.x*64;
  float a = 0.f;
  #pragma unroll 4
  for (int i = g; i < 64; i += 2) a += mem[(size_t)(n0+i)*128 + d];
  s[g][d] = a;
  __syncthreads();
  if (g == 0) atomicAdd(&cm[d], s[0][d] + s[1][d]);
}

// L2-normalize each 128-wide row and emit fp16 (wave per row)
__global__ __launch_bounds__(256) void k_rownorm_cast(const float* __restrict__ A,
                                                      _Float16* __restrict__ Ah, int rows){
  int w = (blockIdx.x*blockDim.x + threadIdx.x) >> 6;
  int lane = threadIdx.x & 63;
  if (w >= rows) return;
  const float* a = A + (size_t)w*128;
  float x0 = a[lane], x1 = a[lane+64];
  float s = x0*x0 + x1*x1;
  #pragma unroll
  for (int o = 32; o > 0; o >>= 1) s += __shfl_xor(s, o);
  float invn = 1.f / fmaxf(sqrtf(s), 1e-12f);
  Ah[(size_t)w*128 + lane]      = (_Float16)(x0*invn);
  Ah[(size_t)w*128 + 64 + lane] = (_Float16)(x1*invn);
}

// cin_h[b,k] = fp16( k<1024 ? x[b,k] : cm[(k-1024)%128]/2048 )
__global__ void k_cin(const float* __restrict__ x, const float* __restrict__ cm, _Float16* __restrict__ cin){
  int idx = blockIdx.x*256 + threadIdx.x;     // 256*1536
  int b = idx / 1536, k = idx - b*1536;
  float v = (k < 1024) ? x[b*1024 + k] : cm[(k-1024) & 127] * (1.f/2048.f);
  cin[idx] = (_Float16)v;
}

// ---------------- fp16 MFMA NT GEMM: C = A @ B^T + bias1 + bias2 ----------------
// BM=32, BN=64, BK=64, 256 threads. M%32==0, K%64==0; N guarded.
// Coalesced half8 loads; LDS [quad][row][8] with padded quad stride.
#define QA 264
#define QB 520
__global__ __launch_bounds__(256) void gemm_f16(
    const _Float16* __restrict__ A, const _Float16* __restrict__ Bm, float* __restrict__ C,
    int M, int N, int K,
    const float* __restrict__ bias1, const float* __restrict__ bias2)
{
  __shared__ _Float16 Ah[2][8*QA];   // 8448 B
  __shared__ _Float16 Bh[2][8*QB];   // 16640 B
  const int tid = threadIdx.x;
  const int m0 = blockIdx.y*32, n0 = blockIdx.x*64;
  const int T = K >> 6;
  const int arow = tid >> 3, aq = tid & 7;
  const _Float16* Aptr = A + (size_t)(m0 + arow)*K + aq*8;
  const int brow = tid >> 3, bq = tid & 7;
  int nB0 = n0 + brow;      if (nB0 >= N) nB0 = N - 1;
  int nB1 = n0 + brow + 32; if (nB1 >= N) nB1 = N - 1;
  const _Float16* Bptr0 = Bm + (size_t)nB0*K + bq*8;
  const _Float16* Bptr1 = Bm + (size_t)nB1*K + bq*8;
  const int wA  = aq*QA + arow*8;
  const int wB0 = bq*QB + brow*8;
  const int wB1 = bq*QB + (brow+32)*8;
  const int wv_ = tid >> 6, lane = tid & 63;
  const int fq = lane >> 4, fr = lane & 15;
  const int m16 = (wv_ & 1)*16, nb = (wv_ >> 1)*32;

  half8 ra, rb0, rb1;
  ra  = *(const half8*)(Aptr);
  rb0 = *(const half8*)(Bptr0);
  rb1 = *(const half8*)(Bptr1);
  *(half8*)&Ah[0][wA]  = ra;
  *(half8*)&Bh[0][wB0] = rb0;
  *(half8*)&Bh[0][wB1] = rb1;
  __syncthreads();

  float4v acc0 = {0.f,0.f,0.f,0.f}, acc1 = {0.f,0.f,0.f,0.f};
  for (int t = 0; t < T; t++){
    const int cur = t & 1, nxt = cur ^ 1;
    if (t+1 < T){
      ra  = *(const half8*)(Aptr  + (t+1)*64);
      rb0 = *(const half8*)(Bptr0 + (t+1)*64);
      rb1 = *(const half8*)(Bptr1 + (t+1)*64);
    }
    #pragma unroll
    for (int s = 0; s < 2; s++){
      int q = s*4 + fq;
      half8 a  = *(half8*)&Ah[cur][q*QA + (m16+fr)*8];
      half8 b0 = *(half8*)&Bh[cur][q*QB + (nb+fr)*8];
      half8 b1 = *(half8*)&Bh[cur][q*QB + (nb+16+fr)*8];
      acc0 = __builtin_amdgcn_mfma_f32_16x16x32_f16(a, b0, acc0, 0, 0, 0);
      acc1 = __builtin_amdgcn_mfma_f32_16x16x32_f16(a, b1, acc1, 0, 0, 0);
    }
    if (t+1 < T){
      *(half8*)&Ah[nxt][wA]  = ra;
      *(half8*)&Bh[nxt][wB0] = rb0;
      *(half8*)&Bh[nxt][wB1] = rb1;
    }
    __syncthreads();
  }

  const int colA = n0 + nb + fr, colB = colA + 16;
  #pragma unroll
  for (int i = 0; i < 4; i++){
    int m = m0 + m16 + fq*4 + i;
    if (colA < N){
      float v = acc0[i];
      if (bias1) v += bias1[colA];
      if (bias2) v += bias2[colA];
      C[(size_t)m*N + colA] = v;
    }
    if (colB < N){
      float v = acc1[i];
      if (bias1) v += bias1[colB];
      if (bias2) v += bias2[colB];
      C[(size_t)m*N + colB] = v;
    }
  }
}

// ---------------- split-K NN GEMM for ro-partials ----------------
__global__ __launch_bounds__(256) void k_pv(const float* __restrict__ P, const float* __restrict__ Mn,
                                            float* __restrict__ part)
{
  __shared__ float Ps[2][16][20];
  __shared__ float Ms[2][16][132];
  const int kc0 = blockIdx.x*256, r0 = blockIdx.y*16;
  const int tid = threadIdx.x;
  const int tx = tid & 31, ty = tid >> 5;
  const int pr = tid >> 2, pk = (tid & 3) << 2;
  const int mk = tid >> 4, mc = (tid & 15) << 3;
  const float* Pptr = P + (size_t)(r0 + (pr & 15))*2048 + kc0 + pk;
  const float* Mptr = Mn + (size_t)(kc0 + mk)*128 + mc;

  float4 vp, vm0, vm1;
  if (tid < 64) vp = *(const float4*)(Pptr);
  vm0 = *(const float4*)(Mptr);
  vm1 = *(const float4*)(Mptr + 4);
  if (tid < 64){
    Ps[0][pk+0][pr]=vp.x; Ps[0][pk+1][pr]=vp.y; Ps[0][pk+2][pr]=vp.z; Ps[0][pk+3][pr]=vp.w;
  }
  *(float4*)&Ms[0][mk][mc]   = vm0;
  *(float4*)&Ms[0][mk][mc+4] = vm1;
  __syncthreads();

  float acc[2][4] = {};
  #pragma unroll 2
  for (int t = 0; t < 16; t++){
    const int cur = t & 1, nxt = cur ^ 1;
    if (t+1 < 16){
      if (tid < 64) vp = *(const float4*)(Pptr + (t+1)*16);
      vm0 = *(const float4*)(Mptr + (size_t)(t+1)*16*128);
      vm1 = *(const float4*)(Mptr + (size_t)(t+1)*16*128 + 4);
    }
    #pragma unroll
    for (int k = 0; k < 16; k++){
      float a0 = Ps[cur][k][ty*2+0];
      float a1 = Ps[cur][k][ty*2+1];
      float b0 = Ms[cur][k][tx*4+0];
      float b1 = Ms[cur][k][tx*4+1];
      float b2 = Ms[cur][k][tx*4+2];
      float b3 = Ms[cur][k][tx*4+3];
      acc[0][0] = fmaf(a0,b0,acc[0][0]); acc[0][1] = fmaf(a0,b1,acc[0][1]);
      acc[0][2] = fmaf(a0,b2,acc[0][2]); acc[0][3] = fmaf(a0,b3,acc[0][3]);
      acc[1][0] = fmaf(a1,b0,acc[1][0]); acc[1][1] = fmaf(a1,b1,acc[1][1]);
      acc[1][2] = fmaf(a1,b2,acc[1][2]); acc[1][3] = fmaf(a1,b3,acc[1][3]);
    }
    if (t+1 < 16){
      if (tid < 64){
        Ps[nxt][pk+0][pr]=vp.x; Ps[nxt][pk+1][pr]=vp.y; Ps[nxt][pk+2][pr]=vp.z; Ps[nxt][pk+3][pr]=vp.w;
      }
      *(float4*)&Ms[nxt][mk][mc]   = vm0;
      *(float4*)&Ms[nxt][mk][mc+4] = vm1;
    }
    __syncthreads();
  }

  float* dst = part + (size_t)blockIdx.x*131072;
  #pragma unroll
  for (int i = 0; i < 2; i++){
    int row = r0 + ty*2 + i;
    float4 v = make_float4(acc[i][0], acc[i][1], acc[i][2], acc[i][3]);
    *(float4*)&dst[(size_t)row*128 + tx*4] = v;
  }
}

__global__ void k_rocomb(const float* __restrict__ part, const float* __restrict__ rm0,
                         const float* __restrict__ rm1, const float* __restrict__ rm2,
                         const float* __restrict__ bwm, const float* __restrict__ fwm,
                         float* __restrict__ ro){
  int idx = blockIdx.x*256 + threadIdx.x;   // 131072
  int row = idx >> 7, d = idx & 127;
  float s = 0.f;
  #pragma unroll
  for (int kc = 0; kc < 8; kc++) s += part[(size_t)kc*131072 + idx];
  ro[idx] = rm0[row]*s + rm1[row]*bwm[d] + rm2[row]*fwm[d];
}

// LSTM gate activation -> fp16 h
__global__ void k_lstm(const float* __restrict__ g, _Float16* __restrict__ h){
  int idx = blockIdx.x*256 + threadIdx.x;    // 256*1024
  int b = idx >> 10, j = idx & 1023;
  const float* gr = g + (size_t)b*4096;
  float c = sigm(gr[j]) * tanhf(gr[2048 + j]);
  h[idx] = (_Float16)(sigm(gr[3072 + j]) * tanhf(c));
}

DEVI float blockReduce128(float v, float* lds2){
  #pragma unroll
  for (int o = 32; o > 0; o >>= 1) v += __shfl_xor(v, o);
  int w = threadIdx.x >> 6;
  __syncthreads();
  if ((threadIdx.x & 63) == 0) lds2[w] = v;
  __syncthreads();
  return lds2[0] + lds2[1];
}

// parse itf; wv_h has invwv folded, rks_h has invk*str folded
__global__ __launch_bounds__(128) void k_parse(const float* __restrict__ itf,
    _Float16* __restrict__ wv_h, float* __restrict__ ev, float* __restrict__ av,
    float* __restrict__ wg_, float* __restrict__ ag_,
    float* __restrict__ rm0, float* __restrict__ rm1, float* __restrict__ rm2,
    _Float16* __restrict__ rks_h)
{
  __shared__ float red[2];
  int b = blockIdx.x, t = threadIdx.x;
  const float* it = itf + (size_t)b*787;
  float wg = sigm(it[256]);
  float ag = sigm(it[257]);
  if (t == 0){ wg_[b] = wg; ag_[b] = ag; }
  float w = it[t];
  av[b*128 + t] = w * wg;
  ev[b*128 + t] = sigm(it[128 + t]) * wg;
  float ss = blockReduce128(w*w, red);
  float invwv = 1.f / fmaxf(sqrtf(ss), 1e-12f);
  wv_h[b*128 + t] = (_Float16)(w * invwv);
  if (t < 4){
    int rr = t;
    float m0v = it[259 + rr*3 + 0], m1v = it[259 + rr*3 + 1], m2v = it[259 + rr*3 + 2];
    float mx = fmaxf(m0v, fmaxf(m1v, m2v));
    float e0 = expf(m0v - mx), e1 = expf(m1v - mx), e2 = expf(m2v - mx);
    float inv = 1.f / (e0 + e1 + e2);
    rm0[b*4 + rr] = e0*inv; rm1[b*4 + rr] = e1*inv; rm2[b*4 + rr] = e2*inv;
  }
  #pragma unroll
  for (int rr = 0; rr < 4; rr++){
    float kv = it[275 + rr*128 + t];
    float ks = blockReduce128(kv*kv, red);
    float sx = it[271 + rr];
    float str = fmaxf(sx, 0.f) + log1pf(expf(-fabsf(sx)));
    float invk = 1.f / fmaxf(sqrtf(ks), 1e-12f);
    rks_h[((size_t)b*4 + rr)*128 + t] = (_Float16)(kv * invk * str);
  }
}

__global__ __launch_bounds__(256) void k_alloc(const float* __restrict__ usage, float* __restrict__ out){
  __shared__ float red[4];
  int n = blockIdx.x, t = threadIdx.x;
  float un = usage[n];
  float prod = 1.f;
  #pragma unroll
  for (int i = 0; i < 8; i++){
    int m = t + i*256;
    float um = usage[m];
    bool before = (um < un) || (um == un && m < n);
    prod *= before ? (1.f - um) : 1.f;
  }
  #pragma unroll
  for (int o = 32; o > 0; o >>= 1) prod *= __shfl_xor(prod, o);
  if ((t & 63) == 0) red[t >> 6] = prod;
  __syncthreads();
  if (t == 0) out[n] = un * (red[0]*red[1]) * (red[2]*red[3]);
}

__global__ __launch_bounds__(256) void k_softmax2048(float* __restrict__ P){
  __shared__ float red[4];
  float* p = P + (size_t)blockIdx.x*2048;
  int t = threadIdx.x;
  float r[8];
  float mx = -3.4e38f;
  #pragma unroll
  for (int i = 0; i < 8; i++){ r[i] = p[t + i*256]; mx = fmaxf(mx, r[i]); }
  #pragma unroll
  for (int o = 32; o > 0; o >>= 1) mx = fmaxf(mx, __shfl_xor(mx, o));
  if ((t & 63) == 0) red[t >> 6] = mx;
  __syncthreads();
  mx = fmaxf(fmaxf(red[0], red[1]), fmaxf(red[2], red[3]));
  float s = 0.f;
  #pragma unroll
  for (int i = 0; i < 8; i++){ r[i] = expf(r[i] - mx); s += r[i]; }
  #pragma unroll
  for (int o = 32; o > 0; o >>= 1) s += __shfl_xor(s, o);
  __syncthreads();
  if ((t & 63) == 0) red[t >> 6] = s;
  __syncthreads();
  s = red[0] + red[1] + red[2] + red[3];
  float inv = 1.f / s;
  #pragma unroll
  for (int i = 0; i < 8; i++) p[t + i*256] = r[i]*inv;
}

__global__ void k_writew(float* __restrict__ cw, const float* __restrict__ alloc,
                         const float* __restrict__ wg, const float* __restrict__ ag){
  int idx = blockIdx.x*256 + threadIdx.x;
  int b = idx >> 11, n = idx & 2047;
  cw[idx] = wg[b] * (0.5f*cw[idx] + 0.5f*alloc[n]*ag[b]);
}

__global__ void k_rowsum(const float* __restrict__ A, float* __restrict__ out, int rows, int cols){
  int w = (blockIdx.x*blockDim.x + threadIdx.x) >> 6;
  int lane = threadIdx.x & 63;
  if (w >= rows) return;
  const float* a = A + (size_t)w*cols;
  float s = 0.f;
  for (int c = lane; c < cols; c += 64) s += a[c];
  #pragma unroll
  for (int o = 32; o > 0; o >>= 1) s += __shfl_down(s, o);
  if (lane == 0) out[w] = s;
}

__global__ void k_colsum2048(const float* __restrict__ A, float* __restrict__ out){
  int c = blockIdx.x*256 + threadIdx.x;
  int r0 = blockIdx.y*128;
  float s = 0.f;
  for (int rr = 0; rr < 128; rr++) s += A[(size_t)(r0+rr)*2048 + c];
  atomicAdd(&out[c], s);
}

__global__ __launch_bounds__(1024) void k_bwfw(const float* __restrict__ ww, const float* __restrict__ tb,
                       const float* __restrict__ rowsum, const float* __restrict__ colsum,
                       float* __restrict__ bw, float* __restrict__ fw){
  __shared__ float sq[4][256], sd[4][256];
  int t = threadIdx.x & 255, z = threadIdx.x >> 8;
  int m = blockIdx.x*256 + t;
  float q = 0.f, dd = 0.f;
  for (int b = z*64; b < z*64 + 64; b++){
    float w = ww[(size_t)b*2048 + m];
    q  = fmaf(tb[b], w, q);
    dd = fmaf(w, w, dd);
  }
  sq[z][t] = q; sd[z][t] = dd;
  __syncthreads();
  if (z == 0){
    q  = sq[0][t] + sq[1][t] + sq[2][t] + sq[3][t];
    dd = sd[0][t] + sd[1][t] + sd[2][t] + sd[3][t];
    float lus = (q - dd) * (1.f/256.f);
    bw[m] = (0.9f*colsum[m] + 0.1f*lus) * (1.f/2048.f);
    fw[m] = (0.9f*rowsum[m] + 0.1f*lus) * (1.f/2048.f);
  }
}

__global__ __launch_bounds__(256) void k_memupdate(const float* __restrict__ ww,
    const float* __restrict__ ev, const float* __restrict__ av,
    const float* __restrict__ mem, float* __restrict__ memn)
{
  __shared__ float Ws[16][68], Es[16][68], Vs[16][68];
  int m0 = blockIdx.y*64, n0 = blockIdx.x*64;
  int tid = threadIdx.x, tx = tid & 15, ty = tid >> 4;
  int kk = tid >> 4, col = (tid & 15) << 2;
  float ae[4][4] = {}, aa[4][4] = {};
  for (int k0 = 0; k0 < 256; k0 += 16){
    float4 vw  = *(const float4*)(ww + (size_t)(k0+kk)*2048 + m0 + col);
    float4 vev = *(const float4*)(ev + (size_t)(k0+kk)*128  + n0 + col);
    float4 vav = *(const float4*)(av + (size_t)(k0+kk)*128  + n0 + col);
    Ws[kk][col]=vw.x;  Ws[kk][col+1]=vw.y;  Ws[kk][col+2]=vw.z;  Ws[kk][col+3]=vw.w;
    Es[kk][col]=vev.x; Es[kk][col+1]=vev.y; Es[kk][col+2]=vev.z; Es[kk][col+3]=vev.w;
    Vs[kk][col]=vav.x; Vs[kk][col+1]=vav.y; Vs[kk][col+2]=vav.z; Vs[kk][col+3]=vav.w;
    __syncthreads();
    #pragma unroll
    for (int k = 0; k < 16; k++){
      float a[4], e[4], v[4];
      #pragma unroll
      for (int i = 0; i < 4; i++) a[i] = Ws[k][ty*4+i];
      #pragma unroll
      for (int j = 0; j < 4; j++){ e[j] = Es[k][tx*4+j]; v[j] = Vs[k][tx*4+j]; }
      #pragma unroll
      for (int i = 0; i < 4; i++)
        #pragma unroll
        for (int j = 0; j < 4; j++){
          ae[i][j] = fmaf(a[i], e[j], ae[i][j]);
          aa[i][j] = fmaf(a[i], v[j], aa[i][j]);
        }
    }
    __syncthreads();
  }
  #pragma unroll
  for (int i = 0; i < 4; i++){
    int n = m0 + ty*4 + i;
    #pragma unroll
    for (int j = 0; j < 4; j++){
      int d = n0 + tx*4 + j;
      float em = ae[i][j] * (1.f/256.f);
      float am = aa[i][j] * (1.f/256.f);
      memn[(size_t)n*128 + d] = mem[(size_t)n*128 + d] * (1.f - em) + am;
    }
  }
}

__global__ __launch_bounds__(256) void k_bwmfwm_part(const float* __restrict__ memn,
    const float* __restrict__ bw, const float* __restrict__ fw,
    float* __restrict__ bwm, float* __restrict__ fwm)
{
  __shared__ float sb[2][128], sf[2][128];
  int d = threadIdx.x & 127, g = threadIdx.x >> 7;
  int n0 = blockIdx.x*64;
  float ab = 0.f, af = 0.f;
  #pragma unroll 4
  for (int i = g; i < 64; i += 2){
    float m = memn[(size_t)(n0+i)*128 + d];
    ab = fmaf(bw[n0+i], m, ab);
    af = fmaf(fw[n0+i], m, af);
  }
  sb[g][d] = ab; sf[g][d] = af;
  __syncthreads();
  if (g == 0){
    atomicAdd(&bwm[d], sb[0][d] + sb[1][d]);
    atomicAdd(&fwm[d], sf[0][d] + sf[1][d]);
  }
}

// hro = concat(h, read_out), fp16 out
__global__ void k_hro(const _Float16* __restrict__ h, const float* __restrict__ ro, _Float16* __restrict__ hro){
  int idx = blockIdx.x*256 + threadIdx.x;
  int b = idx / 1536, k = idx - b*1536;
  hro[idx] = (k < 1024) ? h[b*1024 + k] : (_Float16)ro[b*512 + k - 1024];
}

// ---------------- launcher ----------------

extern "C" void kernel_launch(void* const* d_in, const int* in_sizes, int n_in,
                              void* d_out, int out_size, void* d_ws, size_t ws_size,
                              hipStream_t stream)
{
  const float* x     = (const float*)d_in[0];
  const float* mem   = (const float*)d_in[1];
  const float* usage = (const float*)d_in[2];
  const float* link  = (const float*)d_in[3];
  const float* W_ih  = (const float*)d_in[4];
  // d_in[5] = W_hh: unused (h0 = 0)
  const float* b_ih  = (const float*)d_in[6];
  const float* b_hh  = (const float*)d_in[7];
  const float* W_if  = (const float*)d_in[8];
  const float* b_if  = (const float*)d_in[9];
  const float* W_out = (const float*)d_in[10];
  const float* b_out = (const float*)d_in[11];
  float* out = (float*)d_out;
  float* ws  = (float*)d_ws;

  // fp32 scratch
  float* cm     = ws + 0;         // 128  (zero region)
  float* csl    = ws + 128;       // 2048
  float* bwm    = ws + 2176;      // 128
  float* fwm    = ws + 2304;      // 128  (zero region ends at 2432)
  float* tb     = ws + 2432;      // 256
  float* bw     = ws + 2688;      // 2048
  float* fw     = ws + 4736;      // 2048
  float* wg     = ws + 6784;      // 256
  float* ag     = ws + 7040;      // 256
  float* rm0    = ws + 7296;      // 1024
  float* rm1    = ws + 8320;      // 1024
  float* rm2    = ws + 9344;      // 1024
  float* alloc  = ws + 10368;     // 2048
  float* rsl    = ws + 12416;     // 2048 rowsum(link)
  float* ev     = ws + 14464;     // 32768 (B x 128)
  float* av     = ws + 47232;     // 32768
  float* g      = ws + 80000;     // 1048576 (B x 4096); reused as k_pv partials
  float* itf    = ws + 1128576;   // 201472 (B x 787)
  float* ww     = ws + 1330048;   // 524288 (B x 2048)
  float* memn   = ws + 1854336;   // 262144 (2048 x 128)
  float* sim    = ws + 2116480;   // 2097152 (B*R x 2048)
  float* ro     = ws + 4213632;   // 131072 (B x R*D)
  // fp16 scratch (2 halves per float slot)
  _Float16* Wih_h  = (_Float16*)(ws + 4344704);  // 6,291,456 halves = 3,145,728 fl
  _Float16* Wif_h  = (_Float16*)(ws + 7490432);  //   805,888 h -> 402,944 fl
  _Float16* Wout_h = (_Float16*)(ws + 7893376);  // 1,572,864 h -> 786,432 fl
  _Float16* cin_h  = (_Float16*)(ws + 8679808);  //   393,216 h -> 196,608 fl
  _Float16* h_h    = (_Float16*)(ws + 8876416);  //   262,144 h -> 131,072 fl
  _Float16* hro_h  = (_Float16*)(ws + 9007488);  //   393,216 h -> 196,608 fl
  _Float16* wv_h   = (_Float16*)(ws + 9204096);  //    32,768 h -> 16,384 fl
  _Float16* mem_h  = (_Float16*)(ws + 9220480);  //   262,144 h -> 131,072 fl (row-normalized)
  _Float16* memn_h = (_Float16*)(ws + 9351552);  //   262,144 h -> 131,072 fl (row-normalized)
  _Float16* rks_h  = (_Float16*)(ws + 9482624);  //   131,072 h -> 65,536 fl
  // total 9,548,160 floats = 38.2 MB

  // stage 0: zero accumulators; cast weights to fp16
  k_zero  <<<10, 256, 0, stream>>>(ws, 2432);
  k_cast16<<<3072, 256, 0, stream>>>(W_ih,  Wih_h,  786432);
  k_cast16<<<394,  256, 0, stream>>>(W_if,  Wif_h,  100736);
  k_cast16<<<768,  256, 0, stream>>>(W_out, Wout_h, 196608);

  // stage 1: controller input
  k_colmean_part<<<32, 256, 0, stream>>>(mem, cm);
  k_rownorm_cast<<<512, 256, 0, stream>>>(mem, mem_h, 2048);
  k_cin         <<<1536, 256, 0, stream>>>(x, cm, cin_h);

  // stage 2: LSTM controller
  gemm_f16<<<dim3(64,8), 256, 0, stream>>>(cin_h, Wih_h, g, 256, 4096, 1536, b_ih, b_hh);
  k_lstm  <<<1024, 256, 0, stream>>>(g, h_h);

  // stage 3: interface
  gemm_f16<<<dim3(13,8), 256, 0, stream>>>(h_h, Wif_h, itf, 256, 787, 1024, b_if, nullptr);
  k_parse <<<256, 128, 0, stream>>>(itf, wv_h, ev, av, wg, ag, rm0, rm1, rm2, rks_h);

  // stage 4: write weighting (norm scales pre-folded into wv_h / mem_h)
  k_alloc<<<2048, 256, 0, stream>>>(usage, alloc);
  gemm_f16<<<dim3(32,8), 256, 0, stream>>>(wv_h, mem_h, ww, 256, 2048, 128, nullptr, nullptr);
  k_softmax2048<<<256, 256, 0, stream>>>(ww);
  k_writew<<<2048, 256, 0, stream>>>(ww, alloc, wg, ag);

  // stage 5: link-derived read vectors
  k_rowsum<<<512, 256, 0, stream>>>(link, rsl, 2048, 2048);
  k_colsum2048<<<dim3(8,16), 256, 0, stream>>>(link, csl);
  k_rowsum<<<64, 256, 0, stream>>>(ww, tb, 256, 2048);
  k_bwfw  <<<8, 1024, 0, stream>>>(ww, tb, rsl, csl, bw, fw);

  // stage 6: memory update
  k_memupdate  <<<dim3(2,32), 256, 0, stream>>>(ww, ev, av, mem, memn);
  k_rownorm_cast<<<512, 256, 0, stream>>>(memn, memn_h, 2048);
  k_bwmfwm_part<<<32, 256, 0, stream>>>(memn, bw, fw, bwm, fwm);

  // stage 7: read addressing + read output
  gemm_f16<<<dim3(32,32), 256, 0, stream>>>(rks_h, memn_h, sim, 1024, 2048, 128, nullptr, nullptr);
  k_softmax2048<<<1024, 256, 0, stream>>>(sim);
  k_pv    <<<dim3(8,64), 256, 0, stream>>>(sim, memn, g);
  k_rocomb<<<512, 256, 0, stream>>>(g, rm0, rm1, rm2, bwm, fwm, ro);

  // stage 8: output projection
  k_hro   <<<1536, 256, 0, stream>>>(h_h, ro, hro_h);
  gemm_f16<<<dim3(16,8), 256, 0, stream>>>(hro_h, Wout_h, out, 256, 1024, 1536, b_out, nullptr);

  (void)in_sizes; (void)n_in; (void)out_size; (void)ws_size;
}